// Round 2
// baseline (10353.189 us; speedup 1.0000x reference)
//
#include <hip/hip_runtime.h>
#include <cmath>
#include <cstddef>
#include <cstdint>

// ---------------------------------------------------------------------------
// GEMM: C[M,Nout] = A[M,K] @ W[K,Nout] + bias   (fp32, VALU)
// 128x128 tile, BK=16, 256 threads, 8x8 micro-tile.
// ---------------------------------------------------------------------------
#define BM 128
#define BN 128
#define BK 16

__global__ __launch_bounds__(256) void gemm_bias_k(
    const float* __restrict__ A, const float* __restrict__ W,
    const float* __restrict__ bias, float* __restrict__ C,
    int M, int K, int Nout) {
  __shared__ float As[BK][BM];  // [k][m]
  __shared__ float Bs[BK][BN];  // [k][n]
  const int tid = threadIdx.x;
  const int bm = blockIdx.x * BM;
  const int bn = blockIdx.y * BN;
  const int tx = tid & 15;
  const int ty = tid >> 4;

  float acc[8][8];
#pragma unroll
  for (int i = 0; i < 8; ++i)
#pragma unroll
    for (int j = 0; j < 8; ++j) acc[i][j] = 0.f;

  for (int k0 = 0; k0 < K; k0 += BK) {
    // A tile: 128 rows x 16 cols = 512 float4, 2 per thread; store transposed.
#pragma unroll
    for (int u = 0; u < 2; ++u) {
      int idx = tid + u * 256;
      int row = idx >> 2;
      int kq = (idx & 3) << 2;
      float4 av = make_float4(0.f, 0.f, 0.f, 0.f);
      int gr = bm + row;
      if (gr < M) av = *(const float4*)(A + (size_t)gr * K + k0 + kq);
      As[kq + 0][row] = av.x;
      As[kq + 1][row] = av.y;
      As[kq + 2][row] = av.z;
      As[kq + 3][row] = av.w;
    }
    // B tile: 16 rows x 128 cols = 512 float4, 2 per thread.
#pragma unroll
    for (int u = 0; u < 2; ++u) {
      int idx = tid + u * 256;
      int bk = idx >> 5;
      int c4 = (idx & 31) << 2;
      float4 bv = *(const float4*)(W + (size_t)(k0 + bk) * Nout + bn + c4);
      *(float4*)&Bs[bk][c4] = bv;
    }
    __syncthreads();
#pragma unroll
    for (int kk = 0; kk < BK; ++kk) {
      float a[8], b[8];
      *(float4*)&a[0] = *(const float4*)&As[kk][ty * 8];
      *(float4*)&a[4] = *(const float4*)&As[kk][ty * 8 + 4];
      *(float4*)&b[0] = *(const float4*)&Bs[kk][tx * 8];
      *(float4*)&b[4] = *(const float4*)&Bs[kk][tx * 8 + 4];
#pragma unroll
      for (int i = 0; i < 8; ++i)
#pragma unroll
        for (int j = 0; j < 8; ++j) acc[i][j] = fmaf(a[i], b[j], acc[i][j]);
    }
    __syncthreads();
  }

  float bv[8];
  *(float4*)&bv[0] = *(const float4*)(bias + bn + tx * 8);
  *(float4*)&bv[4] = *(const float4*)(bias + bn + tx * 8 + 4);
#pragma unroll
  for (int i = 0; i < 8; ++i) {
    int gr = bm + ty * 8 + i;
    if (gr < M) {
      float4 o0 = make_float4(acc[i][0] + bv[0], acc[i][1] + bv[1],
                              acc[i][2] + bv[2], acc[i][3] + bv[3]);
      float4 o1 = make_float4(acc[i][4] + bv[4], acc[i][5] + bv[5],
                              acc[i][6] + bv[6], acc[i][7] + bv[7]);
      *(float4*)(C + (size_t)gr * Nout + bn + tx * 8) = o0;
      *(float4*)(C + (size_t)gr * Nout + bn + tx * 8 + 4) = o1;
    }
  }
}

// ---------------------------------------------------------------------------
// CSR build (dst-sorted), once per call.
// ---------------------------------------------------------------------------
__global__ void count_deg_k(const int* __restrict__ dst, int E,
                            int* __restrict__ cnt) {
  int e = blockIdx.x * blockDim.x + threadIdx.x;
  if (e < E) atomicAdd(&cnt[dst[e]], 1);
}

__global__ void scan_k(const int* __restrict__ cnt, int* __restrict__ rowptr,
                       int N) {
  __shared__ int part[1024];
  int t = threadIdx.x;
  int per = (N + 1023) >> 10;
  int base = t * per;
  int s = 0;
  for (int i = 0; i < per; ++i) {
    int idx = base + i;
    if (idx < N) s += cnt[idx];
  }
  part[t] = s;
  __syncthreads();
  for (int off = 1; off < 1024; off <<= 1) {
    int v = (t >= off) ? part[t - off] : 0;
    __syncthreads();
    part[t] += v;
    __syncthreads();
  }
  int run = part[t] - s;  // exclusive prefix for this chunk
  for (int i = 0; i < per; ++i) {
    int idx = base + i;
    if (idx < N) {
      rowptr[idx] = run;
      run += cnt[idx];
    }
  }
  if (t == 1023) rowptr[N] = part[1023];
}

__global__ void scatter_csr_k(const int* __restrict__ src,
                              const int* __restrict__ dst, int E,
                              const int* __restrict__ rowptr,
                              int* __restrict__ fill, int* __restrict__ csr_src,
                              int* __restrict__ csr_eid) {
  int e = blockIdx.x * blockDim.x + threadIdx.x;
  if (e >= E) return;
  int d = dst[e];
  int pos = rowptr[d] + atomicAdd(&fill[d], 1);
  csr_src[pos] = src[e];
  csr_eid[pos] = e;
}

// ---------------------------------------------------------------------------
// Edge attention
// ---------------------------------------------------------------------------
__global__ __launch_bounds__(256) void edge_logits_k(
    const float* __restrict__ q, const float* __restrict__ k,
    const int* __restrict__ src, const int* __restrict__ dst,
    float* __restrict__ logits, int E, int C, float scale) {
  int gid = blockIdx.x * blockDim.x + threadIdx.x;
  int w = gid >> 6;
  int lane = threadIdx.x & 63;
  if (w >= E) return;
  const float* qr = q + (size_t)dst[w] * C;
  const float* kr = k + (size_t)src[w] * C;
  float sum = 0.f;
  for (int c = lane * 4; c < C; c += 256) {
    float4 a = *(const float4*)(qr + c);
    float4 b = *(const float4*)(kr + c);
    sum += a.x * b.x + a.y * b.y + a.z * b.z + a.w * b.w;
  }
#pragma unroll
  for (int off = 32; off > 0; off >>= 1) sum += __shfl_down(sum, off);
  if (lane == 0) logits[w] = sum * scale;
}

__device__ __forceinline__ unsigned f32_key(float f) {
  unsigned s = __float_as_uint(f);
  return (s & 0x80000000u) ? ~s : (s | 0x80000000u);
}
__device__ __forceinline__ float key_f32(unsigned key) {
  unsigned s = (key & 0x80000000u) ? (key ^ 0x80000000u) : ~key;
  return __uint_as_float(s);
}

__global__ void seg_max_k(const float* __restrict__ logits,
                          const int* __restrict__ dst,
                          unsigned* __restrict__ mmax, int E) {
  int e = blockIdx.x * blockDim.x + threadIdx.x;
  if (e >= E) return;
  atomicMax(&mmax[dst[e]], f32_key(logits[e]));
}

__global__ void exp_sum_k(float* __restrict__ logits,
                          const int* __restrict__ dst,
                          const unsigned* __restrict__ mmax,
                          float* __restrict__ ssum, int E) {
  int e = blockIdx.x * blockDim.x + threadIdx.x;
  if (e >= E) return;
  int d = dst[e];
  float m = key_f32(mmax[d]);
  float ee = expf(logits[e] - m);
  logits[e] = ee;
  atomicAdd(&ssum[d], ee);
}

// out[i,:] += sum_{e: dst=i} alpha_e * v[src_e,:]; optional ELU on the total.
__global__ __launch_bounds__(256) void aggregate_k(
    const float* __restrict__ v, const float* __restrict__ ebuf,
    const float* __restrict__ ssum, const int* __restrict__ rowptr,
    const int* __restrict__ csr_src, const int* __restrict__ csr_eid,
    float* __restrict__ out, int C, int do_elu) {
  int i = blockIdx.x;
  int t = threadIdx.x;
  int nq = C >> 10;  // float4 chunks per thread (C/1024): 1 or 2
  float4 acc[2];
  acc[0] = make_float4(0.f, 0.f, 0.f, 0.f);
  acc[1] = acc[0];
  int beg = rowptr[i], end = rowptr[i + 1];
  float denom = 1.f / (ssum[i] + 1e-16f);
  for (int p = beg; p < end; ++p) {
    int s = csr_src[p];
    float alpha = ebuf[csr_eid[p]] * denom;
    const float4* vr = (const float4*)(v + (size_t)s * C);
#pragma unroll
    for (int j = 0; j < 2; ++j) {
      if (j < nq) {
        float4 xv = vr[t + j * 256];
        acc[j].x = fmaf(alpha, xv.x, acc[j].x);
        acc[j].y = fmaf(alpha, xv.y, acc[j].y);
        acc[j].z = fmaf(alpha, xv.z, acc[j].z);
        acc[j].w = fmaf(alpha, xv.w, acc[j].w);
      }
    }
  }
  float4* orow = (float4*)(out + (size_t)i * C);
#pragma unroll
  for (int j = 0; j < 2; ++j) {
    if (j < nq) {
      float4 o = orow[t + j * 256];
      o.x += acc[j].x;
      o.y += acc[j].y;
      o.z += acc[j].z;
      o.w += acc[j].w;
      if (do_elu) {
        o.x = o.x > 0.f ? o.x : expm1f(o.x);
        o.y = o.y > 0.f ? o.y : expm1f(o.y);
        o.z = o.z > 0.f ? o.z : expm1f(o.z);
        o.w = o.w > 0.f ? o.w : expm1f(o.w);
      }
      orow[t + j * 256] = o;
    }
  }
}

// ---------------------------------------------------------------------------
extern "C" void kernel_launch(void* const* d_in, const int* in_sizes, int n_in,
                              void* d_out, int out_size, void* d_ws,
                              size_t ws_size, hipStream_t stream) {
  const float* x = (const float*)d_in[0];
  const int* eidx = (const int*)d_in[1];  // int32 per harness convention
  const int N = in_sizes[0] / 2048;
  const int E = in_sizes[1] / 2;
  const int* srcA = eidx;
  const int* dstA = eidx + E;

  // workspace layout (256B-aligned slices)
  char* p = (char*)d_ws;
  auto alloc = [&](size_t bytes) {
    void* r = (void*)p;
    p += (bytes + 255) & ~(size_t)255;
    return r;
  };
  const size_t NC = (size_t)N * 2048;
  float* bufA = (float*)alloc(NC * 4);
  float* bufB = (float*)alloc(NC * 4);
  float* logits = (float*)alloc((size_t)E * 4);
  float* ssum = (float*)alloc((size_t)N * 4);
  unsigned* mmax = (unsigned*)alloc((size_t)N * 4);
  int* rowptr = (int*)alloc((size_t)(N + 1) * 4);
  int* cnt = (int*)alloc((size_t)N * 4);
  int* fill = (int*)alloc((size_t)N * 4);
  int* csr_src = (int*)alloc((size_t)E * 4);
  int* csr_eid = (int*)alloc((size_t)E * 4);
  float* dout = (float*)d_out;

  // CSR build (edges fixed for all 4 layers)
  hipMemsetAsync(cnt, 0, (size_t)N * 4, stream);
  hipMemsetAsync(fill, 0, (size_t)N * 4, stream);
  count_deg_k<<<(E + 255) / 256, 256, 0, stream>>>(dstA, E, cnt);
  scan_k<<<1, 1024, 0, stream>>>(cnt, rowptr, N);
  scatter_csr_k<<<(E + 255) / 256, 256, 0, stream>>>(srcA, dstA, E, rowptr,
                                                     fill, csr_src, csr_eid);

  const int fi[4] = {2048, 1024, 2048, 1024};
  const int fo[4] = {1024, 2048, 1024, 2048};
  const int elu[4] = {1, 0, 1, 0};
  float* Bbuf[4] = {bufB, dout, bufB, dout};

  const float* cur = x;
  for (int L = 0; L < 4; ++L) {
    const float* Wq = (const float*)d_in[2 + L * 8 + 0];
    const float* bq = (const float*)d_in[2 + L * 8 + 1];
    const float* Wk = (const float*)d_in[2 + L * 8 + 2];
    const float* bk = (const float*)d_in[2 + L * 8 + 3];
    const float* Wv = (const float*)d_in[2 + L * 8 + 4];
    const float* bvv = (const float*)d_in[2 + L * 8 + 5];
    const float* Wsk = (const float*)d_in[2 + L * 8 + 6];
    const float* bsk = (const float*)d_in[2 + L * 8 + 7];
    float* A = bufA;
    float* B = Bbuf[L];
    int K = fi[L], C = fo[L];
    dim3 gg((N + BM - 1) / BM, C / BN);
    float scale = (float)(1.0 / sqrt((double)C));

    // q -> A, k -> B
    gemm_bias_k<<<gg, 256, 0, stream>>>(cur, Wq, bq, A, N, K, C);
    gemm_bias_k<<<gg, 256, 0, stream>>>(cur, Wk, bk, B, N, K, C);
    // logits over edges
    edge_logits_k<<<(E * 64 + 255) / 256, 256, 0, stream>>>(A, B, srcA, dstA,
                                                            logits, E, C, scale);
    hipMemsetAsync(mmax, 0, (size_t)N * 4, stream);
    hipMemsetAsync(ssum, 0, (size_t)N * 4, stream);
    seg_max_k<<<(E + 255) / 256, 256, 0, stream>>>(logits, dstA, mmax, E);
    exp_sum_k<<<(E + 255) / 256, 256, 0, stream>>>(logits, dstA, mmax, ssum, E);
    // v -> A (q dead), skip -> B (k dead)
    gemm_bias_k<<<gg, 256, 0, stream>>>(cur, Wv, bvv, A, N, K, C);
    gemm_bias_k<<<gg, 256, 0, stream>>>(cur, Wsk, bsk, B, N, K, C);
    // B += aggregation; ELU for layers 1,3
    aggregate_k<<<N, 256, 0, stream>>>(A, logits, ssum, rowptr, csr_src,
                                       csr_eid, B, C, elu[L]);
    cur = B;
  }
}

// Round 3
// 4987.270 us; speedup vs baseline: 2.0759x; 2.0759x over previous
//
#include <hip/hip_runtime.h>
#include <cmath>
#include <cstddef>
#include <cstdint>

typedef __attribute__((ext_vector_type(8))) short short8_t;
typedef __attribute__((ext_vector_type(4))) float f32x4;

// ---------------------------------------------------------------------------
// helpers: fp32 -> bf16 split
// ---------------------------------------------------------------------------
__device__ __forceinline__ unsigned short f2bf(float f) {
  unsigned u = __float_as_uint(f);
  unsigned r = u + 0x7fffu + ((u >> 16) & 1u);
  return (unsigned short)(r >> 16);
}
__device__ __forceinline__ float bf2f(unsigned short h) {
  return __uint_as_float((unsigned)h << 16);
}

// ---------------------------------------------------------------------------
// Weight transpose + split: W[K][C] fp32 -> Th[C][K], Tl[C][K] bf16
// ---------------------------------------------------------------------------
__global__ __launch_bounds__(256) void transp_split_k(
    const float* __restrict__ W, unsigned short* __restrict__ Th,
    unsigned short* __restrict__ Tl, int K, int C) {
  __shared__ float t[32][33];
  int k0 = blockIdx.x * 32, c0 = blockIdx.y * 32;
  int tx = threadIdx.x & 31, ty = threadIdx.x >> 5;  // ty 0..7
#pragma unroll
  for (int r = 0; r < 4; ++r)
    t[ty + r * 8][tx] = W[(size_t)(k0 + ty + r * 8) * C + c0 + tx];
  __syncthreads();
#pragma unroll
  for (int r = 0; r < 4; ++r) {
    int c = ty + r * 8;
    float v = t[tx][c];  // = W[k0+tx][c0+c]
    unsigned short h = f2bf(v);
    unsigned short l = f2bf(v - bf2f(h));
    Th[(size_t)(c0 + c) * K + k0 + tx] = h;
    Tl[(size_t)(c0 + c) * K + k0 + tx] = l;
  }
}

// ---------------------------------------------------------------------------
// bf16x3 MFMA GEMM: C[M,Nout] = A[M,K](fp32, split on the fly) @ Wt^T + bias
// Wt given as Bh/Bl [Nout][K] bf16 (pre-transposed, hi/lo).
// 128x128 tile, BK=32, 256 threads = 4 waves (2x2), 16x16x32 bf16 MFMA.
// ---------------------------------------------------------------------------
__global__ __launch_bounds__(256) void gemm_bf16x3_k(
    const float* __restrict__ A, const unsigned short* __restrict__ Bh,
    const unsigned short* __restrict__ Bl, const float* __restrict__ bias,
    float* __restrict__ C, int M, int K, int Nout) {
  __shared__ unsigned short Ah[128][40], Al[128][40];  // +8 pad: 80B stride
  __shared__ unsigned short Bhs[128][40], Bls[128][40];
  const int tid = threadIdx.x;
  const int bm = blockIdx.x * 128, bn = blockIdx.y * 128;
  const int lane = tid & 63, w = tid >> 6;
  const int wm = w >> 1, wn = w & 1;
  const int fr = lane & 15, kg = lane >> 4;  // fragment row/col, k-group

  f32x4 acc[4][4];
#pragma unroll
  for (int i = 0; i < 4; ++i)
#pragma unroll
    for (int j = 0; j < 4; ++j) acc[i][j] = (f32x4)0.f;

  for (int k0 = 0; k0 < K; k0 += 32) {
    // stage A: 128x32 fp32 -> hi/lo bf16 LDS
#pragma unroll
    for (int u = 0; u < 4; ++u) {
      int c = u * 256 + tid;
      int row = c >> 3, kc = (c & 7) * 4;
      int gr = min(bm + row, M - 1);
      float4 av = *(const float4*)(A + (size_t)gr * K + k0 + kc);
      ushort4 h, l;
      h.x = f2bf(av.x); l.x = f2bf(av.x - bf2f(h.x));
      h.y = f2bf(av.y); l.y = f2bf(av.y - bf2f(h.y));
      h.z = f2bf(av.z); l.z = f2bf(av.z - bf2f(h.z));
      h.w = f2bf(av.w); l.w = f2bf(av.w - bf2f(h.w));
      *(ushort4*)&Ah[row][kc] = h;
      *(ushort4*)&Al[row][kc] = l;
    }
    // stage B: 128 cols x 32 k bf16 (hi & lo)
#pragma unroll
    for (int u = 0; u < 2; ++u) {
      int c = u * 256 + tid;
      int row = c >> 2, kc = (c & 3) * 8;
      *(uint4*)&Bhs[row][kc] =
          *(const uint4*)(Bh + (size_t)(bn + row) * K + k0 + kc);
      *(uint4*)&Bls[row][kc] =
          *(const uint4*)(Bl + (size_t)(bn + row) * K + k0 + kc);
    }
    __syncthreads();

    short8_t ah[4], al[4], bh[4], bl[4];
#pragma unroll
    for (int i = 0; i < 4; ++i) {
      ah[i] = *(const short8_t*)&Ah[wm * 64 + i * 16 + fr][kg * 8];
      al[i] = *(const short8_t*)&Al[wm * 64 + i * 16 + fr][kg * 8];
      bh[i] = *(const short8_t*)&Bhs[wn * 64 + i * 16 + fr][kg * 8];
      bl[i] = *(const short8_t*)&Bls[wn * 64 + i * 16 + fr][kg * 8];
    }
#pragma unroll
    for (int i = 0; i < 4; ++i)
#pragma unroll
      for (int j = 0; j < 4; ++j) {
        acc[i][j] = __builtin_amdgcn_mfma_f32_16x16x32_bf16(ah[i], bh[j],
                                                            acc[i][j], 0, 0, 0);
        acc[i][j] = __builtin_amdgcn_mfma_f32_16x16x32_bf16(ah[i], bl[j],
                                                            acc[i][j], 0, 0, 0);
        acc[i][j] = __builtin_amdgcn_mfma_f32_16x16x32_bf16(al[i], bh[j],
                                                            acc[i][j], 0, 0, 0);
      }
    __syncthreads();
  }

  // epilogue: C[row = bm+wm*64+i*16+kg*4+r][col = bn+wn*64+j*16+fr]
  float bv[4];
#pragma unroll
  for (int j = 0; j < 4; ++j) bv[j] = bias[bn + wn * 64 + j * 16 + fr];
#pragma unroll
  for (int i = 0; i < 4; ++i) {
#pragma unroll
    for (int r = 0; r < 4; ++r) {
      int gr = bm + wm * 64 + i * 16 + kg * 4 + r;
      if (gr < M) {
#pragma unroll
        for (int j = 0; j < 4; ++j)
          C[(size_t)gr * Nout + bn + wn * 64 + j * 16 + fr] = acc[i][j][r] + bv[j];
      }
    }
  }
}

// ---------------------------------------------------------------------------
// fp32 VALU GEMM (fallback when ws too small for bf16 path)
// ---------------------------------------------------------------------------
#define BM 128
#define BN 128
#define BK 16

__global__ __launch_bounds__(256) void gemm_bias_k(
    const float* __restrict__ A, const float* __restrict__ W,
    const float* __restrict__ bias, float* __restrict__ C,
    int M, int K, int Nout) {
  __shared__ float As[BK][BM];
  __shared__ float Bs[BK][BN];
  const int tid = threadIdx.x;
  const int bm = blockIdx.x * BM;
  const int bn = blockIdx.y * BN;
  const int tx = tid & 15;
  const int ty = tid >> 4;

  float acc[8][8];
#pragma unroll
  for (int i = 0; i < 8; ++i)
#pragma unroll
    for (int j = 0; j < 8; ++j) acc[i][j] = 0.f;

  for (int k0 = 0; k0 < K; k0 += BK) {
#pragma unroll
    for (int u = 0; u < 2; ++u) {
      int idx = tid + u * 256;
      int row = idx >> 2;
      int kq = (idx & 3) << 2;
      float4 av = make_float4(0.f, 0.f, 0.f, 0.f);
      int gr = bm + row;
      if (gr < M) av = *(const float4*)(A + (size_t)gr * K + k0 + kq);
      As[kq + 0][row] = av.x;
      As[kq + 1][row] = av.y;
      As[kq + 2][row] = av.z;
      As[kq + 3][row] = av.w;
    }
#pragma unroll
    for (int u = 0; u < 2; ++u) {
      int idx = tid + u * 256;
      int bk = idx >> 5;
      int c4 = (idx & 31) << 2;
      float4 bv = *(const float4*)(W + (size_t)(k0 + bk) * Nout + bn + c4);
      *(float4*)&Bs[bk][c4] = bv;
    }
    __syncthreads();
#pragma unroll
    for (int kk = 0; kk < BK; ++kk) {
      float a[8], b[8];
      *(float4*)&a[0] = *(const float4*)&As[kk][ty * 8];
      *(float4*)&a[4] = *(const float4*)&As[kk][ty * 8 + 4];
      *(float4*)&b[0] = *(const float4*)&Bs[kk][tx * 8];
      *(float4*)&b[4] = *(const float4*)&Bs[kk][tx * 8 + 4];
#pragma unroll
      for (int i = 0; i < 8; ++i)
#pragma unroll
        for (int j = 0; j < 8; ++j) acc[i][j] = fmaf(a[i], b[j], acc[i][j]);
    }
    __syncthreads();
  }

  float bv[8];
  *(float4*)&bv[0] = *(const float4*)(bias + bn + tx * 8);
  *(float4*)&bv[4] = *(const float4*)(bias + bn + tx * 8 + 4);
#pragma unroll
  for (int i = 0; i < 8; ++i) {
    int gr = bm + ty * 8 + i;
    if (gr < M) {
      float4 o0 = make_float4(acc[i][0] + bv[0], acc[i][1] + bv[1],
                              acc[i][2] + bv[2], acc[i][3] + bv[3]);
      float4 o1 = make_float4(acc[i][4] + bv[4], acc[i][5] + bv[5],
                              acc[i][6] + bv[6], acc[i][7] + bv[7]);
      *(float4*)(C + (size_t)gr * Nout + bn + tx * 8) = o0;
      *(float4*)(C + (size_t)gr * Nout + bn + tx * 8 + 4) = o1;
    }
  }
}

// ---------------------------------------------------------------------------
// CSR build (dst-sorted), once per call.
// ---------------------------------------------------------------------------
__global__ void count_deg_k(const int* __restrict__ dst, int E,
                            int* __restrict__ cnt) {
  int e = blockIdx.x * blockDim.x + threadIdx.x;
  if (e < E) atomicAdd(&cnt[dst[e]], 1);
}

__global__ void scan_k(const int* __restrict__ cnt, int* __restrict__ rowptr,
                       int N) {
  __shared__ int part[1024];
  int t = threadIdx.x;
  int per = (N + 1023) >> 10;
  int base = t * per;
  int s = 0;
  for (int i = 0; i < per; ++i) {
    int idx = base + i;
    if (idx < N) s += cnt[idx];
  }
  part[t] = s;
  __syncthreads();
  for (int off = 1; off < 1024; off <<= 1) {
    int v = (t >= off) ? part[t - off] : 0;
    __syncthreads();
    part[t] += v;
    __syncthreads();
  }
  int run = part[t] - s;
  for (int i = 0; i < per; ++i) {
    int idx = base + i;
    if (idx < N) {
      rowptr[idx] = run;
      run += cnt[idx];
    }
  }
  if (t == 1023) rowptr[N] = part[1023];
}

__global__ void scatter_csr_k(const int* __restrict__ src,
                              const int* __restrict__ dst, int E,
                              const int* __restrict__ rowptr,
                              int* __restrict__ fill, int* __restrict__ csr_src,
                              int* __restrict__ csr_eid) {
  int e = blockIdx.x * blockDim.x + threadIdx.x;
  if (e >= E) return;
  int d = dst[e];
  int pos = rowptr[d] + atomicAdd(&fill[d], 1);
  csr_src[pos] = src[e];
  csr_eid[pos] = e;
}

// ---------------------------------------------------------------------------
// Edge attention
// ---------------------------------------------------------------------------
__global__ __launch_bounds__(256) void edge_logits_k(
    const float* __restrict__ q, const float* __restrict__ k,
    const int* __restrict__ src, const int* __restrict__ dst,
    float* __restrict__ logits, int E, int C, float scale) {
  int gid = blockIdx.x * blockDim.x + threadIdx.x;
  int w = gid >> 6;
  int lane = threadIdx.x & 63;
  if (w >= E) return;
  const float* qr = q + (size_t)dst[w] * C;
  const float* kr = k + (size_t)src[w] * C;
  float sum = 0.f;
  for (int c = lane * 4; c < C; c += 256) {
    float4 a = *(const float4*)(qr + c);
    float4 b = *(const float4*)(kr + c);
    sum += a.x * b.x + a.y * b.y + a.z * b.z + a.w * b.w;
  }
#pragma unroll
  for (int off = 32; off > 0; off >>= 1) sum += __shfl_down(sum, off);
  if (lane == 0) logits[w] = sum * scale;
}

__device__ __forceinline__ unsigned f32_key(float f) {
  unsigned s = __float_as_uint(f);
  return (s & 0x80000000u) ? ~s : (s | 0x80000000u);
}
__device__ __forceinline__ float key_f32(unsigned key) {
  unsigned s = (key & 0x80000000u) ? (key ^ 0x80000000u) : ~key;
  return __uint_as_float(s);
}

__global__ void seg_max_k(const float* __restrict__ logits,
                          const int* __restrict__ dst,
                          unsigned* __restrict__ mmax, int E) {
  int e = blockIdx.x * blockDim.x + threadIdx.x;
  if (e >= E) return;
  atomicMax(&mmax[dst[e]], f32_key(logits[e]));
}

__global__ void exp_sum_k(float* __restrict__ logits,
                          const int* __restrict__ dst,
                          const unsigned* __restrict__ mmax,
                          float* __restrict__ ssum, int E) {
  int e = blockIdx.x * blockDim.x + threadIdx.x;
  if (e >= E) return;
  int d = dst[e];
  float m = key_f32(mmax[d]);
  float ee = expf(logits[e] - m);
  logits[e] = ee;
  atomicAdd(&ssum[d], ee);
}

__global__ __launch_bounds__(256) void aggregate_k(
    const float* __restrict__ v, const float* __restrict__ ebuf,
    const float* __restrict__ ssum, const int* __restrict__ rowptr,
    const int* __restrict__ csr_src, const int* __restrict__ csr_eid,
    float* __restrict__ out, int C, int do_elu) {
  int i = blockIdx.x;
  int t = threadIdx.x;
  int nq = C >> 10;
  float4 acc[2];
  acc[0] = make_float4(0.f, 0.f, 0.f, 0.f);
  acc[1] = acc[0];
  int beg = rowptr[i], end = rowptr[i + 1];
  float denom = 1.f / (ssum[i] + 1e-16f);
  for (int p = beg; p < end; ++p) {
    int s = csr_src[p];
    float alpha = ebuf[csr_eid[p]] * denom;
    const float4* vr = (const float4*)(v + (size_t)s * C);
#pragma unroll
    for (int j = 0; j < 2; ++j) {
      if (j < nq) {
        float4 xv = vr[t + j * 256];
        acc[j].x = fmaf(alpha, xv.x, acc[j].x);
        acc[j].y = fmaf(alpha, xv.y, acc[j].y);
        acc[j].z = fmaf(alpha, xv.z, acc[j].z);
        acc[j].w = fmaf(alpha, xv.w, acc[j].w);
      }
    }
  }
  float4* orow = (float4*)(out + (size_t)i * C);
#pragma unroll
  for (int j = 0; j < 2; ++j) {
    if (j < nq) {
      float4 o = orow[t + j * 256];
      o.x += acc[j].x;
      o.y += acc[j].y;
      o.z += acc[j].z;
      o.w += acc[j].w;
      if (do_elu) {
        o.x = o.x > 0.f ? o.x : expm1f(o.x);
        o.y = o.y > 0.f ? o.y : expm1f(o.y);
        o.z = o.z > 0.f ? o.z : expm1f(o.z);
        o.w = o.w > 0.f ? o.w : expm1f(o.w);
      }
      orow[t + j * 256] = o;
    }
  }
}

// ---------------------------------------------------------------------------
extern "C" void kernel_launch(void* const* d_in, const int* in_sizes, int n_in,
                              void* d_out, int out_size, void* d_ws,
                              size_t ws_size, hipStream_t stream) {
  const float* x = (const float*)d_in[0];
  const int* eidx = (const int*)d_in[1];
  const int N = in_sizes[0] / 2048;
  const int E = in_sizes[1] / 2;
  const int* srcA = eidx;
  const int* dstA = eidx + E;
  float* dout = (float*)d_out;

  char* p = (char*)d_ws;
  auto alloc = [&](size_t bytes) {
    void* r = (void*)p;
    p += (bytes + 255) & ~(size_t)255;
    return r;
  };

  // small/common buffers
  float* logits = (float*)alloc((size_t)E * 4);
  float* ssum = (float*)alloc((size_t)N * 4);
  unsigned* mmax = (unsigned*)alloc((size_t)N * 4);
  int* rowptr = (int*)alloc((size_t)(N + 1) * 4);
  int* cnt = (int*)alloc((size_t)N * 4);
  int* fill = (int*)alloc((size_t)N * 4);
  int* csr_src = (int*)alloc((size_t)E * 4);
  int* csr_eid = (int*)alloc((size_t)E * 4);

  // CSR build (edges fixed for all 4 layers)
  hipMemsetAsync(cnt, 0, (size_t)N * 4, stream);
  hipMemsetAsync(fill, 0, (size_t)N * 4, stream);
  count_deg_k<<<(E + 255) / 256, 256, 0, stream>>>(dstA, E, cnt);
  scan_k<<<1, 1024, 0, stream>>>(cnt, rowptr, N);
  scatter_csr_k<<<(E + 255) / 256, 256, 0, stream>>>(srcA, dstA, E, rowptr,
                                                     fill, csr_src, csr_eid);

  const size_t used_common = (size_t)(p - (char*)d_ws);
  const size_t szP0 = (size_t)N * 2048 * 4;
  const size_t szP1 = (size_t)N * 1024 * 4;
  const size_t szP2 = (size_t)N * 2048 * 4;
  const size_t szWt = (size_t)2048 * 1024 * 2;  // bf16, one matrix max
  const size_t need_bf16 = used_common + szP0 + szP1 + szP2 + 2 * szWt + 4096;

  if (ws_size >= need_bf16) {
    // ---- MFMA bf16x3 path ----
    float* P0 = (float*)alloc(szP0);
    float* P1 = (float*)alloc(szP1);
    float* P2 = (float*)alloc(szP2);
    unsigned short* Wth = (unsigned short*)alloc(szWt);
    unsigned short* Wtl = (unsigned short*)alloc(szWt);

    auto gemmf = [&](const float* X, int in_idx, float* out, int K, int C) {
      const float* W = (const float*)d_in[in_idx];
      const float* b = (const float*)d_in[in_idx + 1];
      transp_split_k<<<dim3(K / 32, C / 32), 256, 0, stream>>>(W, Wth, Wtl, K, C);
      gemm_bf16x3_k<<<dim3((N + 127) / 128, C / 128), 256, 0, stream>>>(
          X, Wth, Wtl, b, out, N, K, C);
    };

    auto layer = [&](const float* cur, float* qvbuf, float* ksbuf,
                     float* outbuf, int L, int K, int C, int do_elu) {
      int b = 2 + L * 8;
      float scale = (float)(1.0 / sqrt((double)C));
      gemmf(cur, b + 0, qvbuf, K, C);  // q
      gemmf(cur, b + 2, ksbuf, K, C);  // k
      edge_logits_k<<<(E * 64 + 255) / 256, 256, 0, stream>>>(
          qvbuf, ksbuf, srcA, dstA, logits, E, C, scale);
      hipMemsetAsync(mmax, 0, (size_t)N * 4, stream);
      hipMemsetAsync(ssum, 0, (size_t)N * 4, stream);
      seg_max_k<<<(E + 255) / 256, 256, 0, stream>>>(logits, dstA, mmax, E);
      exp_sum_k<<<(E + 255) / 256, 256, 0, stream>>>(logits, dstA, mmax, ssum, E);
      gemmf(cur, b + 4, qvbuf, K, C);   // v (q dead)
      gemmf(cur, b + 6, outbuf, K, C);  // skip (k dead)
      aggregate_k<<<N, 256, 0, stream>>>(qvbuf, logits, ssum, rowptr, csr_src,
                                         csr_eid, outbuf, C, do_elu);
    };

    layer(x, P0, P1, P1, 0, 2048, 1024, 1);     // h1 = P1
    layer(P1, P0, P2, P2, 1, 1024, 2048, 0);    // h2 = P2
    layer(P2, P0, P1, P1, 2, 2048, 1024, 1);    // h3 = P1
    layer(P1, P0, P2, dout, 3, 1024, 2048, 0);  // out
  } else {
    // ---- fallback: fp32 VALU path (Round-2 proven) ----
    const size_t NC = (size_t)N * 2048;
    float* bufA = (float*)alloc(NC * 4);
    float* bufB = (float*)alloc(NC * 4);
    const int fi[4] = {2048, 1024, 2048, 1024};
    const int fo[4] = {1024, 2048, 1024, 2048};
    const int elu[4] = {1, 0, 1, 0};
    float* Bbuf[4] = {bufB, dout, bufB, dout};

    const float* cur = x;
    for (int L = 0; L < 4; ++L) {
      const float* Wq = (const float*)d_in[2 + L * 8 + 0];
      const float* bq = (const float*)d_in[2 + L * 8 + 1];
      const float* Wk = (const float*)d_in[2 + L * 8 + 2];
      const float* bk = (const float*)d_in[2 + L * 8 + 3];
      const float* Wv = (const float*)d_in[2 + L * 8 + 4];
      const float* bvv = (const float*)d_in[2 + L * 8 + 5];
      const float* Wsk = (const float*)d_in[2 + L * 8 + 6];
      const float* bsk = (const float*)d_in[2 + L * 8 + 7];
      float* A = bufA;
      float* B = Bbuf[L];
      int K = fi[L], C = fo[L];
      dim3 gg((N + BM - 1) / BM, C / BN);
      float scale = (float)(1.0 / sqrt((double)C));

      gemm_bias_k<<<gg, 256, 0, stream>>>(cur, Wq, bq, A, N, K, C);
      gemm_bias_k<<<gg, 256, 0, stream>>>(cur, Wk, bk, B, N, K, C);
      edge_logits_k<<<(E * 64 + 255) / 256, 256, 0, stream>>>(
          A, B, srcA, dstA, logits, E, C, scale);
      hipMemsetAsync(mmax, 0, (size_t)N * 4, stream);
      hipMemsetAsync(ssum, 0, (size_t)N * 4, stream);
      seg_max_k<<<(E + 255) / 256, 256, 0, stream>>>(logits, dstA, mmax, E);
      exp_sum_k<<<(E + 255) / 256, 256, 0, stream>>>(logits, dstA, mmax, ssum, E);
      gemm_bias_k<<<gg, 256, 0, stream>>>(cur, Wv, bvv, A, N, K, C);
      gemm_bias_k<<<gg, 256, 0, stream>>>(cur, Wsk, bsk, B, N, K, C);
      aggregate_k<<<N, 256, 0, stream>>>(A, logits, ssum, rowptr, csr_src,
                                         csr_eid, B, C, elu[L]);
      cur = B;
    }
  }
}

// Round 4
// 3895.556 us; speedup vs baseline: 2.6577x; 1.2802x over previous
//
#include <hip/hip_runtime.h>
#include <cmath>
#include <cstddef>
#include <cstdint>

typedef __attribute__((ext_vector_type(8))) short short8_t;
typedef __attribute__((ext_vector_type(4))) float f32x4;

// ---------------------------------------------------------------------------
// helpers: fp32 <-> bf16
// ---------------------------------------------------------------------------
__device__ __forceinline__ unsigned short f2bf(float f) {
  unsigned u = __float_as_uint(f);
  unsigned r = u + 0x7fffu + ((u >> 16) & 1u);
  return (unsigned short)(r >> 16);
}
__device__ __forceinline__ float bf2f(unsigned short h) {
  return __uint_as_float((unsigned)h << 16);
}

// ---------------------------------------------------------------------------
// Weight transpose + split: W[K][C] fp32 -> Th[C][K], Tl[C][K] bf16
// ---------------------------------------------------------------------------
__global__ __launch_bounds__(256) void transp_split_k(
    const float* __restrict__ W, unsigned short* __restrict__ Th,
    unsigned short* __restrict__ Tl, int K, int C) {
  __shared__ float t[32][33];
  int k0 = blockIdx.x * 32, c0 = blockIdx.y * 32;
  int tx = threadIdx.x & 31, ty = threadIdx.x >> 5;  // ty 0..7
#pragma unroll
  for (int r = 0; r < 4; ++r)
    t[ty + r * 8][tx] = W[(size_t)(k0 + ty + r * 8) * C + c0 + tx];
  __syncthreads();
#pragma unroll
  for (int r = 0; r < 4; ++r) {
    int c = ty + r * 8;
    float v = t[tx][c];  // = W[k0+tx][c0+c]
    unsigned short h = f2bf(v);
    unsigned short l = f2bf(v - bf2f(h));
    Th[(size_t)(c0 + c) * K + k0 + tx] = h;
    Tl[(size_t)(c0 + c) * K + k0 + tx] = l;
  }
}

// ---------------------------------------------------------------------------
// bf16x3 MFMA GEMM: out[M,Nout] = A[M,K](fp32, split on the fly) @ Wt^T + bias
// Wt given as Bh/Bl [Nout][K] bf16. Output fp32 (Cf) or bf16 (Cb != null).
// 128x128 tile, BK=32, 256 threads = 4 waves (2x2), 16x16x32 bf16 MFMA.
// ---------------------------------------------------------------------------
__global__ __launch_bounds__(256) void gemm_bf16x3_k(
    const float* __restrict__ A, const unsigned short* __restrict__ Bh,
    const unsigned short* __restrict__ Bl, const float* __restrict__ bias,
    float* __restrict__ Cf, unsigned short* __restrict__ Cb, int M, int K,
    int Nout) {
  __shared__ unsigned short Ah[128][40], Al[128][40];  // +8 pad: 80B stride
  __shared__ unsigned short Bhs[128][40], Bls[128][40];
  const int tid = threadIdx.x;
  const int bm = blockIdx.x * 128, bn = blockIdx.y * 128;
  const int lane = tid & 63, w = tid >> 6;
  const int wm = w >> 1, wn = w & 1;
  const int fr = lane & 15, kg = lane >> 4;

  f32x4 acc[4][4];
#pragma unroll
  for (int i = 0; i < 4; ++i)
#pragma unroll
    for (int j = 0; j < 4; ++j) acc[i][j] = (f32x4)0.f;

  for (int k0 = 0; k0 < K; k0 += 32) {
#pragma unroll
    for (int u = 0; u < 4; ++u) {
      int c = u * 256 + tid;
      int row = c >> 3, kc = (c & 7) * 4;
      int gr = min(bm + row, M - 1);
      float4 av = *(const float4*)(A + (size_t)gr * K + k0 + kc);
      ushort4 h, l;
      h.x = f2bf(av.x); l.x = f2bf(av.x - bf2f(h.x));
      h.y = f2bf(av.y); l.y = f2bf(av.y - bf2f(h.y));
      h.z = f2bf(av.z); l.z = f2bf(av.z - bf2f(h.z));
      h.w = f2bf(av.w); l.w = f2bf(av.w - bf2f(h.w));
      *(ushort4*)&Ah[row][kc] = h;
      *(ushort4*)&Al[row][kc] = l;
    }
#pragma unroll
    for (int u = 0; u < 2; ++u) {
      int c = u * 256 + tid;
      int row = c >> 2, kc = (c & 3) * 8;
      *(uint4*)&Bhs[row][kc] =
          *(const uint4*)(Bh + (size_t)(bn + row) * K + k0 + kc);
      *(uint4*)&Bls[row][kc] =
          *(const uint4*)(Bl + (size_t)(bn + row) * K + k0 + kc);
    }
    __syncthreads();

    short8_t ah[4], al[4], bh[4], bl[4];
#pragma unroll
    for (int i = 0; i < 4; ++i) {
      ah[i] = *(const short8_t*)&Ah[wm * 64 + i * 16 + fr][kg * 8];
      al[i] = *(const short8_t*)&Al[wm * 64 + i * 16 + fr][kg * 8];
      bh[i] = *(const short8_t*)&Bhs[wn * 64 + i * 16 + fr][kg * 8];
      bl[i] = *(const short8_t*)&Bls[wn * 64 + i * 16 + fr][kg * 8];
    }
#pragma unroll
    for (int i = 0; i < 4; ++i)
#pragma unroll
      for (int j = 0; j < 4; ++j) {
        acc[i][j] = __builtin_amdgcn_mfma_f32_16x16x32_bf16(ah[i], bh[j],
                                                            acc[i][j], 0, 0, 0);
        acc[i][j] = __builtin_amdgcn_mfma_f32_16x16x32_bf16(ah[i], bl[j],
                                                            acc[i][j], 0, 0, 0);
        acc[i][j] = __builtin_amdgcn_mfma_f32_16x16x32_bf16(al[i], bh[j],
                                                            acc[i][j], 0, 0, 0);
      }
    __syncthreads();
  }

  float bv[4];
#pragma unroll
  for (int j = 0; j < 4; ++j) bv[j] = bias[bn + wn * 64 + j * 16 + fr];
#pragma unroll
  for (int i = 0; i < 4; ++i) {
#pragma unroll
    for (int r = 0; r < 4; ++r) {
      int gr = bm + wm * 64 + i * 16 + kg * 4 + r;
      if (gr < M) {
        if (Cb) {
#pragma unroll
          for (int j = 0; j < 4; ++j)
            Cb[(size_t)gr * Nout + bn + wn * 64 + j * 16 + fr] =
                f2bf(acc[i][j][r] + bv[j]);
        } else {
#pragma unroll
          for (int j = 0; j < 4; ++j)
            Cf[(size_t)gr * Nout + bn + wn * 64 + j * 16 + fr] =
                acc[i][j][r] + bv[j];
        }
      }
    }
  }
}

// ---------------------------------------------------------------------------
// Fused attention: per node i (block): logits over incoming edges, softmax,
// v-aggregation (bf16 k/v), += into out (which holds skip), optional ELU.
// ---------------------------------------------------------------------------
__global__ __launch_bounds__(256) void attn_fused_k(
    const float* __restrict__ q, const unsigned short* __restrict__ kb,
    const unsigned short* __restrict__ vb, const int* __restrict__ rowptr,
    const int* __restrict__ csr_src, float* __restrict__ gscratch,
    float* __restrict__ out, int C, float scale, int do_elu) {
  __shared__ float qs[2048];
  __shared__ float ebuf[512];
  __shared__ int ssrc[512];
  __shared__ float wred[8];  // [0..3] max, [4..7] sum
  const int i = blockIdx.x;
  const int tid = threadIdx.x;
  const int lane = tid & 63, wid = tid >> 6;
  const int beg = rowptr[i], end = rowptr[i + 1];
  const int deg = end - beg;
  const bool sm = (deg <= 512);

  // stage q row + edge srcs
  for (int c = tid * 4; c < C; c += 1024)
    *(float4*)&qs[c] = *(const float4*)(q + (size_t)i * C + c);
  if (sm)
    for (int p = tid; p < deg; p += 256) ssrc[p] = csr_src[beg + p];
  if (tid < 8) wred[tid] = (tid < 4) ? -INFINITY : 0.f;
  __syncthreads();

  if (deg > 0) {
    // phase 1: per-edge logits (wave per edge)
    float wmaxv = -INFINITY;
    for (int ep = wid; ep < deg; ep += 4) {
      int s = sm ? ssrc[ep] : csr_src[beg + ep];
      const unsigned short* kr = kb + (size_t)s * C;
      float sum = 0.f;
      for (int c0 = lane * 8; c0 < C; c0 += 512) {
        uint4 pk = *(const uint4*)(kr + c0);
        float4 qa = *(const float4*)&qs[c0];
        float4 qb = *(const float4*)&qs[c0 + 4];
        const unsigned* pw = (const unsigned*)&pk;
        sum = fmaf(qa.x, __uint_as_float(pw[0] << 16), sum);
        sum = fmaf(qa.y, __uint_as_float(pw[0] & 0xffff0000u), sum);
        sum = fmaf(qa.z, __uint_as_float(pw[1] << 16), sum);
        sum = fmaf(qa.w, __uint_as_float(pw[1] & 0xffff0000u), sum);
        sum = fmaf(qb.x, __uint_as_float(pw[2] << 16), sum);
        sum = fmaf(qb.y, __uint_as_float(pw[2] & 0xffff0000u), sum);
        sum = fmaf(qb.z, __uint_as_float(pw[3] << 16), sum);
        sum = fmaf(qb.w, __uint_as_float(pw[3] & 0xffff0000u), sum);
      }
#pragma unroll
      for (int o = 32; o; o >>= 1) sum += __shfl_xor(sum, o);
      float lg = sum * scale;
      if (lane == 0) {
        if (sm) ebuf[ep] = lg; else gscratch[beg + ep] = lg;
      }
      wmaxv = fmaxf(wmaxv, lg);
    }
    if (lane == 0) wred[wid] = wmaxv;
    __syncthreads();
    float m = fmaxf(fmaxf(wred[0], wred[1]), fmaxf(wred[2], wred[3]));

    // phase 2: exp + block sum
    float part = 0.f;
    for (int ep = tid; ep < deg; ep += 256) {
      float lg = sm ? ebuf[ep] : gscratch[beg + ep];
      float e = expf(lg - m);
      if (sm) ebuf[ep] = e; else gscratch[beg + ep] = e;
      part += e;
    }
#pragma unroll
    for (int o = 32; o; o >>= 1) part += __shfl_xor(part, o);
    if (lane == 0) wred[4 + wid] = part;
  }
  __syncthreads();

  float total = wred[4] + wred[5] + wred[6] + wred[7];
  float denom = 1.f / (total + 1e-16f);
  const int cpt = C >> 8;  // cols per thread: 4 or 8
  const int col0 = tid * cpt;
  float acc[8];
#pragma unroll
  for (int j = 0; j < 8; ++j) acc[j] = 0.f;

  // phase 3: aggregate alpha * v[src]
  for (int ep = 0; ep < deg; ++ep) {
    float a = (sm ? ebuf[ep] : gscratch[beg + ep]) * denom;
    int s = sm ? ssrc[ep] : csr_src[beg + ep];
    const unsigned short* vr = vb + (size_t)s * C + col0;
    if (cpt == 4) {
      ushort4 pv = *(const ushort4*)vr;
      acc[0] = fmaf(a, bf2f(pv.x), acc[0]);
      acc[1] = fmaf(a, bf2f(pv.y), acc[1]);
      acc[2] = fmaf(a, bf2f(pv.z), acc[2]);
      acc[3] = fmaf(a, bf2f(pv.w), acc[3]);
    } else {
      uint4 pv = *(const uint4*)vr;
      const unsigned* pw = (const unsigned*)&pv;
#pragma unroll
      for (int u = 0; u < 4; ++u) {
        acc[2 * u + 0] = fmaf(a, __uint_as_float(pw[u] << 16), acc[2 * u]);
        acc[2 * u + 1] =
            fmaf(a, __uint_as_float(pw[u] & 0xffff0000u), acc[2 * u + 1]);
      }
    }
  }

  float* orow = out + (size_t)i * C + col0;
#pragma unroll
  for (int v4 = 0; v4 < 2; ++v4) {
    if (v4 * 4 < cpt) {
      float4 o = *(const float4*)(orow + v4 * 4);
      o.x += acc[v4 * 4 + 0];
      o.y += acc[v4 * 4 + 1];
      o.z += acc[v4 * 4 + 2];
      o.w += acc[v4 * 4 + 3];
      if (do_elu) {
        o.x = o.x > 0.f ? o.x : expm1f(o.x);
        o.y = o.y > 0.f ? o.y : expm1f(o.y);
        o.z = o.z > 0.f ? o.z : expm1f(o.z);
        o.w = o.w > 0.f ? o.w : expm1f(o.w);
      }
      *(float4*)(orow + v4 * 4) = o;
    }
  }
}

// ---------------------------------------------------------------------------
// CSR build (dst-sorted), once per call.
// ---------------------------------------------------------------------------
__global__ void count_deg_k(const int* __restrict__ dst, int E,
                            int* __restrict__ cnt) {
  int e = blockIdx.x * blockDim.x + threadIdx.x;
  if (e < E) atomicAdd(&cnt[dst[e]], 1);
}

__global__ void scan_k(const int* __restrict__ cnt, int* __restrict__ rowptr,
                       int N) {
  __shared__ int part[1024];
  int t = threadIdx.x;
  int per = (N + 1023) >> 10;
  int base = t * per;
  int s = 0;
  for (int i = 0; i < per; ++i) {
    int idx = base + i;
    if (idx < N) s += cnt[idx];
  }
  part[t] = s;
  __syncthreads();
  for (int off = 1; off < 1024; off <<= 1) {
    int v = (t >= off) ? part[t - off] : 0;
    __syncthreads();
    part[t] += v;
    __syncthreads();
  }
  int run = part[t] - s;
  for (int i = 0; i < per; ++i) {
    int idx = base + i;
    if (idx < N) {
      rowptr[idx] = run;
      run += cnt[idx];
    }
  }
  if (t == 1023) rowptr[N] = part[1023];
}

__global__ void scatter_csr_k(const int* __restrict__ src,
                              const int* __restrict__ dst, int E,
                              const int* __restrict__ rowptr,
                              int* __restrict__ fill, int* __restrict__ csr_src,
                              int* __restrict__ csr_eid) {
  int e = blockIdx.x * blockDim.x + threadIdx.x;
  if (e >= E) return;
  int d = dst[e];
  int pos = rowptr[d] + atomicAdd(&fill[d], 1);
  csr_src[pos] = src[e];
  csr_eid[pos] = e;
}

// ---------------------------------------------------------------------------
// Legacy fp32 path kernels (fallback when ws too small for bf16 path)
// ---------------------------------------------------------------------------
#define BM 128
#define BN 128
#define BK 16

__global__ __launch_bounds__(256) void gemm_bias_k(
    const float* __restrict__ A, const float* __restrict__ W,
    const float* __restrict__ bias, float* __restrict__ C,
    int M, int K, int Nout) {
  __shared__ float As[BK][BM];
  __shared__ float Bs[BK][BN];
  const int tid = threadIdx.x;
  const int bm = blockIdx.x * BM;
  const int bn = blockIdx.y * BN;
  const int tx = tid & 15;
  const int ty = tid >> 4;

  float acc[8][8];
#pragma unroll
  for (int i = 0; i < 8; ++i)
#pragma unroll
    for (int j = 0; j < 8; ++j) acc[i][j] = 0.f;

  for (int k0 = 0; k0 < K; k0 += BK) {
#pragma unroll
    for (int u = 0; u < 2; ++u) {
      int idx = tid + u * 256;
      int row = idx >> 2;
      int kq = (idx & 3) << 2;
      float4 av = make_float4(0.f, 0.f, 0.f, 0.f);
      int gr = bm + row;
      if (gr < M) av = *(const float4*)(A + (size_t)gr * K + k0 + kq);
      As[kq + 0][row] = av.x;
      As[kq + 1][row] = av.y;
      As[kq + 2][row] = av.z;
      As[kq + 3][row] = av.w;
    }
#pragma unroll
    for (int u = 0; u < 2; ++u) {
      int idx = tid + u * 256;
      int bk = idx >> 5;
      int c4 = (idx & 31) << 2;
      float4 bv = *(const float4*)(W + (size_t)(k0 + bk) * Nout + bn + c4);
      *(float4*)&Bs[bk][c4] = bv;
    }
    __syncthreads();
#pragma unroll
    for (int kk = 0; kk < BK; ++kk) {
      float a[8], b[8];
      *(float4*)&a[0] = *(const float4*)&As[kk][ty * 8];
      *(float4*)&a[4] = *(const float4*)&As[kk][ty * 8 + 4];
      *(float4*)&b[0] = *(const float4*)&Bs[kk][tx * 8];
      *(float4*)&b[4] = *(const float4*)&Bs[kk][tx * 8 + 4];
#pragma unroll
      for (int i = 0; i < 8; ++i)
#pragma unroll
        for (int j = 0; j < 8; ++j) acc[i][j] = fmaf(a[i], b[j], acc[i][j]);
    }
    __syncthreads();
  }

  float bv[8];
  *(float4*)&bv[0] = *(const float4*)(bias + bn + tx * 8);
  *(float4*)&bv[4] = *(const float4*)(bias + bn + tx * 8 + 4);
#pragma unroll
  for (int i = 0; i < 8; ++i) {
    int gr = bm + ty * 8 + i;
    if (gr < M) {
      float4 o0 = make_float4(acc[i][0] + bv[0], acc[i][1] + bv[1],
                              acc[i][2] + bv[2], acc[i][3] + bv[3]);
      float4 o1 = make_float4(acc[i][4] + bv[4], acc[i][5] + bv[5],
                              acc[i][6] + bv[6], acc[i][7] + bv[7]);
      *(float4*)(C + (size_t)gr * Nout + bn + tx * 8) = o0;
      *(float4*)(C + (size_t)gr * Nout + bn + tx * 8 + 4) = o1;
    }
  }
}

__global__ __launch_bounds__(256) void edge_logits_k(
    const float* __restrict__ q, const float* __restrict__ k,
    const int* __restrict__ src, const int* __restrict__ dst,
    float* __restrict__ logits, int E, int C, float scale) {
  int gid = blockIdx.x * blockDim.x + threadIdx.x;
  int w = gid >> 6;
  int lane = threadIdx.x & 63;
  if (w >= E) return;
  const float* qr = q + (size_t)dst[w] * C;
  const float* kr = k + (size_t)src[w] * C;
  float sum = 0.f;
  for (int c = lane * 4; c < C; c += 256) {
    float4 a = *(const float4*)(qr + c);
    float4 b = *(const float4*)(kr + c);
    sum += a.x * b.x + a.y * b.y + a.z * b.z + a.w * b.w;
  }
#pragma unroll
  for (int off = 32; off > 0; off >>= 1) sum += __shfl_down(sum, off);
  if (lane == 0) logits[w] = sum * scale;
}

__device__ __forceinline__ unsigned f32_key(float f) {
  unsigned s = __float_as_uint(f);
  return (s & 0x80000000u) ? ~s : (s | 0x80000000u);
}
__device__ __forceinline__ float key_f32(unsigned key) {
  unsigned s = (key & 0x80000000u) ? (key ^ 0x80000000u) : ~key;
  return __uint_as_float(s);
}

__global__ void seg_max_k(const float* __restrict__ logits,
                          const int* __restrict__ dst,
                          unsigned* __restrict__ mmax, int E) {
  int e = blockIdx.x * blockDim.x + threadIdx.x;
  if (e >= E) return;
  atomicMax(&mmax[dst[e]], f32_key(logits[e]));
}

__global__ void exp_sum_k(float* __restrict__ logits,
                          const int* __restrict__ dst,
                          const unsigned* __restrict__ mmax,
                          float* __restrict__ ssum, int E) {
  int e = blockIdx.x * blockDim.x + threadIdx.x;
  if (e >= E) return;
  int d = dst[e];
  float m = key_f32(mmax[d]);
  float ee = expf(logits[e] - m);
  logits[e] = ee;
  atomicAdd(&ssum[d], ee);
}

__global__ __launch_bounds__(256) void aggregate_k(
    const float* __restrict__ v, const float* __restrict__ ebuf,
    const float* __restrict__ ssum, const int* __restrict__ rowptr,
    const int* __restrict__ csr_src, const int* __restrict__ csr_eid,
    float* __restrict__ out, int C, int do_elu) {
  int i = blockIdx.x;
  int t = threadIdx.x;
  int nq = C >> 10;
  float4 acc[2];
  acc[0] = make_float4(0.f, 0.f, 0.f, 0.f);
  acc[1] = acc[0];
  int beg = rowptr[i], end = rowptr[i + 1];
  float denom = 1.f / (ssum[i] + 1e-16f);
  for (int p = beg; p < end; ++p) {
    int s = csr_src[p];
    float alpha = ebuf[csr_eid[p]] * denom;
    const float4* vr = (const float4*)(v + (size_t)s * C);
#pragma unroll
    for (int j = 0; j < 2; ++j) {
      if (j < nq) {
        float4 xv = vr[t + j * 256];
        acc[j].x = fmaf(alpha, xv.x, acc[j].x);
        acc[j].y = fmaf(alpha, xv.y, acc[j].y);
        acc[j].z = fmaf(alpha, xv.z, acc[j].z);
        acc[j].w = fmaf(alpha, xv.w, acc[j].w);
      }
    }
  }
  float4* orow = (float4*)(out + (size_t)i * C);
#pragma unroll
  for (int j = 0; j < 2; ++j) {
    if (j < nq) {
      float4 o = orow[t + j * 256];
      o.x += acc[j].x;
      o.y += acc[j].y;
      o.z += acc[j].z;
      o.w += acc[j].w;
      if (do_elu) {
        o.x = o.x > 0.f ? o.x : expm1f(o.x);
        o.y = o.y > 0.f ? o.y : expm1f(o.y);
        o.z = o.z > 0.f ? o.z : expm1f(o.z);
        o.w = o.w > 0.f ? o.w : expm1f(o.w);
      }
      orow[t + j * 256] = o;
    }
  }
}

// ---------------------------------------------------------------------------
extern "C" void kernel_launch(void* const* d_in, const int* in_sizes, int n_in,
                              void* d_out, int out_size, void* d_ws,
                              size_t ws_size, hipStream_t stream) {
  const float* x = (const float*)d_in[0];
  const int* eidx = (const int*)d_in[1];
  const int N = in_sizes[0] / 2048;
  const int E = in_sizes[1] / 2;
  const int* srcA = eidx;
  const int* dstA = eidx + E;
  float* dout = (float*)d_out;

  char* p = (char*)d_ws;
  auto alloc = [&](size_t bytes) {
    void* r = (void*)p;
    p += (bytes + 255) & ~(size_t)255;
    return r;
  };

  // common buffers
  float* logits = (float*)alloc((size_t)E * 4);
  float* ssum = (float*)alloc((size_t)N * 4);
  unsigned* mmax = (unsigned*)alloc((size_t)N * 4);
  int* rowptr = (int*)alloc((size_t)(N + 1) * 4);
  int* cnt = (int*)alloc((size_t)N * 4);
  int* fill = (int*)alloc((size_t)N * 4);
  int* csr_src = (int*)alloc((size_t)E * 4);
  int* csr_eid = (int*)alloc((size_t)E * 4);

  // CSR build (edges fixed for all 4 layers)
  hipMemsetAsync(cnt, 0, (size_t)N * 4, stream);
  hipMemsetAsync(fill, 0, (size_t)N * 4, stream);
  count_deg_k<<<(E + 255) / 256, 256, 0, stream>>>(dstA, E, cnt);
  scan_k<<<1, 1024, 0, stream>>>(cnt, rowptr, N);
  scatter_csr_k<<<(E + 255) / 256, 256, 0, stream>>>(srcA, dstA, E, rowptr,
                                                     fill, csr_src, csr_eid);

  const size_t used_common = (size_t)(p - (char*)d_ws);
  const size_t szQ = (size_t)N * 2048 * 4;   // fp32 q
  const size_t szP1 = (size_t)N * 1024 * 4;  // fp32, 1024-wide hidden
  const size_t szKb = (size_t)N * 2048 * 2;  // bf16 k
  const size_t szVb = (size_t)N * 2048 * 2;  // bf16 v
  const size_t szWt = (size_t)2048 * 1024 * 2;
  const size_t need_bf16 =
      used_common + szQ + szP1 + szKb + szVb + 2 * szWt + 4096;

  if (ws_size >= need_bf16) {
    // ---- MFMA bf16x3 + fused attention path ----
    float* Q = (float*)alloc(szQ);
    float* P1 = (float*)alloc(szP1);
    unsigned short* Kb = (unsigned short*)alloc(szKb);
    unsigned short* Vb = (unsigned short*)alloc(szVb);
    unsigned short* Wth = (unsigned short*)alloc(szWt);
    unsigned short* Wtl = (unsigned short*)alloc(szWt);
    float* P2 = dout;  // dout doubles as the 2048-wide hidden buffer

    auto gemmf = [&](const float* X, int in_idx, float* outf,
                     unsigned short* outb, int K, int C) {
      const float* W = (const float*)d_in[in_idx];
      const float* b = (const float*)d_in[in_idx + 1];
      transp_split_k<<<dim3(K / 32, C / 32), 256, 0, stream>>>(W, Wth, Wtl, K,
                                                               C);
      gemm_bf16x3_k<<<dim3((N + 127) / 128, C / 128), 256, 0, stream>>>(
          X, Wth, Wtl, b, outf, outb, N, K, C);
    };

    auto layer = [&](const float* cur, float* outbuf, int L, int K, int C,
                     int do_elu) {
      int b = 2 + L * 8;
      float scale = (float)(1.0 / sqrt((double)C));
      gemmf(cur, b + 0, Q, nullptr, K, C);        // q (fp32)
      gemmf(cur, b + 2, nullptr, Kb, K, C);       // k (bf16)
      gemmf(cur, b + 4, nullptr, Vb, K, C);       // v (bf16)
      gemmf(cur, b + 6, outbuf, nullptr, K, C);   // skip (fp32)
      attn_fused_k<<<N, 256, 0, stream>>>(Q, Kb, Vb, rowptr, csr_src, logits,
                                          outbuf, C, scale, do_elu);
    };

    layer(x, P1, 0, 2048, 1024, 1);    // h1 = P1
    layer(P1, P2, 1, 1024, 2048, 0);   // h2 = P2 (= dout)
    layer(P2, P1, 2, 2048, 1024, 1);   // h3 = P1
    layer(P1, dout, 3, 1024, 2048, 0); // out = dout (h2 dead by now)
  } else {
    // ---- fallback: fp32 VALU path (Round-2 proven) ----
    const size_t NC = (size_t)N * 2048;
    float* bufA = (float*)alloc(NC * 4);
    float* bufB = (float*)alloc(NC * 4);
    const int fi[4] = {2048, 1024, 2048, 1024};
    const int fo[4] = {1024, 2048, 1024, 2048};
    const int elu[4] = {1, 0, 1, 0};
    float* Bbuf[4] = {bufB, dout, bufB, dout};

    const float* cur = x;
    for (int L = 0; L < 4; ++L) {
      const float* Wq = (const float*)d_in[2 + L * 8 + 0];
      const float* bq = (const float*)d_in[2 + L * 8 + 1];
      const float* Wk = (const float*)d_in[2 + L * 8 + 2];
      const float* bk = (const float*)d_in[2 + L * 8 + 3];
      const float* Wv = (const float*)d_in[2 + L * 8 + 4];
      const float* bvv = (const float*)d_in[2 + L * 8 + 5];
      const float* Wsk = (const float*)d_in[2 + L * 8 + 6];
      const float* bsk = (const float*)d_in[2 + L * 8 + 7];
      float* A = bufA;
      float* B = Bbuf[L];
      int K = fi[L], C = fo[L];
      dim3 gg((N + BM - 1) / BM, C / BN);
      float scale = (float)(1.0 / sqrt((double)C));

      gemm_bias_k<<<gg, 256, 0, stream>>>(cur, Wq, bq, A, N, K, C);
      gemm_bias_k<<<gg, 256, 0, stream>>>(cur, Wk, bk, B, N, K, C);
      edge_logits_k<<<(E * 64 + 255) / 256, 256, 0, stream>>>(
          A, B, srcA, dstA, logits, E, C, scale);
      hipMemsetAsync(mmax, 0, (size_t)N * 4, stream);
      hipMemsetAsync(ssum, 0, (size_t)N * 4, stream);
      seg_max_k<<<(E + 255) / 256, 256, 0, stream>>>(logits, dstA, mmax, E);
      exp_sum_k<<<(E + 255) / 256, 256, 0, stream>>>(logits, dstA, mmax, ssum,
                                                     E);
      gemm_bias_k<<<gg, 256, 0, stream>>>(cur, Wv, bvv, A, N, K, C);
      gemm_bias_k<<<gg, 256, 0, stream>>>(cur, Wsk, bsk, B, N, K, C);
      aggregate_k<<<N, 256, 0, stream>>>(A, logits, ssum, rowptr, csr_src,
                                         csr_eid, B, C, elu[L]);
      cur = B;
    }
  }
}

// Round 5
// 3019.975 us; speedup vs baseline: 3.4282x; 1.2899x over previous
//
#include <hip/hip_runtime.h>
#include <cmath>
#include <cstddef>
#include <cstdint>

typedef __attribute__((ext_vector_type(8))) short short8_t;
typedef __attribute__((ext_vector_type(4))) float f32x4;

// ---------------------------------------------------------------------------
// helpers: fp32 <-> bf16
// ---------------------------------------------------------------------------
__device__ __forceinline__ unsigned short f2bf(float f) {
  unsigned u = __float_as_uint(f);
  unsigned r = u + 0x7fffu + ((u >> 16) & 1u);
  return (unsigned short)(r >> 16);
}
__device__ __forceinline__ float bf2f(unsigned short h) {
  return __uint_as_float((unsigned)h << 16);
}

// ---------------------------------------------------------------------------
// split fp32 [n4*4] -> bf16 hi/lo
// ---------------------------------------------------------------------------
__global__ __launch_bounds__(256) void split_k(const float* __restrict__ in,
                                               unsigned short* __restrict__ hh,
                                               unsigned short* __restrict__ hl,
                                               size_t n4) {
  size_t i = (size_t)blockIdx.x * blockDim.x + threadIdx.x;
  if (i >= n4) return;
  float4 v = ((const float4*)in)[i];
  ushort4 h, l;
  h.x = f2bf(v.x); l.x = f2bf(v.x - bf2f(h.x));
  h.y = f2bf(v.y); l.y = f2bf(v.y - bf2f(h.y));
  h.z = f2bf(v.z); l.z = f2bf(v.z - bf2f(h.z));
  h.w = f2bf(v.w); l.w = f2bf(v.w - bf2f(h.w));
  ((ushort4*)hh)[i] = h;
  ((ushort4*)hl)[i] = l;
}

// ---------------------------------------------------------------------------
// Weight transpose + split: W[K][C] fp32 -> Th[C][K], Tl[C][K] bf16
// ---------------------------------------------------------------------------
__global__ __launch_bounds__(256) void transp_split_k(
    const float* __restrict__ W, unsigned short* __restrict__ Th,
    unsigned short* __restrict__ Tl, int K, int C) {
  __shared__ float t[32][33];
  int k0 = blockIdx.x * 32, c0 = blockIdx.y * 32;
  int tx = threadIdx.x & 31, ty = threadIdx.x >> 5;  // ty 0..7
#pragma unroll
  for (int r = 0; r < 4; ++r)
    t[ty + r * 8][tx] = W[(size_t)(k0 + ty + r * 8) * C + c0 + tx];
  __syncthreads();
#pragma unroll
  for (int r = 0; r < 4; ++r) {
    int c = ty + r * 8;
    float v = t[tx][c];  // = W[k0+tx][c0+c]
    unsigned short h = f2bf(v);
    unsigned short l = f2bf(v - bf2f(h));
    Th[(size_t)(c0 + c) * K + k0 + tx] = h;
    Tl[(size_t)(c0 + c) * K + k0 + tx] = l;
  }
}

// ---------------------------------------------------------------------------
// Fused per-layer GEMM: [q|k|v|s] = X @ [Wq|Wk|Wv|Ws] + bias
// X given pre-split (Ah/Al bf16 [M][K]); weights pre-transposed+split
// Wth/Wtl [4C][K]. q/k blocks: 1 MFMA product (hi*hi). v/s: 3 products.
// q,k,v outputs bf16; s output fp32.
// ---------------------------------------------------------------------------
__global__ __launch_bounds__(256) void gemm_fused_k(
    const unsigned short* __restrict__ Ah, const unsigned short* __restrict__ Al,
    const unsigned short* __restrict__ Wth,
    const unsigned short* __restrict__ Wtl, const float* __restrict__ bq,
    const float* __restrict__ bk, const float* __restrict__ bv,
    const float* __restrict__ bs, unsigned short* __restrict__ Qb,
    unsigned short* __restrict__ Kb, unsigned short* __restrict__ Vb,
    float* __restrict__ S, int M, int K, int C) {
  __shared__ unsigned short Ahs[128][40], Als[128][40];  // +8 pad
  __shared__ unsigned short Bhs[128][40], Bls[128][40];
  const int tid = threadIdx.x;
  const int bm = blockIdx.x * 128, n0 = blockIdx.y * 128;
  const int kind = n0 / C;  // 0=q 1=k 2=v 3=s
  const bool full = kind >= 2;
  const int lane = tid & 63, w = tid >> 6;
  const int wm = w >> 1, wn = w & 1;
  const int fr = lane & 15, kg = lane >> 4;

  f32x4 acc[4][4];
#pragma unroll
  for (int i = 0; i < 4; ++i)
#pragma unroll
    for (int j = 0; j < 4; ++j) acc[i][j] = (f32x4)0.f;

  for (int k0 = 0; k0 < K; k0 += 32) {
#pragma unroll
    for (int u = 0; u < 2; ++u) {
      int c = u * 256 + tid;
      int row = c >> 2, kc = (c & 3) * 8;
      int gr = min(bm + row, M - 1);
      *(uint4*)&Ahs[row][kc] = *(const uint4*)(Ah + (size_t)gr * K + k0 + kc);
      *(uint4*)&Bhs[row][kc] =
          *(const uint4*)(Wth + (size_t)(n0 + row) * K + k0 + kc);
      if (full) {
        *(uint4*)&Als[row][kc] = *(const uint4*)(Al + (size_t)gr * K + k0 + kc);
        *(uint4*)&Bls[row][kc] =
            *(const uint4*)(Wtl + (size_t)(n0 + row) * K + k0 + kc);
      }
    }
    __syncthreads();

    short8_t ah[4], bh[4];
#pragma unroll
    for (int i = 0; i < 4; ++i) {
      ah[i] = *(const short8_t*)&Ahs[wm * 64 + i * 16 + fr][kg * 8];
      bh[i] = *(const short8_t*)&Bhs[wn * 64 + i * 16 + fr][kg * 8];
    }
    if (full) {
      short8_t al[4], bl[4];
#pragma unroll
      for (int i = 0; i < 4; ++i) {
        al[i] = *(const short8_t*)&Als[wm * 64 + i * 16 + fr][kg * 8];
        bl[i] = *(const short8_t*)&Bls[wn * 64 + i * 16 + fr][kg * 8];
      }
#pragma unroll
      for (int i = 0; i < 4; ++i)
#pragma unroll
        for (int j = 0; j < 4; ++j) {
          acc[i][j] = __builtin_amdgcn_mfma_f32_16x16x32_bf16(
              ah[i], bh[j], acc[i][j], 0, 0, 0);
          acc[i][j] = __builtin_amdgcn_mfma_f32_16x16x32_bf16(
              ah[i], bl[j], acc[i][j], 0, 0, 0);
          acc[i][j] = __builtin_amdgcn_mfma_f32_16x16x32_bf16(
              al[i], bh[j], acc[i][j], 0, 0, 0);
        }
    } else {
#pragma unroll
      for (int i = 0; i < 4; ++i)
#pragma unroll
        for (int j = 0; j < 4; ++j)
          acc[i][j] = __builtin_amdgcn_mfma_f32_16x16x32_bf16(
              ah[i], bh[j], acc[i][j], 0, 0, 0);
    }
    __syncthreads();
  }

  const float* bptr = (kind == 0) ? bq : (kind == 1) ? bk : (kind == 2) ? bv : bs;
  const int cbase = (n0 - kind * C) + wn * 64;
  float bvv[4];
#pragma unroll
  for (int j = 0; j < 4; ++j) bvv[j] = bptr[cbase + j * 16 + fr];

  unsigned short* ob = (kind == 0) ? Qb : (kind == 1) ? Kb : Vb;
#pragma unroll
  for (int i = 0; i < 4; ++i) {
#pragma unroll
    for (int r = 0; r < 4; ++r) {
      int gr = bm + wm * 64 + i * 16 + kg * 4 + r;
      if (gr < M) {
        if (kind == 3) {
#pragma unroll
          for (int j = 0; j < 4; ++j)
            S[(size_t)gr * C + cbase + j * 16 + fr] = acc[i][j][r] + bvv[j];
        } else {
#pragma unroll
          for (int j = 0; j < 4; ++j)
            ob[(size_t)gr * C + cbase + j * 16 + fr] =
                f2bf(acc[i][j][r] + bvv[j]);
        }
      }
    }
  }
}

// ---------------------------------------------------------------------------
// Fused attention (bf16 q/k/v). skipio holds the skip GEMM output (fp32).
// result = skip + agg, optional ELU; writeH ? split->Hh/Hl : fp32->skipio.
// ---------------------------------------------------------------------------
__global__ __launch_bounds__(256) void attn_fused2_k(
    const unsigned short* __restrict__ Qb, const unsigned short* __restrict__ Kb,
    const unsigned short* __restrict__ Vb, const int* __restrict__ rowptr,
    const int* __restrict__ csr_src, float* __restrict__ gscratch,
    float* __restrict__ skipio, unsigned short* __restrict__ Hh,
    unsigned short* __restrict__ Hl, int C, float scale, int do_elu,
    int writeH) {
  __shared__ float qs[2048];
  __shared__ float ebuf[512];
  __shared__ int ssrc[512];
  __shared__ float wred[8];
  const int i = blockIdx.x;
  const int tid = threadIdx.x;
  const int lane = tid & 63, wid = tid >> 6;
  const int beg = rowptr[i], end = rowptr[i + 1];
  const int deg = end - beg;
  const bool sm = (deg <= 512);

  // stage q row (bf16 -> fp32) + edge srcs
  for (int c = tid * 8; c < C; c += 2048) {
    uint4 pk = *(const uint4*)(Qb + (size_t)i * C + c);
    const unsigned* pw = (const unsigned*)&pk;
#pragma unroll
    for (int u = 0; u < 4; ++u) {
      qs[c + 2 * u] = __uint_as_float(pw[u] << 16);
      qs[c + 2 * u + 1] = __uint_as_float(pw[u] & 0xffff0000u);
    }
  }
  if (sm)
    for (int p = tid; p < deg; p += 256) ssrc[p] = csr_src[beg + p];
  if (tid < 8) wred[tid] = (tid < 4) ? -INFINITY : 0.f;
  __syncthreads();

  if (deg > 0) {
    float wmaxv = -INFINITY;
    for (int ep = wid; ep < deg; ep += 4) {
      int s = sm ? ssrc[ep] : csr_src[beg + ep];
      const unsigned short* kr = Kb + (size_t)s * C;
      float sum = 0.f;
      for (int c0 = lane * 8; c0 < C; c0 += 512) {
        uint4 pk = *(const uint4*)(kr + c0);
        float4 qa = *(const float4*)&qs[c0];
        float4 qb = *(const float4*)&qs[c0 + 4];
        const unsigned* pw = (const unsigned*)&pk;
        sum = fmaf(qa.x, __uint_as_float(pw[0] << 16), sum);
        sum = fmaf(qa.y, __uint_as_float(pw[0] & 0xffff0000u), sum);
        sum = fmaf(qa.z, __uint_as_float(pw[1] << 16), sum);
        sum = fmaf(qa.w, __uint_as_float(pw[1] & 0xffff0000u), sum);
        sum = fmaf(qb.x, __uint_as_float(pw[2] << 16), sum);
        sum = fmaf(qb.y, __uint_as_float(pw[2] & 0xffff0000u), sum);
        sum = fmaf(qb.z, __uint_as_float(pw[3] << 16), sum);
        sum = fmaf(qb.w, __uint_as_float(pw[3] & 0xffff0000u), sum);
      }
#pragma unroll
      for (int o = 32; o; o >>= 1) sum += __shfl_xor(sum, o);
      float lg = sum * scale;
      if (lane == 0) {
        if (sm) ebuf[ep] = lg; else gscratch[beg + ep] = lg;
      }
      wmaxv = fmaxf(wmaxv, lg);
    }
    if (lane == 0) wred[wid] = wmaxv;
    __syncthreads();
    float m = fmaxf(fmaxf(wred[0], wred[1]), fmaxf(wred[2], wred[3]));

    float part = 0.f;
    for (int ep = tid; ep < deg; ep += 256) {
      float lg = sm ? ebuf[ep] : gscratch[beg + ep];
      float e = expf(lg - m);
      if (sm) ebuf[ep] = e; else gscratch[beg + ep] = e;
      part += e;
    }
#pragma unroll
    for (int o = 32; o; o >>= 1) part += __shfl_xor(part, o);
    if (lane == 0) wred[4 + wid] = part;
  }
  __syncthreads();

  float total = wred[4] + wred[5] + wred[6] + wred[7];
  float denom = 1.f / (total + 1e-16f);
  const int cpt = C >> 8;  // 4 or 8 cols per thread
  const int col0 = tid * cpt;
  float acc[8];
#pragma unroll
  for (int j = 0; j < 8; ++j) acc[j] = 0.f;

  for (int ep = 0; ep < deg; ++ep) {
    float a = (sm ? ebuf[ep] : gscratch[beg + ep]) * denom;
    int s = sm ? ssrc[ep] : csr_src[beg + ep];
    const unsigned short* vr = Vb + (size_t)s * C + col0;
    if (cpt == 4) {
      ushort4 pv = *(const ushort4*)vr;
      acc[0] = fmaf(a, bf2f(pv.x), acc[0]);
      acc[1] = fmaf(a, bf2f(pv.y), acc[1]);
      acc[2] = fmaf(a, bf2f(pv.z), acc[2]);
      acc[3] = fmaf(a, bf2f(pv.w), acc[3]);
    } else {
      uint4 pv = *(const uint4*)vr;
      const unsigned* pw = (const unsigned*)&pv;
#pragma unroll
      for (int u = 0; u < 4; ++u) {
        acc[2 * u + 0] = fmaf(a, __uint_as_float(pw[u] << 16), acc[2 * u]);
        acc[2 * u + 1] =
            fmaf(a, __uint_as_float(pw[u] & 0xffff0000u), acc[2 * u + 1]);
      }
    }
  }

  float* srow = skipio + (size_t)i * C + col0;
#pragma unroll
  for (int v4 = 0; v4 < 2; ++v4) {
    if (v4 * 4 < cpt) {
      float4 o = *(const float4*)(srow + v4 * 4);
      o.x += acc[v4 * 4 + 0];
      o.y += acc[v4 * 4 + 1];
      o.z += acc[v4 * 4 + 2];
      o.w += acc[v4 * 4 + 3];
      if (do_elu) {
        o.x = o.x > 0.f ? o.x : expm1f(o.x);
        o.y = o.y > 0.f ? o.y : expm1f(o.y);
        o.z = o.z > 0.f ? o.z : expm1f(o.z);
        o.w = o.w > 0.f ? o.w : expm1f(o.w);
      }
      if (writeH) {
        ushort4 h, l;
        h.x = f2bf(o.x); l.x = f2bf(o.x - bf2f(h.x));
        h.y = f2bf(o.y); l.y = f2bf(o.y - bf2f(h.y));
        h.z = f2bf(o.z); l.z = f2bf(o.z - bf2f(h.z));
        h.w = f2bf(o.w); l.w = f2bf(o.w - bf2f(h.w));
        *(ushort4*)(Hh + (size_t)i * C + col0 + v4 * 4) = h;
        *(ushort4*)(Hl + (size_t)i * C + col0 + v4 * 4) = l;
      } else {
        *(float4*)(srow + v4 * 4) = o;
      }
    }
  }
}

// ---------------------------------------------------------------------------
// Round-4 fallback kernels (used if ws is too small for the new path)
// ---------------------------------------------------------------------------
__global__ __launch_bounds__(256) void gemm_bf16x3_k(
    const float* __restrict__ A, const unsigned short* __restrict__ Bh,
    const unsigned short* __restrict__ Bl, const float* __restrict__ bias,
    float* __restrict__ Cf, unsigned short* __restrict__ Cb, int M, int K,
    int Nout) {
  __shared__ unsigned short Ah[128][40], Al[128][40];
  __shared__ unsigned short Bhs[128][40], Bls[128][40];
  const int tid = threadIdx.x;
  const int bm = blockIdx.x * 128, bn = blockIdx.y * 128;
  const int lane = tid & 63, w = tid >> 6;
  const int wm = w >> 1, wn = w & 1;
  const int fr = lane & 15, kg = lane >> 4;

  f32x4 acc[4][4];
#pragma unroll
  for (int i = 0; i < 4; ++i)
#pragma unroll
    for (int j = 0; j < 4; ++j) acc[i][j] = (f32x4)0.f;

  for (int k0 = 0; k0 < K; k0 += 32) {
#pragma unroll
    for (int u = 0; u < 4; ++u) {
      int c = u * 256 + tid;
      int row = c >> 3, kc = (c & 7) * 4;
      int gr = min(bm + row, M - 1);
      float4 av = *(const float4*)(A + (size_t)gr * K + k0 + kc);
      ushort4 h, l;
      h.x = f2bf(av.x); l.x = f2bf(av.x - bf2f(h.x));
      h.y = f2bf(av.y); l.y = f2bf(av.y - bf2f(h.y));
      h.z = f2bf(av.z); l.z = f2bf(av.z - bf2f(h.z));
      h.w = f2bf(av.w); l.w = f2bf(av.w - bf2f(h.w));
      *(ushort4*)&Ah[row][kc] = h;
      *(ushort4*)&Al[row][kc] = l;
    }
#pragma unroll
    for (int u = 0; u < 2; ++u) {
      int c = u * 256 + tid;
      int row = c >> 2, kc = (c & 3) * 8;
      *(uint4*)&Bhs[row][kc] =
          *(const uint4*)(Bh + (size_t)(bn + row) * K + k0 + kc);
      *(uint4*)&Bls[row][kc] =
          *(const uint4*)(Bl + (size_t)(bn + row) * K + k0 + kc);
    }
    __syncthreads();

    short8_t ah[4], al[4], bh[4], bl[4];
#pragma unroll
    for (int i = 0; i < 4; ++i) {
      ah[i] = *(const short8_t*)&Ah[wm * 64 + i * 16 + fr][kg * 8];
      al[i] = *(const short8_t*)&Al[wm * 64 + i * 16 + fr][kg * 8];
      bh[i] = *(const short8_t*)&Bhs[wn * 64 + i * 16 + fr][kg * 8];
      bl[i] = *(const short8_t*)&Bls[wn * 64 + i * 16 + fr][kg * 8];
    }
#pragma unroll
    for (int i = 0; i < 4; ++i)
#pragma unroll
      for (int j = 0; j < 4; ++j) {
        acc[i][j] = __builtin_amdgcn_mfma_f32_16x16x32_bf16(ah[i], bh[j],
                                                            acc[i][j], 0, 0, 0);
        acc[i][j] = __builtin_amdgcn_mfma_f32_16x16x32_bf16(ah[i], bl[j],
                                                            acc[i][j], 0, 0, 0);
        acc[i][j] = __builtin_amdgcn_mfma_f32_16x16x32_bf16(al[i], bh[j],
                                                            acc[i][j], 0, 0, 0);
      }
    __syncthreads();
  }

  float bv[4];
#pragma unroll
  for (int j = 0; j < 4; ++j) bv[j] = bias[bn + wn * 64 + j * 16 + fr];
#pragma unroll
  for (int i = 0; i < 4; ++i) {
#pragma unroll
    for (int r = 0; r < 4; ++r) {
      int gr = bm + wm * 64 + i * 16 + kg * 4 + r;
      if (gr < M) {
        if (Cb) {
#pragma unroll
          for (int j = 0; j < 4; ++j)
            Cb[(size_t)gr * Nout + bn + wn * 64 + j * 16 + fr] =
                f2bf(acc[i][j][r] + bv[j]);
        } else {
#pragma unroll
          for (int j = 0; j < 4; ++j)
            Cf[(size_t)gr * Nout + bn + wn * 64 + j * 16 + fr] =
                acc[i][j][r] + bv[j];
        }
      }
    }
  }
}

__global__ __launch_bounds__(256) void attn_fused_k(
    const float* __restrict__ q, const unsigned short* __restrict__ kb,
    const unsigned short* __restrict__ vb, const int* __restrict__ rowptr,
    const int* __restrict__ csr_src, float* __restrict__ gscratch,
    float* __restrict__ out, int C, float scale, int do_elu) {
  __shared__ float qs[2048];
  __shared__ float ebuf[512];
  __shared__ int ssrc[512];
  __shared__ float wred[8];
  const int i = blockIdx.x;
  const int tid = threadIdx.x;
  const int lane = tid & 63, wid = tid >> 6;
  const int beg = rowptr[i], end = rowptr[i + 1];
  const int deg = end - beg;
  const bool sm = (deg <= 512);

  for (int c = tid * 4; c < C; c += 1024)
    *(float4*)&qs[c] = *(const float4*)(q + (size_t)i * C + c);
  if (sm)
    for (int p = tid; p < deg; p += 256) ssrc[p] = csr_src[beg + p];
  if (tid < 8) wred[tid] = (tid < 4) ? -INFINITY : 0.f;
  __syncthreads();

  if (deg > 0) {
    float wmaxv = -INFINITY;
    for (int ep = wid; ep < deg; ep += 4) {
      int s = sm ? ssrc[ep] : csr_src[beg + ep];
      const unsigned short* kr = kb + (size_t)s * C;
      float sum = 0.f;
      for (int c0 = lane * 8; c0 < C; c0 += 512) {
        uint4 pk = *(const uint4*)(kr + c0);
        float4 qa = *(const float4*)&qs[c0];
        float4 qb = *(const float4*)&qs[c0 + 4];
        const unsigned* pw = (const unsigned*)&pk;
        sum = fmaf(qa.x, __uint_as_float(pw[0] << 16), sum);
        sum = fmaf(qa.y, __uint_as_float(pw[0] & 0xffff0000u), sum);
        sum = fmaf(qa.z, __uint_as_float(pw[1] << 16), sum);
        sum = fmaf(qa.w, __uint_as_float(pw[1] & 0xffff0000u), sum);
        sum = fmaf(qb.x, __uint_as_float(pw[2] << 16), sum);
        sum = fmaf(qb.y, __uint_as_float(pw[2] & 0xffff0000u), sum);
        sum = fmaf(qb.z, __uint_as_float(pw[3] << 16), sum);
        sum = fmaf(qb.w, __uint_as_float(pw[3] & 0xffff0000u), sum);
      }
#pragma unroll
      for (int o = 32; o; o >>= 1) sum += __shfl_xor(sum, o);
      float lg = sum * scale;
      if (lane == 0) {
        if (sm) ebuf[ep] = lg; else gscratch[beg + ep] = lg;
      }
      wmaxv = fmaxf(wmaxv, lg);
    }
    if (lane == 0) wred[wid] = wmaxv;
    __syncthreads();
    float m = fmaxf(fmaxf(wred[0], wred[1]), fmaxf(wred[2], wred[3]));

    float part = 0.f;
    for (int ep = tid; ep < deg; ep += 256) {
      float lg = sm ? ebuf[ep] : gscratch[beg + ep];
      float e = expf(lg - m);
      if (sm) ebuf[ep] = e; else gscratch[beg + ep] = e;
      part += e;
    }
#pragma unroll
    for (int o = 32; o; o >>= 1) part += __shfl_xor(part, o);
    if (lane == 0) wred[4 + wid] = part;
  }
  __syncthreads();

  float total = wred[4] + wred[5] + wred[6] + wred[7];
  float denom = 1.f / (total + 1e-16f);
  const int cpt = C >> 8;
  const int col0 = tid * cpt;
  float acc[8];
#pragma unroll
  for (int j = 0; j < 8; ++j) acc[j] = 0.f;

  for (int ep = 0; ep < deg; ++ep) {
    float a = (sm ? ebuf[ep] : gscratch[beg + ep]) * denom;
    int s = sm ? ssrc[ep] : csr_src[beg + ep];
    const unsigned short* vr = vb + (size_t)s * C + col0;
    if (cpt == 4) {
      ushort4 pv = *(const ushort4*)vr;
      acc[0] = fmaf(a, bf2f(pv.x), acc[0]);
      acc[1] = fmaf(a, bf2f(pv.y), acc[1]);
      acc[2] = fmaf(a, bf2f(pv.z), acc[2]);
      acc[3] = fmaf(a, bf2f(pv.w), acc[3]);
    } else {
      uint4 pv = *(const uint4*)vr;
      const unsigned* pw = (const unsigned*)&pv;
#pragma unroll
      for (int u = 0; u < 4; ++u) {
        acc[2 * u + 0] = fmaf(a, __uint_as_float(pw[u] << 16), acc[2 * u]);
        acc[2 * u + 1] =
            fmaf(a, __uint_as_float(pw[u] & 0xffff0000u), acc[2 * u + 1]);
      }
    }
  }

  float* orow = out + (size_t)i * C + col0;
#pragma unroll
  for (int v4 = 0; v4 < 2; ++v4) {
    if (v4 * 4 < cpt) {
      float4 o = *(const float4*)(orow + v4 * 4);
      o.x += acc[v4 * 4 + 0];
      o.y += acc[v4 * 4 + 1];
      o.z += acc[v4 * 4 + 2];
      o.w += acc[v4 * 4 + 3];
      if (do_elu) {
        o.x = o.x > 0.f ? o.x : expm1f(o.x);
        o.y = o.y > 0.f ? o.y : expm1f(o.y);
        o.z = o.z > 0.f ? o.z : expm1f(o.z);
        o.w = o.w > 0.f ? o.w : expm1f(o.w);
      }
      *(float4*)(orow + v4 * 4) = o;
    }
  }
}

// ---------------------------------------------------------------------------
// CSR build
// ---------------------------------------------------------------------------
__global__ void count_deg_k(const int* __restrict__ dst, int E,
                            int* __restrict__ cnt) {
  int e = blockIdx.x * blockDim.x + threadIdx.x;
  if (e < E) atomicAdd(&cnt[dst[e]], 1);
}

__global__ void scan_k(const int* __restrict__ cnt, int* __restrict__ rowptr,
                       int N) {
  __shared__ int part[1024];
  int t = threadIdx.x;
  int per = (N + 1023) >> 10;
  int base = t * per;
  int s = 0;
  for (int i = 0; i < per; ++i) {
    int idx = base + i;
    if (idx < N) s += cnt[idx];
  }
  part[t] = s;
  __syncthreads();
  for (int off = 1; off < 1024; off <<= 1) {
    int v = (t >= off) ? part[t - off] : 0;
    __syncthreads();
    part[t] += v;
    __syncthreads();
  }
  int run = part[t] - s;
  for (int i = 0; i < per; ++i) {
    int idx = base + i;
    if (idx < N) {
      rowptr[idx] = run;
      run += cnt[idx];
    }
  }
  if (t == 1023) rowptr[N] = part[1023];
}

__global__ void scatter_csr_k(const int* __restrict__ src,
                              const int* __restrict__ dst, int E,
                              const int* __restrict__ rowptr,
                              int* __restrict__ fill,
                              int* __restrict__ csr_src) {
  int e = blockIdx.x * blockDim.x + threadIdx.x;
  if (e >= E) return;
  int d = dst[e];
  int pos = rowptr[d] + atomicAdd(&fill[d], 1);
  csr_src[pos] = src[e];
}

// ---------------------------------------------------------------------------
extern "C" void kernel_launch(void* const* d_in, const int* in_sizes, int n_in,
                              void* d_out, int out_size, void* d_ws,
                              size_t ws_size, hipStream_t stream) {
  const float* x = (const float*)d_in[0];
  const int* eidx = (const int*)d_in[1];
  const int N = in_sizes[0] / 2048;
  const int E = in_sizes[1] / 2;
  const int* srcA = eidx;
  const int* dstA = eidx + E;
  float* dout = (float*)d_out;

  char* p = (char*)d_ws;
  auto alloc = [&](size_t bytes) {
    void* r = (void*)p;
    p += (bytes + 255) & ~(size_t)255;
    return r;
  };

  // common buffers
  float* logits = (float*)alloc((size_t)E * 4);
  int* rowptr = (int*)alloc((size_t)(N + 1) * 4);
  int* cnt = (int*)alloc((size_t)N * 4);
  int* fill = (int*)alloc((size_t)N * 4);
  int* csr_src = (int*)alloc((size_t)E * 4);

  hipMemsetAsync(cnt, 0, (size_t)N * 4, stream);
  hipMemsetAsync(fill, 0, (size_t)N * 4, stream);
  count_deg_k<<<(E + 255) / 256, 256, 0, stream>>>(dstA, E, cnt);
  scan_k<<<1, 1024, 0, stream>>>(cnt, rowptr, N);
  scatter_csr_k<<<(E + 255) / 256, 256, 0, stream>>>(srcA, dstA, E, rowptr,
                                                     fill, csr_src);

  const size_t used_common = (size_t)(p - (char*)d_ws);
  const size_t szH = (size_t)N * 2048 * 2;        // bf16 [N][2048]
  const size_t szWt = (size_t)4 * 1024 * 2048 * 2;  // bf16 [4C][K] max
  const size_t need_new = used_common + 5 * szH + 2 * szWt + 8192;

  const int fi[4] = {2048, 1024, 2048, 1024};
  const int fo[4] = {1024, 2048, 1024, 2048};
  const int elu[4] = {1, 0, 1, 0};

  if (ws_size >= need_new) {
    // ---- fused path: pre-split X, one GEMM per layer, tiered precision ----
    unsigned short* Hh = (unsigned short*)alloc(szH);
    unsigned short* Hl = (unsigned short*)alloc(szH);
    unsigned short* Qb = (unsigned short*)alloc(szH);
    unsigned short* Kb = (unsigned short*)alloc(szH);
    unsigned short* Vb = (unsigned short*)alloc(szH);
    unsigned short* Wth = (unsigned short*)alloc(szWt);
    unsigned short* Wtl = (unsigned short*)alloc(szWt);

    split_k<<<(int)(((size_t)N * 2048 / 4 + 255) / 256), 256, 0, stream>>>(
        x, Hh, Hl, (size_t)N * 2048 / 4);

    for (int L = 0; L < 4; ++L) {
      const int K = fi[L], C = fo[L];
      const int b = 2 + L * 8;
      const float scale = (float)(1.0 / sqrt((double)C));
      for (int m = 0; m < 4; ++m) {
        const float* W = (const float*)d_in[b + 2 * m];
        transp_split_k<<<dim3(K / 32, C / 32), 256, 0, stream>>>(
            W, Wth + (size_t)m * C * K, Wtl + (size_t)m * C * K, K, C);
      }
      gemm_fused_k<<<dim3((N + 127) / 128, 4 * C / 128), 256, 0, stream>>>(
          Hh, Hl, Wth, Wtl, (const float*)d_in[b + 1], (const float*)d_in[b + 3],
          (const float*)d_in[b + 5], (const float*)d_in[b + 7], Qb, Kb, Vb,
          dout, N, K, C);
      attn_fused2_k<<<N, 256, 0, stream>>>(Qb, Kb, Vb, rowptr, csr_src, logits,
                                           dout, Hh, Hl, C, scale, elu[L],
                                           L < 3 ? 1 : 0);
    }
  } else {
    // ---- Round-4 proven fallback ----
    const size_t szQ = (size_t)N * 2048 * 4;
    const size_t szP1 = (size_t)N * 1024 * 4;
    float* Q = (float*)alloc(szQ);
    float* P1 = (float*)alloc(szP1);
    unsigned short* Kb = (unsigned short*)alloc(szH);
    unsigned short* Vb = (unsigned short*)alloc(szH);
    unsigned short* Wth = (unsigned short*)alloc((size_t)2048 * 1024 * 2);
    unsigned short* Wtl = (unsigned short*)alloc((size_t)2048 * 1024 * 2);
    float* P2 = dout;

    auto gemmf = [&](const float* X, int in_idx, float* outf,
                     unsigned short* outb, int K, int C) {
      const float* W = (const float*)d_in[in_idx];
      const float* bb = (const float*)d_in[in_idx + 1];
      transp_split_k<<<dim3(K / 32, C / 32), 256, 0, stream>>>(W, Wth, Wtl, K,
                                                               C);
      gemm_bf16x3_k<<<dim3((N + 127) / 128, C / 128), 256, 0, stream>>>(
          X, Wth, Wtl, bb, outf, outb, N, K, C);
    };
    auto layer = [&](const float* cur, float* outbuf, int L, int K, int C,
                     int do_elu) {
      int b = 2 + L * 8;
      float scale = (float)(1.0 / sqrt((double)C));
      gemmf(cur, b + 0, Q, nullptr, K, C);
      gemmf(cur, b + 2, nullptr, Kb, K, C);
      gemmf(cur, b + 4, nullptr, Vb, K, C);
      gemmf(cur, b + 6, outbuf, nullptr, K, C);
      attn_fused_k<<<N, 256, 0, stream>>>(Q, Kb, Vb, rowptr, csr_src, logits,
                                          outbuf, C, scale, do_elu);
    };
    layer(x, P1, 0, 2048, 1024, 1);
    layer(P1, P2, 1, 1024, 2048, 0);
    layer(P2, P1, 2, 2048, 1024, 1);
    layer(P1, dout, 3, 1024, 2048, 0);
  }
}

// Round 6
// 2717.764 us; speedup vs baseline: 3.8095x; 1.1112x over previous
//
#include <hip/hip_runtime.h>
#include <cmath>
#include <cstddef>
#include <cstdint>

typedef __attribute__((ext_vector_type(8))) short short8_t;
typedef __attribute__((ext_vector_type(4))) float f32x4;

// ---------------------------------------------------------------------------
// helpers: fp32 <-> bf16
// ---------------------------------------------------------------------------
__device__ __forceinline__ unsigned short f2bf(float f) {
  unsigned u = __float_as_uint(f);
  unsigned r = u + 0x7fffu + ((u >> 16) & 1u);
  return (unsigned short)(r >> 16);
}
__device__ __forceinline__ float bf2f(unsigned short h) {
  return __uint_as_float((unsigned)h << 16);
}

// async global -> LDS, 16B per lane (wave-uniform LDS base + lane*16)
__device__ __forceinline__ void gload16(const unsigned short* g,
                                        unsigned short* l) {
  __builtin_amdgcn_global_load_lds(
      (const __attribute__((address_space(1))) unsigned int*)g,
      (__attribute__((address_space(3))) unsigned int*)l, 16, 0, 0);
}

// ---------------------------------------------------------------------------
// split fp32 [n4*4] -> bf16 hi/lo
// ---------------------------------------------------------------------------
__global__ __launch_bounds__(256) void split_k(const float* __restrict__ in,
                                               unsigned short* __restrict__ hh,
                                               unsigned short* __restrict__ hl,
                                               size_t n4) {
  size_t i = (size_t)blockIdx.x * blockDim.x + threadIdx.x;
  if (i >= n4) return;
  float4 v = ((const float4*)in)[i];
  ushort4 h, l;
  h.x = f2bf(v.x); l.x = f2bf(v.x - bf2f(h.x));
  h.y = f2bf(v.y); l.y = f2bf(v.y - bf2f(h.y));
  h.z = f2bf(v.z); l.z = f2bf(v.z - bf2f(h.z));
  h.w = f2bf(v.w); l.w = f2bf(v.w - bf2f(h.w));
  ((ushort4*)hh)[i] = h;
  ((ushort4*)hl)[i] = l;
}

// ---------------------------------------------------------------------------
// Weight transpose + split: W[K][C] fp32 -> Th[C][K], Tl[C][K] bf16
// ---------------------------------------------------------------------------
__global__ __launch_bounds__(256) void transp_split_k(
    const float* __restrict__ W, unsigned short* __restrict__ Th,
    unsigned short* __restrict__ Tl, int K, int C) {
  __shared__ float t[32][33];
  int k0 = blockIdx.x * 32, c0 = blockIdx.y * 32;
  int tx = threadIdx.x & 31, ty = threadIdx.x >> 5;  // ty 0..7
#pragma unroll
  for (int r = 0; r < 4; ++r)
    t[ty + r * 8][tx] = W[(size_t)(k0 + ty + r * 8) * C + c0 + tx];
  __syncthreads();
#pragma unroll
  for (int r = 0; r < 4; ++r) {
    int c = ty + r * 8;
    float v = t[tx][c];  // = W[k0+tx][c0+c]
    unsigned short h = f2bf(v);
    unsigned short l = f2bf(v - bf2f(h));
    Th[(size_t)(c0 + c) * K + k0 + tx] = h;
    Tl[(size_t)(c0 + c) * K + k0 + tx] = l;
  }
}

// ---------------------------------------------------------------------------
// Fused per-layer GEMM v2: [q|k|v|s] = X @ [Wq|Wk|Wv|Ws] + bias
// X pre-split (Ah/Al bf16 [M][K]); weights Wth/Wtl [4C][K] bf16.
// q/k: 1 MFMA product; v/s: 3 products. global_load_lds staging, linear LDS,
// column-fast + bijective-XCD block remap for A-panel L2 reuse.
// ---------------------------------------------------------------------------
__global__ __launch_bounds__(256) void gemm_fused2_k(
    const unsigned short* __restrict__ Ah, const unsigned short* __restrict__ Al,
    const unsigned short* __restrict__ Wth,
    const unsigned short* __restrict__ Wtl, const float* __restrict__ bq,
    const float* __restrict__ bk, const float* __restrict__ bv,
    const float* __restrict__ bs, unsigned short* __restrict__ Qb,
    unsigned short* __restrict__ Kb, unsigned short* __restrict__ Vb,
    float* __restrict__ S, int M, int K, int C, int NX, int NY) {
  __shared__ unsigned short lds[4 * 128 * 32];  // AH | BH | AL | BL, linear
  unsigned short* AHs = lds;
  unsigned short* BHs = lds + 4096;
  unsigned short* ALs = lds + 8192;
  unsigned short* BLs = lds + 12288;

  // bijective XCD-aware remap; column (by) is the fast index so consecutive
  // blocks on one XCD share the same A-panel (L2-resident).
  const int nwg = NX * NY;
  const int bid = blockIdx.x;
  const int qq = nwg >> 3, rr = nwg & 7;
  const int xcd = bid & 7, idx = bid >> 3;
  const int wgid =
      (xcd < rr ? xcd * (qq + 1) : rr * (qq + 1) + (xcd - rr) * qq) + idx;
  const int by = wgid % NY, bx = wgid / NY;

  const int bm = bx * 128, n0 = by * 128;
  const int kind = n0 / C;  // 0=q 1=k 2=v 3=s
  const bool full = kind >= 2;
  const int tid = threadIdx.x;
  const int lane = tid & 63, w = tid >> 6;
  const int wm = w >> 1, wn = w & 1;
  const int fr = lane & 15, kg = lane >> 4;

  // staging: wave w covers tile rows [w*32, w*32+32) as two 1KB chunks
  const int srow = w * 32 + (lane >> 2);
  const int soff = (lane & 3) * 8;  // k-offset within row (8 bf16 = 16B)
  const size_t ga0 = (size_t)min(bm + srow, M - 1) * K + soff;
  const size_t ga1 = (size_t)min(bm + srow + 16, M - 1) * K + soff;
  const size_t gb0 = (size_t)(n0 + srow) * K + soff;
  const size_t gb1 = (size_t)(n0 + srow + 16) * K + soff;
  const int l0 = w * 1024;       // ushort offset of wave chunk 0
  const int l1 = w * 1024 + 512; // chunk 1

  f32x4 acc[4][4];
#pragma unroll
  for (int i = 0; i < 4; ++i)
#pragma unroll
    for (int j = 0; j < 4; ++j) acc[i][j] = (f32x4)0.f;

  for (int k0 = 0; k0 < K; k0 += 32) {
    gload16(Ah + ga0 + k0, AHs + l0);
    gload16(Ah + ga1 + k0, AHs + l1);
    gload16(Wth + gb0 + k0, BHs + l0);
    gload16(Wth + gb1 + k0, BHs + l1);
    if (full) {
      gload16(Al + ga0 + k0, ALs + l0);
      gload16(Al + ga1 + k0, ALs + l1);
      gload16(Wtl + gb0 + k0, BLs + l0);
      gload16(Wtl + gb1 + k0, BLs + l1);
    }
    __syncthreads();  // drains vmcnt before barrier (compiler-inserted)

    short8_t ah[4], bh[4];
#pragma unroll
    for (int i = 0; i < 4; ++i) {
      ah[i] = *(const short8_t*)(AHs + (wm * 64 + i * 16 + fr) * 32 + kg * 8);
      bh[i] = *(const short8_t*)(BHs + (wn * 64 + i * 16 + fr) * 32 + kg * 8);
    }
    if (full) {
      short8_t al[4], bl[4];
#pragma unroll
      for (int i = 0; i < 4; ++i) {
        al[i] = *(const short8_t*)(ALs + (wm * 64 + i * 16 + fr) * 32 + kg * 8);
        bl[i] = *(const short8_t*)(BLs + (wn * 64 + i * 16 + fr) * 32 + kg * 8);
      }
#pragma unroll
      for (int i = 0; i < 4; ++i)
#pragma unroll
        for (int j = 0; j < 4; ++j) {
          acc[i][j] = __builtin_amdgcn_mfma_f32_16x16x32_bf16(
              ah[i], bh[j], acc[i][j], 0, 0, 0);
          acc[i][j] = __builtin_amdgcn_mfma_f32_16x16x32_bf16(
              ah[i], bl[j], acc[i][j], 0, 0, 0);
          acc[i][j] = __builtin_amdgcn_mfma_f32_16x16x32_bf16(
              al[i], bh[j], acc[i][j], 0, 0, 0);
        }
    } else {
#pragma unroll
      for (int i = 0; i < 4; ++i)
#pragma unroll
        for (int j = 0; j < 4; ++j)
          acc[i][j] = __builtin_amdgcn_mfma_f32_16x16x32_bf16(
              ah[i], bh[j], acc[i][j], 0, 0, 0);
    }
    __syncthreads();
  }

  const float* bptr = (kind == 0) ? bq : (kind == 1) ? bk : (kind == 2) ? bv : bs;
  const int cbase = (n0 - kind * C) + wn * 64;
  float bvv[4];
#pragma unroll
  for (int j = 0; j < 4; ++j) bvv[j] = bptr[cbase + j * 16 + fr];

  unsigned short* ob = (kind == 0) ? Qb : (kind == 1) ? Kb : Vb;
#pragma unroll
  for (int i = 0; i < 4; ++i) {
#pragma unroll
    for (int r = 0; r < 4; ++r) {
      int gr = bm + wm * 64 + i * 16 + kg * 4 + r;
      if (gr < M) {
        if (kind == 3) {
#pragma unroll
          for (int j = 0; j < 4; ++j)
            S[(size_t)gr * C + cbase + j * 16 + fr] = acc[i][j][r] + bvv[j];
        } else {
#pragma unroll
          for (int j = 0; j < 4; ++j)
            ob[(size_t)gr * C + cbase + j * 16 + fr] =
                f2bf(acc[i][j][r] + bvv[j]);
        }
      }
    }
  }
}

// ---------------------------------------------------------------------------
// Fused attention (bf16 q/k/v). skipio holds the skip GEMM output (fp32).
// result = skip + agg, optional ELU; writeH ? split->Hh/Hl : fp32->skipio.
// ---------------------------------------------------------------------------
__global__ __launch_bounds__(256) void attn_fused2_k(
    const unsigned short* __restrict__ Qb, const unsigned short* __restrict__ Kb,
    const unsigned short* __restrict__ Vb, const int* __restrict__ rowptr,
    const int* __restrict__ csr_src, float* __restrict__ gscratch,
    float* __restrict__ skipio, unsigned short* __restrict__ Hh,
    unsigned short* __restrict__ Hl, int C, float scale, int do_elu,
    int writeH) {
  __shared__ float qs[2048];
  __shared__ float ebuf[512];
  __shared__ int ssrc[512];
  __shared__ float wred[8];
  const int i = blockIdx.x;
  const int tid = threadIdx.x;
  const int lane = tid & 63, wid = tid >> 6;
  const int beg = rowptr[i], end = rowptr[i + 1];
  const int deg = end - beg;
  const bool sm = (deg <= 512);

  for (int c = tid * 8; c < C; c += 2048) {
    uint4 pk = *(const uint4*)(Qb + (size_t)i * C + c);
    const unsigned* pw = (const unsigned*)&pk;
#pragma unroll
    for (int u = 0; u < 4; ++u) {
      qs[c + 2 * u] = __uint_as_float(pw[u] << 16);
      qs[c + 2 * u + 1] = __uint_as_float(pw[u] & 0xffff0000u);
    }
  }
  if (sm)
    for (int p = tid; p < deg; p += 256) ssrc[p] = csr_src[beg + p];
  if (tid < 8) wred[tid] = (tid < 4) ? -INFINITY : 0.f;
  __syncthreads();

  if (deg > 0) {
    float wmaxv = -INFINITY;
    for (int ep = wid; ep < deg; ep += 4) {
      int s = sm ? ssrc[ep] : csr_src[beg + ep];
      const unsigned short* kr = Kb + (size_t)s * C;
      float sum = 0.f;
      for (int c0 = lane * 8; c0 < C; c0 += 512) {
        uint4 pk = *(const uint4*)(kr + c0);
        float4 qa = *(const float4*)&qs[c0];
        float4 qb = *(const float4*)&qs[c0 + 4];
        const unsigned* pw = (const unsigned*)&pk;
        sum = fmaf(qa.x, __uint_as_float(pw[0] << 16), sum);
        sum = fmaf(qa.y, __uint_as_float(pw[0] & 0xffff0000u), sum);
        sum = fmaf(qa.z, __uint_as_float(pw[1] << 16), sum);
        sum = fmaf(qa.w, __uint_as_float(pw[1] & 0xffff0000u), sum);
        sum = fmaf(qb.x, __uint_as_float(pw[2] << 16), sum);
        sum = fmaf(qb.y, __uint_as_float(pw[2] & 0xffff0000u), sum);
        sum = fmaf(qb.z, __uint_as_float(pw[3] << 16), sum);
        sum = fmaf(qb.w, __uint_as_float(pw[3] & 0xffff0000u), sum);
      }
#pragma unroll
      for (int o = 32; o; o >>= 1) sum += __shfl_xor(sum, o);
      float lg = sum * scale;
      if (lane == 0) {
        if (sm) ebuf[ep] = lg; else gscratch[beg + ep] = lg;
      }
      wmaxv = fmaxf(wmaxv, lg);
    }
    if (lane == 0) wred[wid] = wmaxv;
    __syncthreads();
    float m = fmaxf(fmaxf(wred[0], wred[1]), fmaxf(wred[2], wred[3]));

    float part = 0.f;
    for (int ep = tid; ep < deg; ep += 256) {
      float lg = sm ? ebuf[ep] : gscratch[beg + ep];
      float e = expf(lg - m);
      if (sm) ebuf[ep] = e; else gscratch[beg + ep] = e;
      part += e;
    }
#pragma unroll
    for (int o = 32; o; o >>= 1) part += __shfl_xor(part, o);
    if (lane == 0) wred[4 + wid] = part;
  }
  __syncthreads();

  float total = wred[4] + wred[5] + wred[6] + wred[7];
  float denom = 1.f / (total + 1e-16f);
  const int cpt = C >> 8;  // 4 or 8 cols per thread
  const int col0 = tid * cpt;
  float acc[8];
#pragma unroll
  for (int j = 0; j < 8; ++j) acc[j] = 0.f;

  for (int ep = 0; ep < deg; ++ep) {
    float a = (sm ? ebuf[ep] : gscratch[beg + ep]) * denom;
    int s = sm ? ssrc[ep] : csr_src[beg + ep];
    const unsigned short* vr = Vb + (size_t)s * C + col0;
    if (cpt == 4) {
      ushort4 pv = *(const ushort4*)vr;
      acc[0] = fmaf(a, bf2f(pv.x), acc[0]);
      acc[1] = fmaf(a, bf2f(pv.y), acc[1]);
      acc[2] = fmaf(a, bf2f(pv.z), acc[2]);
      acc[3] = fmaf(a, bf2f(pv.w), acc[3]);
    } else {
      uint4 pv = *(const uint4*)vr;
      const unsigned* pw = (const unsigned*)&pv;
#pragma unroll
      for (int u = 0; u < 4; ++u) {
        acc[2 * u + 0] = fmaf(a, __uint_as_float(pw[u] << 16), acc[2 * u]);
        acc[2 * u + 1] =
            fmaf(a, __uint_as_float(pw[u] & 0xffff0000u), acc[2 * u + 1]);
      }
    }
  }

  float* srow = skipio + (size_t)i * C + col0;
#pragma unroll
  for (int v4 = 0; v4 < 2; ++v4) {
    if (v4 * 4 < cpt) {
      float4 o = *(const float4*)(srow + v4 * 4);
      o.x += acc[v4 * 4 + 0];
      o.y += acc[v4 * 4 + 1];
      o.z += acc[v4 * 4 + 2];
      o.w += acc[v4 * 4 + 3];
      if (do_elu) {
        o.x = o.x > 0.f ? o.x : expm1f(o.x);
        o.y = o.y > 0.f ? o.y : expm1f(o.y);
        o.z = o.z > 0.f ? o.z : expm1f(o.z);
        o.w = o.w > 0.f ? o.w : expm1f(o.w);
      }
      if (writeH) {
        ushort4 h, l;
        h.x = f2bf(o.x); l.x = f2bf(o.x - bf2f(h.x));
        h.y = f2bf(o.y); l.y = f2bf(o.y - bf2f(h.y));
        h.z = f2bf(o.z); l.z = f2bf(o.z - bf2f(h.z));
        h.w = f2bf(o.w); l.w = f2bf(o.w - bf2f(h.w));
        *(ushort4*)(Hh + (size_t)i * C + col0 + v4 * 4) = h;
        *(ushort4*)(Hl + (size_t)i * C + col0 + v4 * 4) = l;
      } else {
        *(float4*)(srow + v4 * 4) = o;
      }
    }
  }
}

// ---------------------------------------------------------------------------
// Round-4 fallback kernels (used only if ws is too small for the main path)
// ---------------------------------------------------------------------------
__global__ __launch_bounds__(256) void gemm_bf16x3_k(
    const float* __restrict__ A, const unsigned short* __restrict__ Bh,
    const unsigned short* __restrict__ Bl, const float* __restrict__ bias,
    float* __restrict__ Cf, unsigned short* __restrict__ Cb, int M, int K,
    int Nout) {
  __shared__ unsigned short Ahs[128][40], Als[128][40];
  __shared__ unsigned short Bhs[128][40], Bls[128][40];
  const int tid = threadIdx.x;
  const int bm = blockIdx.x * 128, bn = blockIdx.y * 128;
  const int lane = tid & 63, w = tid >> 6;
  const int wm = w >> 1, wn = w & 1;
  const int fr = lane & 15, kg = lane >> 4;

  f32x4 acc[4][4];
#pragma unroll
  for (int i = 0; i < 4; ++i)
#pragma unroll
    for (int j = 0; j < 4; ++j) acc[i][j] = (f32x4)0.f;

  for (int k0 = 0; k0 < K; k0 += 32) {
#pragma unroll
    for (int u = 0; u < 4; ++u) {
      int c = u * 256 + tid;
      int row = c >> 3, kc = (c & 7) * 4;
      int gr = min(bm + row, M - 1);
      float4 av = *(const float4*)(A + (size_t)gr * K + k0 + kc);
      ushort4 h, l;
      h.x = f2bf(av.x); l.x = f2bf(av.x - bf2f(h.x));
      h.y = f2bf(av.y); l.y = f2bf(av.y - bf2f(h.y));
      h.z = f2bf(av.z); l.z = f2bf(av.z - bf2f(h.z));
      h.w = f2bf(av.w); l.w = f2bf(av.w - bf2f(h.w));
      *(ushort4*)&Ahs[row][kc] = h;
      *(ushort4*)&Als[row][kc] = l;
    }
#pragma unroll
    for (int u = 0; u < 2; ++u) {
      int c = u * 256 + tid;
      int row = c >> 2, kc = (c & 3) * 8;
      *(uint4*)&Bhs[row][kc] =
          *(const uint4*)(Bh + (size_t)(bn + row) * K + k0 + kc);
      *(uint4*)&Bls[row][kc] =
          *(const uint4*)(Bl + (size_t)(bn + row) * K + k0 + kc);
    }
    __syncthreads();

    short8_t ah[4], al[4], bh[4], bl[4];
#pragma unroll
    for (int i = 0; i < 4; ++i) {
      ah[i] = *(const short8_t*)&Ahs[wm * 64 + i * 16 + fr][kg * 8];
      al[i] = *(const short8_t*)&Als[wm * 64 + i * 16 + fr][kg * 8];
      bh[i] = *(const short8_t*)&Bhs[wn * 64 + i * 16 + fr][kg * 8];
      bl[i] = *(const short8_t*)&Bls[wn * 64 + i * 16 + fr][kg * 8];
    }
#pragma unroll
    for (int i = 0; i < 4; ++i)
#pragma unroll
      for (int j = 0; j < 4; ++j) {
        acc[i][j] = __builtin_amdgcn_mfma_f32_16x16x32_bf16(ah[i], bh[j],
                                                            acc[i][j], 0, 0, 0);
        acc[i][j] = __builtin_amdgcn_mfma_f32_16x16x32_bf16(ah[i], bl[j],
                                                            acc[i][j], 0, 0, 0);
        acc[i][j] = __builtin_amdgcn_mfma_f32_16x16x32_bf16(al[i], bh[j],
                                                            acc[i][j], 0, 0, 0);
      }
    __syncthreads();
  }

  float bv[4];
#pragma unroll
  for (int j = 0; j < 4; ++j) bv[j] = bias[bn + wn * 64 + j * 16 + fr];
#pragma unroll
  for (int i = 0; i < 4; ++i) {
#pragma unroll
    for (int r = 0; r < 4; ++r) {
      int gr = bm + wm * 64 + i * 16 + kg * 4 + r;
      if (gr < M) {
        if (Cb) {
#pragma unroll
          for (int j = 0; j < 4; ++j)
            Cb[(size_t)gr * Nout + bn + wn * 64 + j * 16 + fr] =
                f2bf(acc[i][j][r] + bv[j]);
        } else {
#pragma unroll
          for (int j = 0; j < 4; ++j)
            Cf[(size_t)gr * Nout + bn + wn * 64 + j * 16 + fr] =
                acc[i][j][r] + bv[j];
        }
      }
    }
  }
}

__global__ __launch_bounds__(256) void attn_fused_k(
    const float* __restrict__ q, const unsigned short* __restrict__ kb,
    const unsigned short* __restrict__ vb, const int* __restrict__ rowptr,
    const int* __restrict__ csr_src, float* __restrict__ gscratch,
    float* __restrict__ out, int C, float scale, int do_elu) {
  __shared__ float qs[2048];
  __shared__ float ebuf[512];
  __shared__ int ssrc[512];
  __shared__ float wred[8];
  const int i = blockIdx.x;
  const int tid = threadIdx.x;
  const int lane = tid & 63, wid = tid >> 6;
  const int beg = rowptr[i], end = rowptr[i + 1];
  const int deg = end - beg;
  const bool sm = (deg <= 512);

  for (int c = tid * 4; c < C; c += 1024)
    *(float4*)&qs[c] = *(const float4*)(q + (size_t)i * C + c);
  if (sm)
    for (int p = tid; p < deg; p += 256) ssrc[p] = csr_src[beg + p];
  if (tid < 8) wred[tid] = (tid < 4) ? -INFINITY : 0.f;
  __syncthreads();

  if (deg > 0) {
    float wmaxv = -INFINITY;
    for (int ep = wid; ep < deg; ep += 4) {
      int s = sm ? ssrc[ep] : csr_src[beg + ep];
      const unsigned short* kr = kb + (size_t)s * C;
      float sum = 0.f;
      for (int c0 = lane * 8; c0 < C; c0 += 512) {
        uint4 pk = *(const uint4*)(kr + c0);
        float4 qa = *(const float4*)&qs[c0];
        float4 qb = *(const float4*)&qs[c0 + 4];
        const unsigned* pw = (const unsigned*)&pk;
        sum = fmaf(qa.x, __uint_as_float(pw[0] << 16), sum);
        sum = fmaf(qa.y, __uint_as_float(pw[0] & 0xffff0000u), sum);
        sum = fmaf(qa.z, __uint_as_float(pw[1] << 16), sum);
        sum = fmaf(qa.w, __uint_as_float(pw[1] & 0xffff0000u), sum);
        sum = fmaf(qb.x, __uint_as_float(pw[2] << 16), sum);
        sum = fmaf(qb.y, __uint_as_float(pw[2] & 0xffff0000u), sum);
        sum = fmaf(qb.z, __uint_as_float(pw[3] << 16), sum);
        sum = fmaf(qb.w, __uint_as_float(pw[3] & 0xffff0000u), sum);
      }
#pragma unroll
      for (int o = 32; o; o >>= 1) sum += __shfl_xor(sum, o);
      float lg = sum * scale;
      if (lane == 0) {
        if (sm) ebuf[ep] = lg; else gscratch[beg + ep] = lg;
      }
      wmaxv = fmaxf(wmaxv, lg);
    }
    if (lane == 0) wred[wid] = wmaxv;
    __syncthreads();
    float m = fmaxf(fmaxf(wred[0], wred[1]), fmaxf(wred[2], wred[3]));

    float part = 0.f;
    for (int ep = tid; ep < deg; ep += 256) {
      float lg = sm ? ebuf[ep] : gscratch[beg + ep];
      float e = expf(lg - m);
      if (sm) ebuf[ep] = e; else gscratch[beg + ep] = e;
      part += e;
    }
#pragma unroll
    for (int o = 32; o; o >>= 1) part += __shfl_xor(part, o);
    if (lane == 0) wred[4 + wid] = part;
  }
  __syncthreads();

  float total = wred[4] + wred[5] + wred[6] + wred[7];
  float denom = 1.f / (total + 1e-16f);
  const int cpt = C >> 8;
  const int col0 = tid * cpt;
  float acc[8];
#pragma unroll
  for (int j = 0; j < 8; ++j) acc[j] = 0.f;

  for (int ep = 0; ep < deg; ++ep) {
    float a = (sm ? ebuf[ep] : gscratch[beg + ep]) * denom;
    int s = sm ? ssrc[ep] : csr_src[beg + ep];
    const unsigned short* vr = vb + (size_t)s * C + col0;
    if (cpt == 4) {
      ushort4 pv = *(const ushort4*)vr;
      acc[0] = fmaf(a, bf2f(pv.x), acc[0]);
      acc[1] = fmaf(a, bf2f(pv.y), acc[1]);
      acc[2] = fmaf(a, bf2f(pv.z), acc[2]);
      acc[3] = fmaf(a, bf2f(pv.w), acc[3]);
    } else {
      uint4 pv = *(const uint4*)vr;
      const unsigned* pw = (const unsigned*)&pv;
#pragma unroll
      for (int u = 0; u < 4; ++u) {
        acc[2 * u + 0] = fmaf(a, __uint_as_float(pw[u] << 16), acc[2 * u]);
        acc[2 * u + 1] =
            fmaf(a, __uint_as_float(pw[u] & 0xffff0000u), acc[2 * u + 1]);
      }
    }
  }

  float* orow = out + (size_t)i * C + col0;
#pragma unroll
  for (int v4 = 0; v4 < 2; ++v4) {
    if (v4 * 4 < cpt) {
      float4 o = *(const float4*)(orow + v4 * 4);
      o.x += acc[v4 * 4 + 0];
      o.y += acc[v4 * 4 + 1];
      o.z += acc[v4 * 4 + 2];
      o.w += acc[v4 * 4 + 3];
      if (do_elu) {
        o.x = o.x > 0.f ? o.x : expm1f(o.x);
        o.y = o.y > 0.f ? o.y : expm1f(o.y);
        o.z = o.z > 0.f ? o.z : expm1f(o.z);
        o.w = o.w > 0.f ? o.w : expm1f(o.w);
      }
      *(float4*)(orow + v4 * 4) = o;
    }
  }
}

// ---------------------------------------------------------------------------
// CSR build
// ---------------------------------------------------------------------------
__global__ void count_deg_k(const int* __restrict__ dst, int E,
                            int* __restrict__ cnt) {
  int e = blockIdx.x * blockDim.x + threadIdx.x;
  if (e < E) atomicAdd(&cnt[dst[e]], 1);
}

__global__ void scan_k(const int* __restrict__ cnt, int* __restrict__ rowptr,
                       int N) {
  __shared__ int part[1024];
  int t = threadIdx.x;
  int per = (N + 1023) >> 10;
  int base = t * per;
  int s = 0;
  for (int i = 0; i < per; ++i) {
    int idx = base + i;
    if (idx < N) s += cnt[idx];
  }
  part[t] = s;
  __syncthreads();
  for (int off = 1; off < 1024; off <<= 1) {
    int v = (t >= off) ? part[t - off] : 0;
    __syncthreads();
    part[t] += v;
    __syncthreads();
  }
  int run = part[t] - s;
  for (int i = 0; i < per; ++i) {
    int idx = base + i;
    if (idx < N) {
      rowptr[idx] = run;
      run += cnt[idx];
    }
  }
  if (t == 1023) rowptr[N] = part[1023];
}

__global__ void scatter_csr_k(const int* __restrict__ src,
                              const int* __restrict__ dst, int E,
                              const int* __restrict__ rowptr,
                              int* __restrict__ fill,
                              int* __restrict__ csr_src) {
  int e = blockIdx.x * blockDim.x + threadIdx.x;
  if (e >= E) return;
  int d = dst[e];
  int pos = rowptr[d] + atomicAdd(&fill[d], 1);
  csr_src[pos] = src[e];
}

// ---------------------------------------------------------------------------
extern "C" void kernel_launch(void* const* d_in, const int* in_sizes, int n_in,
                              void* d_out, int out_size, void* d_ws,
                              size_t ws_size, hipStream_t stream) {
  const float* x = (const float*)d_in[0];
  const int* eidx = (const int*)d_in[1];
  const int N = in_sizes[0] / 2048;
  const int E = in_sizes[1] / 2;
  const int* srcA = eidx;
  const int* dstA = eidx + E;
  float* dout = (float*)d_out;

  char* p = (char*)d_ws;
  auto alloc = [&](size_t bytes) {
    void* r = (void*)p;
    p += (bytes + 255) & ~(size_t)255;
    return r;
  };

  // common buffers
  float* logits = (float*)alloc((size_t)E * 4);
  int* rowptr = (int*)alloc((size_t)(N + 1) * 4);
  int* cnt = (int*)alloc((size_t)N * 4);
  int* fill = (int*)alloc((size_t)N * 4);
  int* csr_src = (int*)alloc((size_t)E * 4);

  hipMemsetAsync(cnt, 0, (size_t)N * 4, stream);
  hipMemsetAsync(fill, 0, (size_t)N * 4, stream);
  count_deg_k<<<(E + 255) / 256, 256, 0, stream>>>(dstA, E, cnt);
  scan_k<<<1, 1024, 0, stream>>>(cnt, rowptr, N);
  scatter_csr_k<<<(E + 255) / 256, 256, 0, stream>>>(srcA, dstA, E, rowptr,
                                                     fill, csr_src);

  const size_t used_common = (size_t)(p - (char*)d_ws);
  const size_t szH = (size_t)N * 2048 * 2;          // bf16 [N][2048]
  const size_t szWt = (size_t)4 * 1024 * 2048 * 2;  // bf16 [4C][K] max
  const size_t need_new = used_common + 5 * szH + 2 * szWt + 8192;

  const int fi[4] = {2048, 1024, 2048, 1024};
  const int fo[4] = {1024, 2048, 1024, 2048};
  const int elu[4] = {1, 0, 1, 0};

  if (ws_size >= need_new) {
    // ---- main path: pre-split X, one fused GEMM per layer, gload_lds ----
    unsigned short* Hh = (unsigned short*)alloc(szH);
    unsigned short* Hl = (unsigned short*)alloc(szH);
    unsigned short* Qb = (unsigned short*)alloc(szH);
    unsigned short* Kb = (unsigned short*)alloc(szH);
    unsigned short* Vb = (unsigned short*)alloc(szH);
    unsigned short* Wth = (unsigned short*)alloc(szWt);
    unsigned short* Wtl = (unsigned short*)alloc(szWt);

    split_k<<<(int)(((size_t)N * 2048 / 4 + 255) / 256), 256, 0, stream>>>(
        x, Hh, Hl, (size_t)N * 2048 / 4);

    for (int L = 0; L < 4; ++L) {
      const int K = fi[L], C = fo[L];
      const int b = 2 + L * 8;
      const float scale = (float)(1.0 / sqrt((double)C));
      for (int m = 0; m < 4; ++m) {
        const float* W = (const float*)d_in[b + 2 * m];
        transp_split_k<<<dim3(K / 32, C / 32), 256, 0, stream>>>(
            W, Wth + (size_t)m * C * K, Wtl + (size_t)m * C * K, K, C);
      }
      const int NX = (N + 127) / 128, NY = 4 * C / 128;
      gemm_fused2_k<<<NX * NY, 256, 0, stream>>>(
          Hh, Hl, Wth, Wtl, (const float*)d_in[b + 1],
          (const float*)d_in[b + 3], (const float*)d_in[b + 5],
          (const float*)d_in[b + 7], Qb, Kb, Vb, dout, N, K, C, NX, NY);
      attn_fused2_k<<<N, 256, 0, stream>>>(Qb, Kb, Vb, rowptr, csr_src, logits,
                                           dout, Hh, Hl, C, scale, elu[L],
                                           L < 3 ? 1 : 0);
    }
  } else {
    // ---- Round-4 proven fallback ----
    const size_t szQ = (size_t)N * 2048 * 4;
    const size_t szP1 = (size_t)N * 1024 * 4;
    float* Q = (float*)alloc(szQ);
    float* P1 = (float*)alloc(szP1);
    unsigned short* Kb = (unsigned short*)alloc(szH);
    unsigned short* Vb = (unsigned short*)alloc(szH);
    unsigned short* Wth = (unsigned short*)alloc((size_t)2048 * 1024 * 2);
    unsigned short* Wtl = (unsigned short*)alloc((size_t)2048 * 1024 * 2);
    float* P2 = dout;

    auto gemmf = [&](const float* X, int in_idx, float* outf,
                     unsigned short* outb, int K, int C) {
      const float* W = (const float*)d_in[in_idx];
      const float* bb = (const float*)d_in[in_idx + 1];
      transp_split_k<<<dim3(K / 32, C / 32), 256, 0, stream>>>(W, Wth, Wtl, K,
                                                               C);
      gemm_bf16x3_k<<<dim3((N + 127) / 128, C / 128), 256, 0, stream>>>(
          X, Wth, Wtl, bb, outf, outb, N, K, C);
    };
    auto layer = [&](const float* cur, float* outbuf, int L, int K, int C,
                     int do_elu) {
      int b = 2 + L * 8;
      float scale = (float)(1.0 / sqrt((double)C));
      gemmf(cur, b + 0, Q, nullptr, K, C);
      gemmf(cur, b + 2, nullptr, Kb, K, C);
      gemmf(cur, b + 4, nullptr, Vb, K, C);
      gemmf(cur, b + 6, outbuf, nullptr, K, C);
      attn_fused_k<<<N, 256, 0, stream>>>(Q, Kb, Vb, rowptr, csr_src, logits,
                                          outbuf, C, scale, do_elu);
    };
    layer(x, P1, 0, 2048, 1024, 1);
    layer(P1, P2, 1, 1024, 2048, 0);
    layer(P2, P1, 2, 2048, 1024, 1);
    layer(P1, dout, 3, 1024, 2048, 0);
  }
}

// Round 7
// 2190.945 us; speedup vs baseline: 4.7254x; 1.2405x over previous
//
#include <hip/hip_runtime.h>
#include <cmath>
#include <cstddef>
#include <cstdint>

typedef __attribute__((ext_vector_type(8))) short short8_t;
typedef __attribute__((ext_vector_type(4))) float f32x4;

// ---------------------------------------------------------------------------
// helpers: fp32 <-> bf16
// ---------------------------------------------------------------------------
__device__ __forceinline__ unsigned short f2bf(float f) {
  unsigned u = __float_as_uint(f);
  unsigned r = u + 0x7fffu + ((u >> 16) & 1u);
  return (unsigned short)(r >> 16);
}
__device__ __forceinline__ float bf2f(unsigned short h) {
  return __uint_as_float((unsigned)h << 16);
}

// async global -> LDS, 16B per lane (wave-uniform LDS base + lane*16)
__device__ __forceinline__ void gload16(const unsigned short* g,
                                        unsigned short* l) {
  __builtin_amdgcn_global_load_lds(
      (const __attribute__((address_space(1))) unsigned int*)g,
      (__attribute__((address_space(3))) unsigned int*)l, 16, 0, 0);
}

// ---------------------------------------------------------------------------
// split fp32 [n4*4] -> bf16 hi/lo
// ---------------------------------------------------------------------------
__global__ __launch_bounds__(256) void split_k(const float* __restrict__ in,
                                               unsigned short* __restrict__ hh,
                                               unsigned short* __restrict__ hl,
                                               size_t n4) {
  size_t i = (size_t)blockIdx.x * blockDim.x + threadIdx.x;
  if (i >= n4) return;
  float4 v = ((const float4*)in)[i];
  ushort4 h, l;
  h.x = f2bf(v.x); l.x = f2bf(v.x - bf2f(h.x));
  h.y = f2bf(v.y); l.y = f2bf(v.y - bf2f(h.y));
  h.z = f2bf(v.z); l.z = f2bf(v.z - bf2f(h.z));
  h.w = f2bf(v.w); l.w = f2bf(v.w - bf2f(h.w));
  ((ushort4*)hh)[i] = h;
  ((ushort4*)hl)[i] = l;
}

// ---------------------------------------------------------------------------
// Weight transpose + split: W[K][C] fp32 -> Th[C][K], Tl[C][K] bf16
// ---------------------------------------------------------------------------
__global__ __launch_bounds__(256) void transp_split_k(
    const float* __restrict__ W, unsigned short* __restrict__ Th,
    unsigned short* __restrict__ Tl, int K, int C) {
  __shared__ float t[32][33];
  int k0 = blockIdx.x * 32, c0 = blockIdx.y * 32;
  int tx = threadIdx.x & 31, ty = threadIdx.x >> 5;  // ty 0..7
#pragma unroll
  for (int r = 0; r < 4; ++r)
    t[ty + r * 8][tx] = W[(size_t)(k0 + ty + r * 8) * C + c0 + tx];
  __syncthreads();
#pragma unroll
  for (int r = 0; r < 4; ++r) {
    int c = ty + r * 8;
    float v = t[tx][c];  // = W[k0+tx][c0+c]
    unsigned short h = f2bf(v);
    unsigned short l = f2bf(v - bf2f(h));
    Th[(size_t)(c0 + c) * K + k0 + tx] = h;
    Tl[(size_t)(c0 + c) * K + k0 + tx] = l;
  }
}

// ---------------------------------------------------------------------------
// q/k GEMM (bf16, 1 product): [q|k] = Xh @ Wt2^T + bias, bf16 out.
// Wt2 = rows [0,2C) of transposed weights (q then k). Double-buffered LDS,
// STAGE-before-compute, one barrier per K-step.
// ---------------------------------------------------------------------------
__global__ __launch_bounds__(256) void gemm_qk_k(
    const unsigned short* __restrict__ Ah, const unsigned short* __restrict__ Wt2,
    const float* __restrict__ bq, const float* __restrict__ bk,
    unsigned short* __restrict__ Qb, unsigned short* __restrict__ Kb, int M,
    int K, int C, int NX, int NY2) {
  __shared__ unsigned short lds[2][2][4096];  // [buf][A|B][128*32]

  const int nwg = NX * NY2;
  const int bid = blockIdx.x;
  const int qq = nwg >> 3, rr = nwg & 7;
  const int xcd = bid & 7, idx = bid >> 3;
  const int wgid =
      (xcd < rr ? xcd * (qq + 1) : rr * (qq + 1) + (xcd - rr) * qq) + idx;
  const int by = wgid % NY2, bx = wgid / NY2;

  const int bm = bx * 128, n0 = by * 128;
  const int kind = (n0 >= C);  // 0=q 1=k
  const int tid = threadIdx.x;
  const int lane = tid & 63, w = tid >> 6;
  const int wm = w >> 1, wn = w & 1;
  const int fr = lane & 15, kg = lane >> 4;

  const int srow = w * 32 + (lane >> 2);
  const int soff = (lane & 3) * 8;
  const size_t ga0 = (size_t)min(bm + srow, M - 1) * K + soff;
  const size_t ga1 = (size_t)min(bm + srow + 16, M - 1) * K + soff;
  const size_t gb0 = (size_t)(n0 + srow) * K + soff;
  const size_t gb1 = (size_t)(n0 + srow + 16) * K + soff;
  const int l0 = w * 1024, l1 = w * 1024 + 512;

  f32x4 acc[4][4];
#pragma unroll
  for (int i = 0; i < 4; ++i)
#pragma unroll
    for (int j = 0; j < 4; ++j) acc[i][j] = (f32x4)0.f;

  // prologue stage
  gload16(Ah + ga0, &lds[0][0][l0]);
  gload16(Ah + ga1, &lds[0][0][l1]);
  gload16(Wt2 + gb0, &lds[0][1][l0]);
  gload16(Wt2 + gb1, &lds[0][1][l1]);
  __syncthreads();

  const int T = K / 32;
  for (int t = 0; t < T; ++t) {
    const int cur = t & 1;
    if (t + 1 < T) {
      const int ko = (t + 1) * 32;
      gload16(Ah + ga0 + ko, &lds[cur ^ 1][0][l0]);
      gload16(Ah + ga1 + ko, &lds[cur ^ 1][0][l1]);
      gload16(Wt2 + gb0 + ko, &lds[cur ^ 1][1][l0]);
      gload16(Wt2 + gb1 + ko, &lds[cur ^ 1][1][l1]);
    }
    const unsigned short* As = lds[cur][0];
    const unsigned short* Bs = lds[cur][1];
    short8_t ah[4], bh[4];
#pragma unroll
    for (int i = 0; i < 4; ++i) {
      ah[i] = *(const short8_t*)(As + (wm * 64 + i * 16 + fr) * 32 + kg * 8);
      bh[i] = *(const short8_t*)(Bs + (wn * 64 + i * 16 + fr) * 32 + kg * 8);
    }
#pragma unroll
    for (int i = 0; i < 4; ++i)
#pragma unroll
      for (int j = 0; j < 4; ++j)
        acc[i][j] = __builtin_amdgcn_mfma_f32_16x16x32_bf16(ah[i], bh[j],
                                                            acc[i][j], 0, 0, 0);
    __syncthreads();
  }

  const float* bptr = kind ? bk : bq;
  const int cbase = (n0 - kind * C) + wn * 64;
  float bvv[4];
#pragma unroll
  for (int j = 0; j < 4; ++j) bvv[j] = bptr[cbase + j * 16 + fr];
  unsigned short* ob = kind ? Kb : Qb;
#pragma unroll
  for (int i = 0; i < 4; ++i) {
#pragma unroll
    for (int r = 0; r < 4; ++r) {
      int gr = bm + wm * 64 + i * 16 + kg * 4 + r;
      if (gr < M) {
#pragma unroll
        for (int j = 0; j < 4; ++j)
          ob[(size_t)gr * C + cbase + j * 16 + fr] = f2bf(acc[i][j][r] + bvv[j]);
      }
    }
  }
}

// ---------------------------------------------------------------------------
// v/s GEMM (bf16x3): [v|s] = X @ Wt2^T + bias. Wt2h/Wt2l = rows [2C,4C).
// v -> bf16 Vb, s -> fp32 S. Double-buffered, one barrier per K-step.
// ---------------------------------------------------------------------------
__global__ __launch_bounds__(256) void gemm_vs_k(
    const unsigned short* __restrict__ Ah, const unsigned short* __restrict__ Al,
    const unsigned short* __restrict__ Bh2,
    const unsigned short* __restrict__ Bl2, const float* __restrict__ bv,
    const float* __restrict__ bs, unsigned short* __restrict__ Vb,
    float* __restrict__ S, int M, int K, int C, int NX, int NY2) {
  __shared__ unsigned short lds[2][4][4096];  // [buf][AH|BH|AL|BL]

  const int nwg = NX * NY2;
  const int bid = blockIdx.x;
  const int qq = nwg >> 3, rr = nwg & 7;
  const int xcd = bid & 7, idx = bid >> 3;
  const int wgid =
      (xcd < rr ? xcd * (qq + 1) : rr * (qq + 1) + (xcd - rr) * qq) + idx;
  const int by = wgid % NY2, bx = wgid / NY2;

  const int bm = bx * 128, n0 = by * 128;
  const int kind = (n0 >= C);  // 0=v 1=s
  const int tid = threadIdx.x;
  const int lane = tid & 63, w = tid >> 6;
  const int wm = w >> 1, wn = w & 1;
  const int fr = lane & 15, kg = lane >> 4;

  const int srow = w * 32 + (lane >> 2);
  const int soff = (lane & 3) * 8;
  const size_t ga0 = (size_t)min(bm + srow, M - 1) * K + soff;
  const size_t ga1 = (size_t)min(bm + srow + 16, M - 1) * K + soff;
  const size_t gb0 = (size_t)(n0 + srow) * K + soff;
  const size_t gb1 = (size_t)(n0 + srow + 16) * K + soff;
  const int l0 = w * 1024, l1 = w * 1024 + 512;

  f32x4 acc[4][4];
#pragma unroll
  for (int i = 0; i < 4; ++i)
#pragma unroll
    for (int j = 0; j < 4; ++j) acc[i][j] = (f32x4)0.f;

  // prologue stage
  gload16(Ah + ga0, &lds[0][0][l0]);
  gload16(Ah + ga1, &lds[0][0][l1]);
  gload16(Bh2 + gb0, &lds[0][1][l0]);
  gload16(Bh2 + gb1, &lds[0][1][l1]);
  gload16(Al + ga0, &lds[0][2][l0]);
  gload16(Al + ga1, &lds[0][2][l1]);
  gload16(Bl2 + gb0, &lds[0][3][l0]);
  gload16(Bl2 + gb1, &lds[0][3][l1]);
  __syncthreads();

  const int T = K / 32;
  for (int t = 0; t < T; ++t) {
    const int cur = t & 1;
    if (t + 1 < T) {
      const int ko = (t + 1) * 32;
      gload16(Ah + ga0 + ko, &lds[cur ^ 1][0][l0]);
      gload16(Ah + ga1 + ko, &lds[cur ^ 1][0][l1]);
      gload16(Bh2 + gb0 + ko, &lds[cur ^ 1][1][l0]);
      gload16(Bh2 + gb1 + ko, &lds[cur ^ 1][1][l1]);
      gload16(Al + ga0 + ko, &lds[cur ^ 1][2][l0]);
      gload16(Al + ga1 + ko, &lds[cur ^ 1][2][l1]);
      gload16(Bl2 + gb0 + ko, &lds[cur ^ 1][3][l0]);
      gload16(Bl2 + gb1 + ko, &lds[cur ^ 1][3][l1]);
    }
    const unsigned short* AHs = lds[cur][0];
    const unsigned short* BHs = lds[cur][1];
    const unsigned short* ALs = lds[cur][2];
    const unsigned short* BLs = lds[cur][3];
    short8_t ah[4], bh[4], al[4], bl[4];
#pragma unroll
    for (int i = 0; i < 4; ++i) {
      ah[i] = *(const short8_t*)(AHs + (wm * 64 + i * 16 + fr) * 32 + kg * 8);
      bh[i] = *(const short8_t*)(BHs + (wn * 64 + i * 16 + fr) * 32 + kg * 8);
      al[i] = *(const short8_t*)(ALs + (wm * 64 + i * 16 + fr) * 32 + kg * 8);
      bl[i] = *(const short8_t*)(BLs + (wn * 64 + i * 16 + fr) * 32 + kg * 8);
    }
#pragma unroll
    for (int i = 0; i < 4; ++i)
#pragma unroll
      for (int j = 0; j < 4; ++j) {
        acc[i][j] = __builtin_amdgcn_mfma_f32_16x16x32_bf16(ah[i], bh[j],
                                                            acc[i][j], 0, 0, 0);
        acc[i][j] = __builtin_amdgcn_mfma_f32_16x16x32_bf16(ah[i], bl[j],
                                                            acc[i][j], 0, 0, 0);
        acc[i][j] = __builtin_amdgcn_mfma_f32_16x16x32_bf16(al[i], bh[j],
                                                            acc[i][j], 0, 0, 0);
      }
    __syncthreads();
  }

  const float* bptr = kind ? bs : bv;
  const int cbase = (n0 - kind * C) + wn * 64;
  float bvv[4];
#pragma unroll
  for (int j = 0; j < 4; ++j) bvv[j] = bptr[cbase + j * 16 + fr];
#pragma unroll
  for (int i = 0; i < 4; ++i) {
#pragma unroll
    for (int r = 0; r < 4; ++r) {
      int gr = bm + wm * 64 + i * 16 + kg * 4 + r;
      if (gr < M) {
        if (kind) {
#pragma unroll
          for (int j = 0; j < 4; ++j)
            S[(size_t)gr * C + cbase + j * 16 + fr] = acc[i][j][r] + bvv[j];
        } else {
#pragma unroll
          for (int j = 0; j < 4; ++j)
            Vb[(size_t)gr * C + cbase + j * 16 + fr] =
                f2bf(acc[i][j][r] + bvv[j]);
        }
      }
    }
  }
}

// ---------------------------------------------------------------------------
// Fused attention (bf16 q/k/v). skipio holds the skip GEMM output (fp32).
// result = skip + agg, optional ELU; writeH ? split->Hh/Hl : fp32->skipio.
// ---------------------------------------------------------------------------
__global__ __launch_bounds__(256) void attn_fused2_k(
    const unsigned short* __restrict__ Qb, const unsigned short* __restrict__ Kb,
    const unsigned short* __restrict__ Vb, const int* __restrict__ rowptr,
    const int* __restrict__ csr_src, float* __restrict__ gscratch,
    float* __restrict__ skipio, unsigned short* __restrict__ Hh,
    unsigned short* __restrict__ Hl, int C, float scale, int do_elu,
    int writeH) {
  __shared__ float qs[2048];
  __shared__ float ebuf[512];
  __shared__ int ssrc[512];
  __shared__ float wred[8];
  const int i = blockIdx.x;
  const int tid = threadIdx.x;
  const int lane = tid & 63, wid = tid >> 6;
  const int beg = rowptr[i], end = rowptr[i + 1];
  const int deg = end - beg;
  const bool sm = (deg <= 512);

  // stage q row (bf16 -> fp32), conflict-free float4 writes
  for (int c0 = tid * 4; c0 < C; c0 += 1024) {
    uint2 pk = *(const uint2*)(Qb + (size_t)i * C + c0);
    float4 f;
    f.x = __uint_as_float(pk.x << 16);
    f.y = __uint_as_float(pk.x & 0xffff0000u);
    f.z = __uint_as_float(pk.y << 16);
    f.w = __uint_as_float(pk.y & 0xffff0000u);
    *(float4*)&qs[c0] = f;
  }
  if (sm)
    for (int p = tid; p < deg; p += 256) ssrc[p] = csr_src[beg + p];
  if (tid < 8) wred[tid] = (tid < 4) ? -INFINITY : 0.f;
  __syncthreads();

  if (deg > 0) {
    float wmaxv = -INFINITY;
    for (int ep = wid; ep < deg; ep += 4) {
      int s = sm ? ssrc[ep] : csr_src[beg + ep];
      const unsigned short* kr = Kb + (size_t)s * C;
      float sum = 0.f;
      for (int c0 = lane * 8; c0 < C; c0 += 512) {
        uint4 pk = *(const uint4*)(kr + c0);
        float4 qa = *(const float4*)&qs[c0];
        float4 qb = *(const float4*)&qs[c0 + 4];
        const unsigned* pw = (const unsigned*)&pk;
        sum = fmaf(qa.x, __uint_as_float(pw[0] << 16), sum);
        sum = fmaf(qa.y, __uint_as_float(pw[0] & 0xffff0000u), sum);
        sum = fmaf(qa.z, __uint_as_float(pw[1] << 16), sum);
        sum = fmaf(qa.w, __uint_as_float(pw[1] & 0xffff0000u), sum);
        sum = fmaf(qb.x, __uint_as_float(pw[2] << 16), sum);
        sum = fmaf(qb.y, __uint_as_float(pw[2] & 0xffff0000u), sum);
        sum = fmaf(qb.z, __uint_as_float(pw[3] << 16), sum);
        sum = fmaf(qb.w, __uint_as_float(pw[3] & 0xffff0000u), sum);
      }
#pragma unroll
      for (int o = 32; o; o >>= 1) sum += __shfl_xor(sum, o);
      float lg = sum * scale;
      if (lane == 0) {
        if (sm) ebuf[ep] = lg; else gscratch[beg + ep] = lg;
      }
      wmaxv = fmaxf(wmaxv, lg);
    }
    if (lane == 0) wred[wid] = wmaxv;
    __syncthreads();
    float m = fmaxf(fmaxf(wred[0], wred[1]), fmaxf(wred[2], wred[3]));

    float part = 0.f;
    for (int ep = tid; ep < deg; ep += 256) {
      float lg = sm ? ebuf[ep] : gscratch[beg + ep];
      float e = expf(lg - m);
      if (sm) ebuf[ep] = e; else gscratch[beg + ep] = e;
      part += e;
    }
#pragma unroll
    for (int o = 32; o; o >>= 1) part += __shfl_xor(part, o);
    if (lane == 0) wred[4 + wid] = part;
  }
  __syncthreads();

  float total = wred[4] + wred[5] + wred[6] + wred[7];
  float denom = 1.f / (total + 1e-16f);
  const int cpt = C >> 8;  // 4 or 8 cols per thread
  const int col0 = tid * cpt;
  float acc[8];
#pragma unroll
  for (int j = 0; j < 8; ++j) acc[j] = 0.f;

  for (int ep = 0; ep < deg; ++ep) {
    float a = (sm ? ebuf[ep] : gscratch[beg + ep]) * denom;
    int s = sm ? ssrc[ep] : csr_src[beg + ep];
    const unsigned short* vr = Vb + (size_t)s * C + col0;
    if (cpt == 4) {
      ushort4 pv = *(const ushort4*)vr;
      acc[0] = fmaf(a, bf2f(pv.x), acc[0]);
      acc[1] = fmaf(a, bf2f(pv.y), acc[1]);
      acc[2] = fmaf(a, bf2f(pv.z), acc[2]);
      acc[3] = fmaf(a, bf2f(pv.w), acc[3]);
    } else {
      uint4 pv = *(const uint4*)vr;
      const unsigned* pw = (const unsigned*)&pv;
#pragma unroll
      for (int u = 0; u < 4; ++u) {
        acc[2 * u + 0] = fmaf(a, __uint_as_float(pw[u] << 16), acc[2 * u]);
        acc[2 * u + 1] =
            fmaf(a, __uint_as_float(pw[u] & 0xffff0000u), acc[2 * u + 1]);
      }
    }
  }

  float* srow = skipio + (size_t)i * C + col0;
#pragma unroll
  for (int v4 = 0; v4 < 2; ++v4) {
    if (v4 * 4 < cpt) {
      float4 o = *(const float4*)(srow + v4 * 4);
      o.x += acc[v4 * 4 + 0];
      o.y += acc[v4 * 4 + 1];
      o.z += acc[v4 * 4 + 2];
      o.w += acc[v4 * 4 + 3];
      if (do_elu) {
        o.x = o.x > 0.f ? o.x : expm1f(o.x);
        o.y = o.y > 0.f ? o.y : expm1f(o.y);
        o.z = o.z > 0.f ? o.z : expm1f(o.z);
        o.w = o.w > 0.f ? o.w : expm1f(o.w);
      }
      if (writeH) {
        ushort4 h, l;
        h.x = f2bf(o.x); l.x = f2bf(o.x - bf2f(h.x));
        h.y = f2bf(o.y); l.y = f2bf(o.y - bf2f(h.y));
        h.z = f2bf(o.z); l.z = f2bf(o.z - bf2f(h.z));
        h.w = f2bf(o.w); l.w = f2bf(o.w - bf2f(h.w));
        *(ushort4*)(Hh + (size_t)i * C + col0 + v4 * 4) = h;
        *(ushort4*)(Hl + (size_t)i * C + col0 + v4 * 4) = l;
      } else {
        *(float4*)(srow + v4 * 4) = o;
      }
    }
  }
}

// ---------------------------------------------------------------------------
// CSR build
// ---------------------------------------------------------------------------
__global__ void count_deg_k(const int* __restrict__ dst, int E,
                            int* __restrict__ cnt) {
  int e = blockIdx.x * blockDim.x + threadIdx.x;
  if (e < E) atomicAdd(&cnt[dst[e]], 1);
}

__global__ void scan_k(const int* __restrict__ cnt, int* __restrict__ rowptr,
                       int N) {
  __shared__ int part[1024];
  int t = threadIdx.x;
  int per = (N + 1023) >> 10;
  int base = t * per;
  int s = 0;
  for (int i = 0; i < per; ++i) {
    int idx = base + i;
    if (idx < N) s += cnt[idx];
  }
  part[t] = s;
  __syncthreads();
  for (int off = 1; off < 1024; off <<= 1) {
    int v = (t >= off) ? part[t - off] : 0;
    __syncthreads();
    part[t] += v;
    __syncthreads();
  }
  int run = part[t] - s;
  for (int i = 0; i < per; ++i) {
    int idx = base + i;
    if (idx < N) {
      rowptr[idx] = run;
      run += cnt[idx];
    }
  }
  if (t == 1023) rowptr[N] = part[1023];
}

__global__ void scatter_csr_k(const int* __restrict__ src,
                              const int* __restrict__ dst, int E,
                              const int* __restrict__ rowptr,
                              int* __restrict__ fill,
                              int* __restrict__ csr_src) {
  int e = blockIdx.x * blockDim.x + threadIdx.x;
  if (e >= E) return;
  int d = dst[e];
  int pos = rowptr[d] + atomicAdd(&fill[d], 1);
  csr_src[pos] = src[e];
}

// ---------------------------------------------------------------------------
extern "C" void kernel_launch(void* const* d_in, const int* in_sizes, int n_in,
                              void* d_out, int out_size, void* d_ws,
                              size_t ws_size, hipStream_t stream) {
  const float* x = (const float*)d_in[0];
  const int* eidx = (const int*)d_in[1];
  const int N = in_sizes[0] / 2048;
  const int E = in_sizes[1] / 2;
  const int* srcA = eidx;
  const int* dstA = eidx + E;
  float* dout = (float*)d_out;

  char* p = (char*)d_ws;
  auto alloc = [&](size_t bytes) {
    void* r = (void*)p;
    p += (bytes + 255) & ~(size_t)255;
    return r;
  };

  // common buffers
  float* logits = (float*)alloc((size_t)E * 4);
  int* rowptr = (int*)alloc((size_t)(N + 1) * 4);
  int* cnt = (int*)alloc((size_t)N * 4);
  int* fill = (int*)alloc((size_t)N * 4);
  int* csr_src = (int*)alloc((size_t)E * 4);

  hipMemsetAsync(cnt, 0, (size_t)N * 4, stream);
  hipMemsetAsync(fill, 0, (size_t)N * 4, stream);
  count_deg_k<<<(E + 255) / 256, 256, 0, stream>>>(dstA, E, cnt);
  scan_k<<<1, 1024, 0, stream>>>(cnt, rowptr, N);
  scatter_csr_k<<<(E + 255) / 256, 256, 0, stream>>>(srcA, dstA, E, rowptr,
                                                     fill, csr_src);

  const size_t szH = (size_t)N * 2048 * 2;          // bf16 [N][2048]
  const size_t szWt = (size_t)4 * 1024 * 2048 * 2;  // bf16 [4C][K] max

  // main path buffers (ws_size verified sufficient in prior rounds)
  unsigned short* Hh = (unsigned short*)alloc(szH);
  unsigned short* Hl = (unsigned short*)alloc(szH);
  unsigned short* Qb = (unsigned short*)alloc(szH);
  unsigned short* Kb = (unsigned short*)alloc(szH);
  unsigned short* Vb = (unsigned short*)alloc(szH);
  unsigned short* Wth = (unsigned short*)alloc(szWt);
  unsigned short* Wtl = (unsigned short*)alloc(szWt);

  const int fi[4] = {2048, 1024, 2048, 1024};
  const int fo[4] = {1024, 2048, 1024, 2048};
  const int elu[4] = {1, 0, 1, 0};

  split_k<<<(int)(((size_t)N * 2048 / 4 + 255) / 256), 256, 0, stream>>>(
      x, Hh, Hl, (size_t)N * 2048 / 4);

  for (int L = 0; L < 4; ++L) {
    const int K = fi[L], C = fo[L];
    const int b = 2 + L * 8;
    const float scale = (float)(1.0 / sqrt((double)C));
    for (int m = 0; m < 4; ++m) {
      const float* W = (const float*)d_in[b + 2 * m];
      transp_split_k<<<dim3(K / 32, C / 32), 256, 0, stream>>>(
          W, Wth + (size_t)m * C * K, Wtl + (size_t)m * C * K, K, C);
    }
    const int NX = (N + 127) / 128;
    const int NY2 = 2 * C / 128;
    // q,k (hi-only weights occupy rows [0,2C))
    gemm_qk_k<<<NX * NY2, 256, 0, stream>>>(
        Hh, Wth, (const float*)d_in[b + 1], (const float*)d_in[b + 3], Qb, Kb,
        N, K, C, NX, NY2);
    // v,s (rows [2C,4C))
    gemm_vs_k<<<NX * NY2, 256, 0, stream>>>(
        Hh, Hl, Wth + (size_t)2 * C * K, Wtl + (size_t)2 * C * K,
        (const float*)d_in[b + 5], (const float*)d_in[b + 7], Vb, dout, N, K,
        C, NX, NY2);
    attn_fused2_k<<<N, 256, 0, stream>>>(Qb, Kb, Vb, rowptr, csr_src, logits,
                                         dout, Hh, Hl, C, scale, elu[L],
                                         L < 3 ? 1 : 0);
  }
}

// Round 8
// 1907.878 us; speedup vs baseline: 5.4265x; 1.1484x over previous
//
#include <hip/hip_runtime.h>
#include <cmath>
#include <cstddef>
#include <cstdint>

typedef __attribute__((ext_vector_type(8))) short short8_t;
typedef __attribute__((ext_vector_type(4))) float f32x4;

// ---------------------------------------------------------------------------
// helpers: fp32 <-> bf16
// ---------------------------------------------------------------------------
__device__ __forceinline__ unsigned short f2bf(float f) {
  unsigned u = __float_as_uint(f);
  unsigned r = u + 0x7fffu + ((u >> 16) & 1u);
  return (unsigned short)(r >> 16);
}
__device__ __forceinline__ float bf2f(unsigned short h) {
  return __uint_as_float((unsigned)h << 16);
}

// async global -> LDS, 16B per lane (wave-uniform LDS base + lane*16)
__device__ __forceinline__ void gload16(const unsigned short* g,
                                        unsigned short* l) {
  __builtin_amdgcn_global_load_lds(
      (const __attribute__((address_space(1))) unsigned int*)g,
      (__attribute__((address_space(3))) unsigned int*)l, 16, 0, 0);
}

// ---------------------------------------------------------------------------
// cast fp32 -> bf16 (vectorized)
// ---------------------------------------------------------------------------
__global__ __launch_bounds__(256) void cast_bf16_k(
    const float* __restrict__ in, unsigned short* __restrict__ out, size_t n4) {
  size_t i = (size_t)blockIdx.x * blockDim.x + threadIdx.x;
  if (i >= n4) return;
  float4 v = ((const float4*)in)[i];
  ushort4 h;
  h.x = f2bf(v.x);
  h.y = f2bf(v.y);
  h.z = f2bf(v.z);
  h.w = f2bf(v.w);
  ((ushort4*)out)[i] = h;
}

// ---------------------------------------------------------------------------
// Weight transpose + split, 4 matrices in one launch (z = matrix index):
// W[K][C] fp32 -> Th[C][K], Tl[C][K] bf16 at offset z*C*K.
// ---------------------------------------------------------------------------
__global__ __launch_bounds__(256) void transp_split4_k(
    const float* __restrict__ W0, const float* __restrict__ W1,
    const float* __restrict__ W2, const float* __restrict__ W3,
    unsigned short* __restrict__ Th, unsigned short* __restrict__ Tl, int K,
    int C) {
  __shared__ float t[32][33];
  const int m = blockIdx.z;
  const float* W = (m == 0) ? W0 : (m == 1) ? W1 : (m == 2) ? W2 : W3;
  unsigned short* th = Th + (size_t)m * C * K;
  unsigned short* tl = Tl + (size_t)m * C * K;
  int k0 = blockIdx.x * 32, c0 = blockIdx.y * 32;
  int tx = threadIdx.x & 31, ty = threadIdx.x >> 5;  // ty 0..7
#pragma unroll
  for (int r = 0; r < 4; ++r)
    t[ty + r * 8][tx] = W[(size_t)(k0 + ty + r * 8) * C + c0 + tx];
  __syncthreads();
#pragma unroll
  for (int r = 0; r < 4; ++r) {
    int c = ty + r * 8;
    float v = t[tx][c];  // = W[k0+tx][c0+c]
    unsigned short h = f2bf(v);
    unsigned short l = f2bf(v - bf2f(h));
    th[(size_t)(c0 + c) * K + k0 + tx] = h;
    tl[(size_t)(c0 + c) * K + k0 + tx] = l;
  }
}

// ---------------------------------------------------------------------------
// q/k GEMM (bf16, 1 product): [q|k] = Xb @ Wt2^T + bias, bf16 out.
// Double-buffered LDS, STAGE-before-compute, one barrier per K-step.
// ---------------------------------------------------------------------------
__global__ __launch_bounds__(256) void gemm_qk_k(
    const unsigned short* __restrict__ Ab, const unsigned short* __restrict__ Wt2,
    const float* __restrict__ bq, const float* __restrict__ bk,
    unsigned short* __restrict__ Qb, unsigned short* __restrict__ Kb, int M,
    int K, int C, int NX, int NY2) {
  __shared__ unsigned short lds[2][2][4096];  // [buf][A|B][128*32]

  const int nwg = NX * NY2;
  const int bid = blockIdx.x;
  const int qq = nwg >> 3, rr = nwg & 7;
  const int xcd = bid & 7, idx = bid >> 3;
  const int wgid =
      (xcd < rr ? xcd * (qq + 1) : rr * (qq + 1) + (xcd - rr) * qq) + idx;
  const int by = wgid % NY2, bx = wgid / NY2;

  const int bm = bx * 128, n0 = by * 128;
  const int kind = (n0 >= C);  // 0=q 1=k
  const int tid = threadIdx.x;
  const int lane = tid & 63, w = tid >> 6;
  const int wm = w >> 1, wn = w & 1;
  const int fr = lane & 15, kg = lane >> 4;

  const int srow = w * 32 + (lane >> 2);
  const int soff = (lane & 3) * 8;
  const size_t ga0 = (size_t)min(bm + srow, M - 1) * K + soff;
  const size_t ga1 = (size_t)min(bm + srow + 16, M - 1) * K + soff;
  const size_t gb0 = (size_t)(n0 + srow) * K + soff;
  const size_t gb1 = (size_t)(n0 + srow + 16) * K + soff;
  const int l0 = w * 1024, l1 = w * 1024 + 512;

  f32x4 acc[4][4];
#pragma unroll
  for (int i = 0; i < 4; ++i)
#pragma unroll
    for (int j = 0; j < 4; ++j) acc[i][j] = (f32x4)0.f;

  gload16(Ab + ga0, &lds[0][0][l0]);
  gload16(Ab + ga1, &lds[0][0][l1]);
  gload16(Wt2 + gb0, &lds[0][1][l0]);
  gload16(Wt2 + gb1, &lds[0][1][l1]);
  __syncthreads();

  const int T = K / 32;
  for (int t = 0; t < T; ++t) {
    const int cur = t & 1;
    if (t + 1 < T) {
      const int ko = (t + 1) * 32;
      gload16(Ab + ga0 + ko, &lds[cur ^ 1][0][l0]);
      gload16(Ab + ga1 + ko, &lds[cur ^ 1][0][l1]);
      gload16(Wt2 + gb0 + ko, &lds[cur ^ 1][1][l0]);
      gload16(Wt2 + gb1 + ko, &lds[cur ^ 1][1][l1]);
    }
    const unsigned short* As = lds[cur][0];
    const unsigned short* Bs = lds[cur][1];
    short8_t ah[4], bh[4];
#pragma unroll
    for (int i = 0; i < 4; ++i) {
      ah[i] = *(const short8_t*)(As + (wm * 64 + i * 16 + fr) * 32 + kg * 8);
      bh[i] = *(const short8_t*)(Bs + (wn * 64 + i * 16 + fr) * 32 + kg * 8);
    }
#pragma unroll
    for (int i = 0; i < 4; ++i)
#pragma unroll
      for (int j = 0; j < 4; ++j)
        acc[i][j] = __builtin_amdgcn_mfma_f32_16x16x32_bf16(ah[i], bh[j],
                                                            acc[i][j], 0, 0, 0);
    __syncthreads();
  }

  const float* bptr = kind ? bk : bq;
  const int cbase = (n0 - kind * C) + wn * 64;
  float bvv[4];
#pragma unroll
  for (int j = 0; j < 4; ++j) bvv[j] = bptr[cbase + j * 16 + fr];
  unsigned short* ob = kind ? Kb : Qb;
#pragma unroll
  for (int i = 0; i < 4; ++i) {
#pragma unroll
    for (int r = 0; r < 4; ++r) {
      int gr = bm + wm * 64 + i * 16 + kg * 4 + r;
      if (gr < M) {
#pragma unroll
        for (int j = 0; j < 4; ++j)
          ob[(size_t)gr * C + cbase + j * 16 + fr] = f2bf(acc[i][j][r] + bvv[j]);
      }
    }
  }
}

// ---------------------------------------------------------------------------
// v/s GEMM (2-product: xh*(wh+wl)): [v|s] = Xb @ Wt2^T + bias.
// Wt2h/Wt2l = rows [2C,4C). v -> bf16 Vb, s -> fp32 S.
// ---------------------------------------------------------------------------
__global__ __launch_bounds__(256) void gemm_vs_k(
    const unsigned short* __restrict__ Ab, const unsigned short* __restrict__ Bh2,
    const unsigned short* __restrict__ Bl2, const float* __restrict__ bv,
    const float* __restrict__ bs, unsigned short* __restrict__ Vb,
    float* __restrict__ S, int M, int K, int C, int NX, int NY2) {
  __shared__ unsigned short lds[2][3][4096];  // [buf][A|BH|BL]

  const int nwg = NX * NY2;
  const int bid = blockIdx.x;
  const int qq = nwg >> 3, rr = nwg & 7;
  const int xcd = bid & 7, idx = bid >> 3;
  const int wgid =
      (xcd < rr ? xcd * (qq + 1) : rr * (qq + 1) + (xcd - rr) * qq) + idx;
  const int by = wgid % NY2, bx = wgid / NY2;

  const int bm = bx * 128, n0 = by * 128;
  const int kind = (n0 >= C);  // 0=v 1=s
  const int tid = threadIdx.x;
  const int lane = tid & 63, w = tid >> 6;
  const int wm = w >> 1, wn = w & 1;
  const int fr = lane & 15, kg = lane >> 4;

  const int srow = w * 32 + (lane >> 2);
  const int soff = (lane & 3) * 8;
  const size_t ga0 = (size_t)min(bm + srow, M - 1) * K + soff;
  const size_t ga1 = (size_t)min(bm + srow + 16, M - 1) * K + soff;
  const size_t gb0 = (size_t)(n0 + srow) * K + soff;
  const size_t gb1 = (size_t)(n0 + srow + 16) * K + soff;
  const int l0 = w * 1024, l1 = w * 1024 + 512;

  f32x4 acc[4][4];
#pragma unroll
  for (int i = 0; i < 4; ++i)
#pragma unroll
    for (int j = 0; j < 4; ++j) acc[i][j] = (f32x4)0.f;

  gload16(Ab + ga0, &lds[0][0][l0]);
  gload16(Ab + ga1, &lds[0][0][l1]);
  gload16(Bh2 + gb0, &lds[0][1][l0]);
  gload16(Bh2 + gb1, &lds[0][1][l1]);
  gload16(Bl2 + gb0, &lds[0][2][l0]);
  gload16(Bl2 + gb1, &lds[0][2][l1]);
  __syncthreads();

  const int T = K / 32;
  for (int t = 0; t < T; ++t) {
    const int cur = t & 1;
    if (t + 1 < T) {
      const int ko = (t + 1) * 32;
      gload16(Ab + ga0 + ko, &lds[cur ^ 1][0][l0]);
      gload16(Ab + ga1 + ko, &lds[cur ^ 1][0][l1]);
      gload16(Bh2 + gb0 + ko, &lds[cur ^ 1][1][l0]);
      gload16(Bh2 + gb1 + ko, &lds[cur ^ 1][1][l1]);
      gload16(Bl2 + gb0 + ko, &lds[cur ^ 1][2][l0]);
      gload16(Bl2 + gb1 + ko, &lds[cur ^ 1][2][l1]);
    }
    const unsigned short* As = lds[cur][0];
    const unsigned short* BHs = lds[cur][1];
    const unsigned short* BLs = lds[cur][2];
    short8_t ah[4], bh[4], bl[4];
#pragma unroll
    for (int i = 0; i < 4; ++i) {
      ah[i] = *(const short8_t*)(As + (wm * 64 + i * 16 + fr) * 32 + kg * 8);
      bh[i] = *(const short8_t*)(BHs + (wn * 64 + i * 16 + fr) * 32 + kg * 8);
      bl[i] = *(const short8_t*)(BLs + (wn * 64 + i * 16 + fr) * 32 + kg * 8);
    }
#pragma unroll
    for (int i = 0; i < 4; ++i)
#pragma unroll
      for (int j = 0; j < 4; ++j) {
        acc[i][j] = __builtin_amdgcn_mfma_f32_16x16x32_bf16(ah[i], bh[j],
                                                            acc[i][j], 0, 0, 0);
        acc[i][j] = __builtin_amdgcn_mfma_f32_16x16x32_bf16(ah[i], bl[j],
                                                            acc[i][j], 0, 0, 0);
      }
    __syncthreads();
  }

  const float* bptr = kind ? bs : bv;
  const int cbase = (n0 - kind * C) + wn * 64;
  float bvv[4];
#pragma unroll
  for (int j = 0; j < 4; ++j) bvv[j] = bptr[cbase + j * 16 + fr];
#pragma unroll
  for (int i = 0; i < 4; ++i) {
#pragma unroll
    for (int r = 0; r < 4; ++r) {
      int gr = bm + wm * 64 + i * 16 + kg * 4 + r;
      if (gr < M) {
        if (kind) {
#pragma unroll
          for (int j = 0; j < 4; ++j)
            S[(size_t)gr * C + cbase + j * 16 + fr] = acc[i][j][r] + bvv[j];
        } else {
#pragma unroll
          for (int j = 0; j < 4; ++j)
            Vb[(size_t)gr * C + cbase + j * 16 + fr] =
                f2bf(acc[i][j][r] + bvv[j]);
        }
      }
    }
  }
}

// ---------------------------------------------------------------------------
// Fused attention (bf16 q/k/v). skipio holds the skip GEMM output (fp32).
// result = skip + agg, optional ELU; writeH ? bf16->Hb : fp32->skipio.
// ---------------------------------------------------------------------------
__global__ __launch_bounds__(256) void attn_fused2_k(
    const unsigned short* __restrict__ Qb, const unsigned short* __restrict__ Kb,
    const unsigned short* __restrict__ Vb, const int* __restrict__ rowptr,
    const int* __restrict__ csr_src, float* __restrict__ gscratch,
    float* __restrict__ skipio, unsigned short* __restrict__ Hb, int C,
    float scale, int do_elu, int writeH) {
  __shared__ float qs[2048];
  __shared__ float ebuf[512];
  __shared__ int ssrc[512];
  __shared__ float wred[8];
  const int i = blockIdx.x;
  const int tid = threadIdx.x;
  const int lane = tid & 63, wid = tid >> 6;
  const int beg = rowptr[i], end = rowptr[i + 1];
  const int deg = end - beg;
  const bool sm = (deg <= 512);

  // stage q row (bf16 -> fp32), conflict-free float4 writes
  for (int c0 = tid * 4; c0 < C; c0 += 1024) {
    uint2 pk = *(const uint2*)(Qb + (size_t)i * C + c0);
    float4 f;
    f.x = __uint_as_float(pk.x << 16);
    f.y = __uint_as_float(pk.x & 0xffff0000u);
    f.z = __uint_as_float(pk.y << 16);
    f.w = __uint_as_float(pk.y & 0xffff0000u);
    *(float4*)&qs[c0] = f;
  }
  if (sm)
    for (int p = tid; p < deg; p += 256) ssrc[p] = csr_src[beg + p];
  if (tid < 8) wred[tid] = (tid < 4) ? -INFINITY : 0.f;
  __syncthreads();

  if (deg > 0) {
    float wmaxv = -INFINITY;
    for (int ep = wid; ep < deg; ep += 4) {
      int s = sm ? ssrc[ep] : csr_src[beg + ep];
      const unsigned short* kr = Kb + (size_t)s * C;
      float sum = 0.f;
      for (int c0 = lane * 8; c0 < C; c0 += 512) {
        uint4 pk = *(const uint4*)(kr + c0);
        float4 qa = *(const float4*)&qs[c0];
        float4 qb = *(const float4*)&qs[c0 + 4];
        const unsigned* pw = (const unsigned*)&pk;
        sum = fmaf(qa.x, __uint_as_float(pw[0] << 16), sum);
        sum = fmaf(qa.y, __uint_as_float(pw[0] & 0xffff0000u), sum);
        sum = fmaf(qa.z, __uint_as_float(pw[1] << 16), sum);
        sum = fmaf(qa.w, __uint_as_float(pw[1] & 0xffff0000u), sum);
        sum = fmaf(qb.x, __uint_as_float(pw[2] << 16), sum);
        sum = fmaf(qb.y, __uint_as_float(pw[2] & 0xffff0000u), sum);
        sum = fmaf(qb.z, __uint_as_float(pw[3] << 16), sum);
        sum = fmaf(qb.w, __uint_as_float(pw[3] & 0xffff0000u), sum);
      }
#pragma unroll
      for (int o = 32; o; o >>= 1) sum += __shfl_xor(sum, o);
      float lg = sum * scale;
      if (lane == 0) {
        if (sm) ebuf[ep] = lg; else gscratch[beg + ep] = lg;
      }
      wmaxv = fmaxf(wmaxv, lg);
    }
    if (lane == 0) wred[wid] = wmaxv;
    __syncthreads();
    float m = fmaxf(fmaxf(wred[0], wred[1]), fmaxf(wred[2], wred[3]));

    float part = 0.f;
    for (int ep = tid; ep < deg; ep += 256) {
      float lg = sm ? ebuf[ep] : gscratch[beg + ep];
      float e = expf(lg - m);
      if (sm) ebuf[ep] = e; else gscratch[beg + ep] = e;
      part += e;
    }
#pragma unroll
    for (int o = 32; o; o >>= 1) part += __shfl_xor(part, o);
    if (lane == 0) wred[4 + wid] = part;
  }
  __syncthreads();

  float total = wred[4] + wred[5] + wred[6] + wred[7];
  float denom = 1.f / (total + 1e-16f);
  const int cpt = C >> 8;  // 4 or 8 cols per thread
  const int col0 = tid * cpt;
  float acc[8];
#pragma unroll
  for (int j = 0; j < 8; ++j) acc[j] = 0.f;

  for (int ep = 0; ep < deg; ++ep) {
    float a = (sm ? ebuf[ep] : gscratch[beg + ep]) * denom;
    int s = sm ? ssrc[ep] : csr_src[beg + ep];
    const unsigned short* vr = Vb + (size_t)s * C + col0;
    if (cpt == 4) {
      ushort4 pv = *(const ushort4*)vr;
      acc[0] = fmaf(a, bf2f(pv.x), acc[0]);
      acc[1] = fmaf(a, bf2f(pv.y), acc[1]);
      acc[2] = fmaf(a, bf2f(pv.z), acc[2]);
      acc[3] = fmaf(a, bf2f(pv.w), acc[3]);
    } else {
      uint4 pv = *(const uint4*)vr;
      const unsigned* pw = (const unsigned*)&pv;
#pragma unroll
      for (int u = 0; u < 4; ++u) {
        acc[2 * u + 0] = fmaf(a, __uint_as_float(pw[u] << 16), acc[2 * u]);
        acc[2 * u + 1] =
            fmaf(a, __uint_as_float(pw[u] & 0xffff0000u), acc[2 * u + 1]);
      }
    }
  }

  float* srow = skipio + (size_t)i * C + col0;
#pragma unroll
  for (int v4 = 0; v4 < 2; ++v4) {
    if (v4 * 4 < cpt) {
      float4 o = *(const float4*)(srow + v4 * 4);
      o.x += acc[v4 * 4 + 0];
      o.y += acc[v4 * 4 + 1];
      o.z += acc[v4 * 4 + 2];
      o.w += acc[v4 * 4 + 3];
      if (do_elu) {
        o.x = o.x > 0.f ? o.x : expm1f(o.x);
        o.y = o.y > 0.f ? o.y : expm1f(o.y);
        o.z = o.z > 0.f ? o.z : expm1f(o.z);
        o.w = o.w > 0.f ? o.w : expm1f(o.w);
      }
      if (writeH) {
        ushort4 h;
        h.x = f2bf(o.x);
        h.y = f2bf(o.y);
        h.z = f2bf(o.z);
        h.w = f2bf(o.w);
        *(ushort4*)(Hb + (size_t)i * C + col0 + v4 * 4) = h;
      } else {
        *(float4*)(srow + v4 * 4) = o;
      }
    }
  }
}

// ---------------------------------------------------------------------------
// CSR build
// ---------------------------------------------------------------------------
__global__ void count_deg_k(const int* __restrict__ dst, int E,
                            int* __restrict__ cnt) {
  int e = blockIdx.x * blockDim.x + threadIdx.x;
  if (e < E) atomicAdd(&cnt[dst[e]], 1);
}

__global__ void scan_k(const int* __restrict__ cnt, int* __restrict__ rowptr,
                       int N) {
  __shared__ int part[1024];
  int t = threadIdx.x;
  int per = (N + 1023) >> 10;
  int base = t * per;
  int s = 0;
  for (int i = 0; i < per; ++i) {
    int idx = base + i;
    if (idx < N) s += cnt[idx];
  }
  part[t] = s;
  __syncthreads();
  for (int off = 1; off < 1024; off <<= 1) {
    int v = (t >= off) ? part[t - off] : 0;
    __syncthreads();
    part[t] += v;
    __syncthreads();
  }
  int run = part[t] - s;
  for (int i = 0; i < per; ++i) {
    int idx = base + i;
    if (idx < N) {
      rowptr[idx] = run;
      run += cnt[idx];
    }
  }
  if (t == 1023) rowptr[N] = part[1023];
}

__global__ void scatter_csr_k(const int* __restrict__ src,
                              const int* __restrict__ dst, int E,
                              const int* __restrict__ rowptr,
                              int* __restrict__ fill,
                              int* __restrict__ csr_src) {
  int e = blockIdx.x * blockDim.x + threadIdx.x;
  if (e >= E) return;
  int d = dst[e];
  int pos = rowptr[d] + atomicAdd(&fill[d], 1);
  csr_src[pos] = src[e];
}

// ---------------------------------------------------------------------------
extern "C" void kernel_launch(void* const* d_in, const int* in_sizes, int n_in,
                              void* d_out, int out_size, void* d_ws,
                              size_t ws_size, hipStream_t stream) {
  const float* x = (const float*)d_in[0];
  const int* eidx = (const int*)d_in[1];
  const int N = in_sizes[0] / 2048;
  const int E = in_sizes[1] / 2;
  const int* srcA = eidx;
  const int* dstA = eidx + E;
  float* dout = (float*)d_out;

  char* p = (char*)d_ws;
  auto alloc = [&](size_t bytes) {
    void* r = (void*)p;
    p += (bytes + 255) & ~(size_t)255;
    return r;
  };

  // common buffers
  float* logits = (float*)alloc((size_t)E * 4);
  int* rowptr = (int*)alloc((size_t)(N + 1) * 4);
  int* cnt = (int*)alloc((size_t)N * 4);
  int* fill = (int*)alloc((size_t)N * 4);
  int* csr_src = (int*)alloc((size_t)E * 4);

  hipMemsetAsync(cnt, 0, (size_t)N * 4, stream);
  hipMemsetAsync(fill, 0, (size_t)N * 4, stream);
  count_deg_k<<<(E + 255) / 256, 256, 0, stream>>>(dstA, E, cnt);
  scan_k<<<1, 1024, 0, stream>>>(cnt, rowptr, N);
  scatter_csr_k<<<(E + 255) / 256, 256, 0, stream>>>(srcA, dstA, E, rowptr,
                                                     fill, csr_src);

  const size_t szH = (size_t)N * 2048 * 2;          // bf16 [N][2048]
  const size_t szWt = (size_t)4 * 1024 * 2048 * 2;  // bf16 [4C][K] max

  unsigned short* Hb = (unsigned short*)alloc(szH);
  unsigned short* Qb = (unsigned short*)alloc(szH);
  unsigned short* Kb = (unsigned short*)alloc(szH);
  unsigned short* Vb = (unsigned short*)alloc(szH);
  unsigned short* Wth = (unsigned short*)alloc(szWt);
  unsigned short* Wtl = (unsigned short*)alloc(szWt);

  const int fi[4] = {2048, 1024, 2048, 1024};
  const int fo[4] = {1024, 2048, 1024, 2048};
  const int elu[4] = {1, 0, 1, 0};

  cast_bf16_k<<<(int)(((size_t)N * 2048 / 4 + 255) / 256), 256, 0, stream>>>(
      x, Hb, (size_t)N * 2048 / 4);

  for (int L = 0; L < 4; ++L) {
    const int K = fi[L], C = fo[L];
    const int b = 2 + L * 8;
    const float scale = (float)(1.0 / sqrt((double)C));
    transp_split4_k<<<dim3(K / 32, C / 32, 4), 256, 0, stream>>>(
        (const float*)d_in[b + 0], (const float*)d_in[b + 2],
        (const float*)d_in[b + 4], (const float*)d_in[b + 6], Wth, Wtl, K, C);
    const int NX = (N + 127) / 128;
    const int NY2 = 2 * C / 128;
    // q,k (rows [0,2C) of Wth; hi only)
    gemm_qk_k<<<NX * NY2, 256, 0, stream>>>(
        Hb, Wth, (const float*)d_in[b + 1], (const float*)d_in[b + 3], Qb, Kb,
        N, K, C, NX, NY2);
    // v,s (rows [2C,4C); hi+lo weights, hi-only activations)
    gemm_vs_k<<<NX * NY2, 256, 0, stream>>>(
        Hb, Wth + (size_t)2 * C * K, Wtl + (size_t)2 * C * K,
        (const float*)d_in[b + 5], (const float*)d_in[b + 7], Vb, dout, N, K,
        C, NX, NY2);
    attn_fused2_k<<<N, 256, 0, stream>>>(Qb, Kb, Vb, rowptr, csr_src, logits,
                                         dout, Hb, C, scale, elu[L],
                                         L < 3 ? 1 : 0);
  }
}

// Round 9
// 1676.088 us; speedup vs baseline: 6.1770x; 1.1383x over previous
//
#include <hip/hip_runtime.h>
#include <cmath>
#include <cstddef>
#include <cstdint>

typedef __attribute__((ext_vector_type(8))) _Float16 half8_t;
typedef __attribute__((ext_vector_type(4))) _Float16 half4_t;
typedef __attribute__((ext_vector_type(2))) _Float16 half2_t;
typedef __attribute__((ext_vector_type(4))) float f32x4;

// ---------------------------------------------------------------------------
// helpers
// ---------------------------------------------------------------------------
__device__ __forceinline__ float dot2f16(half2_t a, half2_t b, float c) {
#if __has_builtin(__builtin_amdgcn_fdot2)
  return __builtin_amdgcn_fdot2(a, b, c, false);
#else
  return c + (float)a.x * (float)b.x + (float)a.y * (float)b.y;
#endif
}

// async global -> LDS, 16B per lane (wave-uniform LDS base + lane*16)
__device__ __forceinline__ void gload16(const unsigned short* g,
                                        unsigned short* l) {
  __builtin_amdgcn_global_load_lds(
      (const __attribute__((address_space(1))) unsigned int*)g,
      (__attribute__((address_space(3))) unsigned int*)l, 16, 0, 0);
}

// ---------------------------------------------------------------------------
// cast fp32 -> fp16 (vectorized)
// ---------------------------------------------------------------------------
__global__ __launch_bounds__(256) void cast_f16_k(
    const float* __restrict__ in, unsigned short* __restrict__ out, size_t n4) {
  size_t i = (size_t)blockIdx.x * blockDim.x + threadIdx.x;
  if (i >= n4) return;
  float4 v = ((const float4*)in)[i];
  half4_t h;
  h.x = (_Float16)v.x;
  h.y = (_Float16)v.y;
  h.z = (_Float16)v.z;
  h.w = (_Float16)v.w;
  ((half4_t*)out)[i] = h;
}

// ---------------------------------------------------------------------------
// Weight transpose, 4 matrices per launch (z = matrix):
// W[K][C] fp32 -> T[C][K] fp16 at offset z*C*K.
// ---------------------------------------------------------------------------
__global__ __launch_bounds__(256) void transp_f16_k(
    const float* __restrict__ W0, const float* __restrict__ W1,
    const float* __restrict__ W2, const float* __restrict__ W3,
    unsigned short* __restrict__ T, int K, int C) {
  __shared__ float t[32][33];
  const int m = blockIdx.z;
  const float* W = (m == 0) ? W0 : (m == 1) ? W1 : (m == 2) ? W2 : W3;
  _Float16* th = (_Float16*)T + (size_t)m * C * K;
  int k0 = blockIdx.x * 32, c0 = blockIdx.y * 32;
  int tx = threadIdx.x & 31, ty = threadIdx.x >> 5;  // ty 0..7
#pragma unroll
  for (int r = 0; r < 4; ++r)
    t[ty + r * 8][tx] = W[(size_t)(k0 + ty + r * 8) * C + c0 + tx];
  __syncthreads();
#pragma unroll
  for (int r = 0; r < 4; ++r) {
    int c = ty + r * 8;
    th[(size_t)(c0 + c) * K + k0 + tx] = (_Float16)t[tx][c];
  }
}

// ---------------------------------------------------------------------------
// Fused per-layer GEMM (fp16 single product): [q|k|v|s] = X @ Wt^T + bias
// X fp16 [M][K]; Wt fp16 [4C][K]. q,k,v -> fp16; s -> fp32.
// Double-buffered LDS, STAGE-before-compute, one barrier per K-step.
// Column-fast + bijective XCD remap for A-panel L2 reuse.
// ---------------------------------------------------------------------------
__global__ __launch_bounds__(256) void gemm_f16_k(
    const unsigned short* __restrict__ Ab, const unsigned short* __restrict__ Wt,
    const float* __restrict__ bq, const float* __restrict__ bk,
    const float* __restrict__ bv, const float* __restrict__ bs,
    unsigned short* __restrict__ Qh, unsigned short* __restrict__ Kh,
    unsigned short* __restrict__ Vh, float* __restrict__ S, int M, int K,
    int C, int NX, int NY) {
  __shared__ unsigned short lds[2][2][4096];  // [buf][A|B][128*32]

  const int nwg = NX * NY;
  const int bid = blockIdx.x;
  const int qq = nwg >> 3, rr = nwg & 7;
  const int xcd = bid & 7, idx = bid >> 3;
  const int wgid =
      (xcd < rr ? xcd * (qq + 1) : rr * (qq + 1) + (xcd - rr) * qq) + idx;
  const int by = wgid % NY, bx = wgid / NY;

  const int bm = bx * 128, n0 = by * 128;
  const int kind = n0 / C;  // 0=q 1=k 2=v 3=s
  const int tid = threadIdx.x;
  const int lane = tid & 63, w = tid >> 6;
  const int wm = w >> 1, wn = w & 1;
  const int fr = lane & 15, kg = lane >> 4;

  const int srow = w * 32 + (lane >> 2);
  const int soff = (lane & 3) * 8;
  const size_t ga0 = (size_t)min(bm + srow, M - 1) * K + soff;
  const size_t ga1 = (size_t)min(bm + srow + 16, M - 1) * K + soff;
  const size_t gb0 = (size_t)(n0 + srow) * K + soff;
  const size_t gb1 = (size_t)(n0 + srow + 16) * K + soff;
  const int l0 = w * 1024, l1 = w * 1024 + 512;

  f32x4 acc[4][4];
#pragma unroll
  for (int i = 0; i < 4; ++i)
#pragma unroll
    for (int j = 0; j < 4; ++j) acc[i][j] = (f32x4)0.f;

  gload16(Ab + ga0, &lds[0][0][l0]);
  gload16(Ab + ga1, &lds[0][0][l1]);
  gload16(Wt + gb0, &lds[0][1][l0]);
  gload16(Wt + gb1, &lds[0][1][l1]);
  __syncthreads();

  const int T = K / 32;
  for (int t = 0; t < T; ++t) {
    const int cur = t & 1;
    if (t + 1 < T) {
      const int ko = (t + 1) * 32;
      gload16(Ab + ga0 + ko, &lds[cur ^ 1][0][l0]);
      gload16(Ab + ga1 + ko, &lds[cur ^ 1][0][l1]);
      gload16(Wt + gb0 + ko, &lds[cur ^ 1][1][l0]);
      gload16(Wt + gb1 + ko, &lds[cur ^ 1][1][l1]);
    }
    const unsigned short* As = lds[cur][0];
    const unsigned short* Bs = lds[cur][1];
    half8_t ah[4], bh[4];
#pragma unroll
    for (int i = 0; i < 4; ++i) {
      ah[i] = *(const half8_t*)(As + (wm * 64 + i * 16 + fr) * 32 + kg * 8);
      bh[i] = *(const half8_t*)(Bs + (wn * 64 + i * 16 + fr) * 32 + kg * 8);
    }
#pragma unroll
    for (int i = 0; i < 4; ++i)
#pragma unroll
      for (int j = 0; j < 4; ++j)
        acc[i][j] = __builtin_amdgcn_mfma_f32_16x16x32_f16(ah[i], bh[j],
                                                           acc[i][j], 0, 0, 0);
    __syncthreads();
  }

  const float* bptr = (kind == 0) ? bq : (kind == 1) ? bk : (kind == 2) ? bv : bs;
  const int cbase = (n0 - kind * C) + wn * 64;
  float bvv[4];
#pragma unroll
  for (int j = 0; j < 4; ++j) bvv[j] = bptr[cbase + j * 16 + fr];

  unsigned short* obu = (kind == 0) ? Qh : (kind == 1) ? Kh : Vh;
  _Float16* ob = (_Float16*)obu;
#pragma unroll
  for (int i = 0; i < 4; ++i) {
#pragma unroll
    for (int r = 0; r < 4; ++r) {
      int gr = bm + wm * 64 + i * 16 + kg * 4 + r;
      if (gr < M) {
        if (kind == 3) {
#pragma unroll
          for (int j = 0; j < 4; ++j)
            S[(size_t)gr * C + cbase + j * 16 + fr] = acc[i][j][r] + bvv[j];
        } else {
#pragma unroll
          for (int j = 0; j < 4; ++j)
            ob[(size_t)gr * C + cbase + j * 16 + fr] =
                (_Float16)(acc[i][j][r] + bvv[j]);
        }
      }
    }
  }
}

// ---------------------------------------------------------------------------
// Fused attention (fp16 q/k/v). skipio holds the skip GEMM output (fp32).
// result = skip + agg, optional ELU; writeH ? fp16->Hb : fp32->skipio.
// ---------------------------------------------------------------------------
__global__ __launch_bounds__(256) void attn_fused2_k(
    const unsigned short* __restrict__ Qh, const unsigned short* __restrict__ Kh,
    const unsigned short* __restrict__ Vh, const int* __restrict__ rowptr,
    const int* __restrict__ csr_src, float* __restrict__ gscratch,
    float* __restrict__ skipio, unsigned short* __restrict__ Hb, int C,
    float scale, int do_elu, int writeH) {
  __shared__ _Float16 qs[2048];
  __shared__ float ebuf[512];
  __shared__ int ssrc[512];
  __shared__ float wred[8];
  const int i = blockIdx.x;
  const int tid = threadIdx.x;
  const int lane = tid & 63, wid = tid >> 6;
  const int beg = rowptr[i], end = rowptr[i + 1];
  const int deg = end - beg;
  const bool sm = (deg <= 512);

  // stage q row (fp16, raw copy)
  for (int c0 = tid * 4; c0 < C; c0 += 1024)
    *(uint2*)&qs[c0] = *(const uint2*)(Qh + (size_t)i * C + c0);
  if (sm)
    for (int p = tid; p < deg; p += 256) ssrc[p] = csr_src[beg + p];
  if (tid < 8) wred[tid] = (tid < 4) ? -INFINITY : 0.f;
  __syncthreads();

  if (deg > 0) {
    float wmaxv = -INFINITY;
    for (int ep = wid; ep < deg; ep += 4) {
      int s = sm ? ssrc[ep] : csr_src[beg + ep];
      const unsigned short* kr = Kh + (size_t)s * C;
      float sum = 0.f;
      for (int c0 = lane * 8; c0 < C; c0 += 512) {
        uint4 kk = *(const uint4*)(kr + c0);
        uint4 qq4 = *(const uint4*)&qs[c0];
        const half2_t* kp = (const half2_t*)&kk;
        const half2_t* qp = (const half2_t*)&qq4;
        sum = dot2f16(kp[0], qp[0], sum);
        sum = dot2f16(kp[1], qp[1], sum);
        sum = dot2f16(kp[2], qp[2], sum);
        sum = dot2f16(kp[3], qp[3], sum);
      }
#pragma unroll
      for (int o = 32; o; o >>= 1) sum += __shfl_xor(sum, o);
      float lg = sum * scale;
      if (lane == 0) {
        if (sm) ebuf[ep] = lg; else gscratch[beg + ep] = lg;
      }
      wmaxv = fmaxf(wmaxv, lg);
    }
    if (lane == 0) wred[wid] = wmaxv;
    __syncthreads();
    float m = fmaxf(fmaxf(wred[0], wred[1]), fmaxf(wred[2], wred[3]));

    float part = 0.f;
    for (int ep = tid; ep < deg; ep += 256) {
      float lg = sm ? ebuf[ep] : gscratch[beg + ep];
      float e = expf(lg - m);
      if (sm) ebuf[ep] = e; else gscratch[beg + ep] = e;
      part += e;
    }
#pragma unroll
    for (int o = 32; o; o >>= 1) part += __shfl_xor(part, o);
    if (lane == 0) wred[4 + wid] = part;
  }
  __syncthreads();

  float total = wred[4] + wred[5] + wred[6] + wred[7];
  float denom = 1.f / (total + 1e-16f);
  const int cpt = C >> 8;  // 4 or 8 cols per thread
  const int col0 = tid * cpt;
  float acc[8];
#pragma unroll
  for (int j = 0; j < 8; ++j) acc[j] = 0.f;

  for (int ep = 0; ep < deg; ++ep) {
    float a = (sm ? ebuf[ep] : gscratch[beg + ep]) * denom;
    int s = sm ? ssrc[ep] : csr_src[beg + ep];
    const unsigned short* vr = Vh + (size_t)s * C + col0;
    if (cpt == 4) {
      ushort4 pv = *(const ushort4*)vr;
      const _Float16* ph = (const _Float16*)&pv;
#pragma unroll
      for (int u = 0; u < 4; ++u) acc[u] = fmaf(a, (float)ph[u], acc[u]);
    } else {
      uint4 pv = *(const uint4*)vr;
      const _Float16* ph = (const _Float16*)&pv;
#pragma unroll
      for (int u = 0; u < 8; ++u) acc[u] = fmaf(a, (float)ph[u], acc[u]);
    }
  }

  float* srow = skipio + (size_t)i * C + col0;
#pragma unroll
  for (int v4 = 0; v4 < 2; ++v4) {
    if (v4 * 4 < cpt) {
      float4 o = *(const float4*)(srow + v4 * 4);
      o.x += acc[v4 * 4 + 0];
      o.y += acc[v4 * 4 + 1];
      o.z += acc[v4 * 4 + 2];
      o.w += acc[v4 * 4 + 3];
      if (do_elu) {
        o.x = o.x > 0.f ? o.x : expm1f(o.x);
        o.y = o.y > 0.f ? o.y : expm1f(o.y);
        o.z = o.z > 0.f ? o.z : expm1f(o.z);
        o.w = o.w > 0.f ? o.w : expm1f(o.w);
      }
      if (writeH) {
        half4_t h;
        h.x = (_Float16)o.x;
        h.y = (_Float16)o.y;
        h.z = (_Float16)o.z;
        h.w = (_Float16)o.w;
        *(half4_t*)((_Float16*)Hb + (size_t)i * C + col0 + v4 * 4) = h;
      } else {
        *(float4*)(srow + v4 * 4) = o;
      }
    }
  }
}

// ---------------------------------------------------------------------------
// CSR build
// ---------------------------------------------------------------------------
__global__ void count_deg_k(const int* __restrict__ dst, int E,
                            int* __restrict__ cnt) {
  int e = blockIdx.x * blockDim.x + threadIdx.x;
  if (e < E) atomicAdd(&cnt[dst[e]], 1);
}

__global__ void scan_k(const int* __restrict__ cnt, int* __restrict__ rowptr,
                       int N) {
  __shared__ int part[1024];
  int t = threadIdx.x;
  int per = (N + 1023) >> 10;
  int base = t * per;
  int s = 0;
  for (int i = 0; i < per; ++i) {
    int idx = base + i;
    if (idx < N) s += cnt[idx];
  }
  part[t] = s;
  __syncthreads();
  for (int off = 1; off < 1024; off <<= 1) {
    int v = (t >= off) ? part[t - off] : 0;
    __syncthreads();
    part[t] += v;
    __syncthreads();
  }
  int run = part[t] - s;
  for (int i = 0; i < per; ++i) {
    int idx = base + i;
    if (idx < N) {
      rowptr[idx] = run;
      run += cnt[idx];
    }
  }
  if (t == 1023) rowptr[N] = part[1023];
}

__global__ void scatter_csr_k(const int* __restrict__ src,
                              const int* __restrict__ dst, int E,
                              const int* __restrict__ rowptr,
                              int* __restrict__ fill,
                              int* __restrict__ csr_src) {
  int e = blockIdx.x * blockDim.x + threadIdx.x;
  if (e >= E) return;
  int d = dst[e];
  int pos = rowptr[d] + atomicAdd(&fill[d], 1);
  csr_src[pos] = src[e];
}

// ---------------------------------------------------------------------------
extern "C" void kernel_launch(void* const* d_in, const int* in_sizes, int n_in,
                              void* d_out, int out_size, void* d_ws,
                              size_t ws_size, hipStream_t stream) {
  const float* x = (const float*)d_in[0];
  const int* eidx = (const int*)d_in[1];
  const int N = in_sizes[0] / 2048;
  const int E = in_sizes[1] / 2;
  const int* srcA = eidx;
  const int* dstA = eidx + E;
  float* dout = (float*)d_out;

  char* p = (char*)d_ws;
  auto alloc = [&](size_t bytes) {
    void* r = (void*)p;
    p += (bytes + 255) & ~(size_t)255;
    return r;
  };

  // common buffers
  float* logits = (float*)alloc((size_t)E * 4);
  int* rowptr = (int*)alloc((size_t)(N + 1) * 4);
  int* cnt = (int*)alloc((size_t)N * 4);
  int* fill = (int*)alloc((size_t)N * 4);
  int* csr_src = (int*)alloc((size_t)E * 4);

  hipMemsetAsync(cnt, 0, (size_t)N * 4, stream);
  hipMemsetAsync(fill, 0, (size_t)N * 4, stream);
  count_deg_k<<<(E + 255) / 256, 256, 0, stream>>>(dstA, E, cnt);
  scan_k<<<1, 1024, 0, stream>>>(cnt, rowptr, N);
  scatter_csr_k<<<(E + 255) / 256, 256, 0, stream>>>(srcA, dstA, E, rowptr,
                                                     fill, csr_src);

  const size_t szH = (size_t)N * 2048 * 2;          // fp16 [N][2048]
  const size_t szWt = (size_t)4 * 1024 * 2048 * 2;  // fp16 [4C][K] max

  unsigned short* Hb = (unsigned short*)alloc(szH);
  unsigned short* Qh = (unsigned short*)alloc(szH);
  unsigned short* Kh = (unsigned short*)alloc(szH);
  unsigned short* Vh = (unsigned short*)alloc(szH);
  unsigned short* Wt = (unsigned short*)alloc(szWt);

  const int fi[4] = {2048, 1024, 2048, 1024};
  const int fo[4] = {1024, 2048, 1024, 2048};
  const int elu[4] = {1, 0, 1, 0};

  cast_f16_k<<<(int)(((size_t)N * 2048 / 4 + 255) / 256), 256, 0, stream>>>(
      x, Hb, (size_t)N * 2048 / 4);

  for (int L = 0; L < 4; ++L) {
    const int K = fi[L], C = fo[L];
    const int b = 2 + L * 8;
    const float scale = (float)(1.0 / sqrt((double)C));
    transp_f16_k<<<dim3(K / 32, C / 32, 4), 256, 0, stream>>>(
        (const float*)d_in[b + 0], (const float*)d_in[b + 2],
        (const float*)d_in[b + 4], (const float*)d_in[b + 6], Wt, K, C);
    const int NX = (N + 127) / 128;
    const int NY = 4 * C / 128;
    gemm_f16_k<<<NX * NY, 256, 0, stream>>>(
        Hb, Wt, (const float*)d_in[b + 1], (const float*)d_in[b + 3],
        (const float*)d_in[b + 5], (const float*)d_in[b + 7], Qh, Kh, Vh, dout,
        N, K, C, NX, NY);
    attn_fused2_k<<<N, 256, 0, stream>>>(Qh, Kh, Vh, rowptr, csr_src, logits,
                                         dout, Hb, C, scale, elu[L],
                                         L < 3 ? 1 : 0);
  }
}

// Round 11
// 1653.842 us; speedup vs baseline: 6.2601x; 1.0135x over previous
//
#include <hip/hip_runtime.h>
#include <cmath>
#include <cstddef>
#include <cstdint>

typedef __attribute__((ext_vector_type(8))) _Float16 half8_t;
typedef __attribute__((ext_vector_type(4))) _Float16 half4_t;
typedef __attribute__((ext_vector_type(2))) _Float16 half2_t;
typedef __attribute__((ext_vector_type(4))) float f32x4;

// ---------------------------------------------------------------------------
// helpers
// ---------------------------------------------------------------------------
__device__ __forceinline__ float dot2f16(half2_t a, half2_t b, float c) {
#if __has_builtin(__builtin_amdgcn_fdot2)
  return __builtin_amdgcn_fdot2(a, b, c, false);
#else
  return c + (float)a.x * (float)b.x + (float)a.y * (float)b.y;
#endif
}

// async global -> LDS, 16B per lane (wave-uniform LDS base + lane*16)
__device__ __forceinline__ void gload16(const unsigned short* g,
                                        unsigned short* l) {
  __builtin_amdgcn_global_load_lds(
      (const __attribute__((address_space(1))) unsigned int*)g,
      (__attribute__((address_space(3))) unsigned int*)l, 16, 0, 0);
}

// ---------------------------------------------------------------------------
// cast fp32 -> fp16 (vectorized)
// ---------------------------------------------------------------------------
__global__ __launch_bounds__(256) void cast_f16_k(
    const float* __restrict__ in, unsigned short* __restrict__ out, size_t n4) {
  size_t i = (size_t)blockIdx.x * blockDim.x + threadIdx.x;
  if (i >= n4) return;
  float4 v = ((const float4*)in)[i];
  half4_t h;
  h.x = (_Float16)v.x;
  h.y = (_Float16)v.y;
  h.z = (_Float16)v.z;
  h.w = (_Float16)v.w;
  ((half4_t*)out)[i] = h;
}

// ---------------------------------------------------------------------------
// Weight transpose, 4 matrices per launch (z = matrix):
// W[K][C] fp32 -> T[C][K] fp16 at offset z*C*K.
// ---------------------------------------------------------------------------
__global__ __launch_bounds__(256) void transp_f16_k(
    const float* __restrict__ W0, const float* __restrict__ W1,
    const float* __restrict__ W2, const float* __restrict__ W3,
    unsigned short* __restrict__ T, int K, int C) {
  __shared__ float t[32][33];
  const int m = blockIdx.z;
  const float* W = (m == 0) ? W0 : (m == 1) ? W1 : (m == 2) ? W2 : W3;
  _Float16* th = (_Float16*)T + (size_t)m * C * K;
  int k0 = blockIdx.x * 32, c0 = blockIdx.y * 32;
  int tx = threadIdx.x & 31, ty = threadIdx.x >> 5;  // ty 0..7
#pragma unroll
  for (int r = 0; r < 4; ++r)
    t[ty + r * 8][tx] = W[(size_t)(k0 + ty + r * 8) * C + c0 + tx];
  __syncthreads();
#pragma unroll
  for (int r = 0; r < 4; ++r) {
    int c = ty + r * 8;
    th[(size_t)(c0 + c) * K + k0 + tx] = (_Float16)t[tx][c];
  }
}

// ---------------------------------------------------------------------------
// Fused per-layer GEMM (fp16): [q|k|v|s] = X @ Wt^T + bias
// X fp16 [M][K]; Wt fp16 [4C][K]. q,k,v -> fp16; s -> fp32.
// 3-buffer LDS, depth-2 prefetch, counted vmcnt (never 0 mid-loop),
// raw s_barrier (one per K-step). Column-fast + bijective XCD remap.
// ---------------------------------------------------------------------------
__global__ __launch_bounds__(256) void gemm_f16_k(
    const unsigned short* __restrict__ Ab, const unsigned short* __restrict__ Wt,
    const float* __restrict__ bq, const float* __restrict__ bk,
    const float* __restrict__ bv, const float* __restrict__ bs,
    unsigned short* __restrict__ Qh, unsigned short* __restrict__ Kh,
    unsigned short* __restrict__ Vh, float* __restrict__ S, int M, int K,
    int C, int NX, int NY) {
  __shared__ unsigned short lds[3][2][4096];  // [buf][A|B][128*32] fp16

  const int nwg = NX * NY;
  const int bid = blockIdx.x;
  const int qq = nwg >> 3, rr = nwg & 7;
  const int xcd = bid & 7, idx = bid >> 3;
  const int wgid =
      (xcd < rr ? xcd * (qq + 1) : rr * (qq + 1) + (xcd - rr) * qq) + idx;
  const int by = wgid % NY, bx = wgid / NY;

  const int bm = bx * 128, n0 = by * 128;
  const int kind = n0 / C;  // 0=q 1=k 2=v 3=s
  const int tid = threadIdx.x;
  const int lane = tid & 63, w = tid >> 6;
  const int wm = w >> 1, wn = w & 1;
  const int fr = lane & 15, kg = lane >> 4;

  const int srow = w * 32 + (lane >> 2);
  const int soff = (lane & 3) * 8;
  const size_t ga0 = (size_t)min(bm + srow, M - 1) * K + soff;
  const size_t ga1 = (size_t)min(bm + srow + 16, M - 1) * K + soff;
  const size_t gb0 = (size_t)(n0 + srow) * K + soff;
  const size_t gb1 = (size_t)(n0 + srow + 16) * K + soff;
  const int l0 = w * 1024, l1 = w * 1024 + 512;

  f32x4 acc[4][4];
#pragma unroll
  for (int i = 0; i < 4; ++i)
#pragma unroll
    for (int j = 0; j < 4; ++j) acc[i][j] = (f32x4)0.f;

  auto STAGE = [&](int buf, int ko) {
    gload16(Ab + ga0 + ko, &lds[buf][0][l0]);
    gload16(Ab + ga1 + ko, &lds[buf][0][l1]);
    gload16(Wt + gb0 + ko, &lds[buf][1][l0]);
    gload16(Wt + gb1 + ko, &lds[buf][1][l1]);
  };

  const int T = K / 32;
  STAGE(0, 0);
  STAGE(1, 32);

  int buf = 0;
  for (int t = 0; t < T; ++t) {
    if (t + 1 < T)
      asm volatile("s_waitcnt vmcnt(4)" ::: "memory");  // tile t retired
    else
      asm volatile("s_waitcnt vmcnt(0)" ::: "memory");  // final drain
    __builtin_amdgcn_s_barrier();   // all waves' tile-t DMA visible
    asm volatile("" ::: "memory");  // no LDS reads hoisted above this point
    if (t + 2 < T) {
      int nb = buf + 2;
      if (nb >= 3) nb -= 3;
      STAGE(nb, (t + 2) * 32);  // overwrites buffer whose reads retired at t-1
    }
    const unsigned short* As = lds[buf][0];
    const unsigned short* Bs = lds[buf][1];
    half8_t ah[4], bh[4];
#pragma unroll
    for (int i = 0; i < 4; ++i) {
      ah[i] = *(const half8_t*)(As + (wm * 64 + i * 16 + fr) * 32 + kg * 8);
      bh[i] = *(const half8_t*)(Bs + (wn * 64 + i * 16 + fr) * 32 + kg * 8);
    }
#pragma unroll
    for (int i = 0; i < 4; ++i)
#pragma unroll
      for (int j = 0; j < 4; ++j)
        acc[i][j] = __builtin_amdgcn_mfma_f32_16x16x32_f16(ah[i], bh[j],
                                                           acc[i][j], 0, 0, 0);
    asm volatile("s_waitcnt lgkmcnt(0)" ::: "memory");  // my LDS reads retired
    buf = (buf == 2) ? 0 : buf + 1;
  }

  const float* bptr = (kind == 0) ? bq : (kind == 1) ? bk : (kind == 2) ? bv : bs;
  const int cbase = (n0 - kind * C) + wn * 64;
  float bvv[4];
#pragma unroll
  for (int j = 0; j < 4; ++j) bvv[j] = bptr[cbase + j * 16 + fr];

  unsigned short* obu = (kind == 0) ? Qh : (kind == 1) ? Kh : Vh;
  _Float16* ob = (_Float16*)obu;
#pragma unroll
  for (int i = 0; i < 4; ++i) {
#pragma unroll
    for (int r = 0; r < 4; ++r) {
      int gr = bm + wm * 64 + i * 16 + kg * 4 + r;
      if (gr < M) {
        if (kind == 3) {
#pragma unroll
          for (int j = 0; j < 4; ++j)
            S[(size_t)gr * C + cbase + j * 16 + fr] = acc[i][j][r] + bvv[j];
        } else {
#pragma unroll
          for (int j = 0; j < 4; ++j)
            ob[(size_t)gr * C + cbase + j * 16 + fr] =
                (_Float16)(acc[i][j][r] + bvv[j]);
        }
      }
    }
  }
}

// ---------------------------------------------------------------------------
// Fused attention (fp16 q/k/v). skipio holds the skip GEMM output (fp32).
// ---------------------------------------------------------------------------
__global__ __launch_bounds__(256) void attn_fused2_k(
    const unsigned short* __restrict__ Qh, const unsigned short* __restrict__ Kh,
    const unsigned short* __restrict__ Vh, const int* __restrict__ rowptr,
    const int* __restrict__ csr_src, float* __restrict__ gscratch,
    float* __restrict__ skipio, unsigned short* __restrict__ Hb, int C,
    float scale, int do_elu, int writeH) {
  __shared__ _Float16 qs[2048];
  __shared__ float ebuf[512];
  __shared__ int ssrc[512];
  __shared__ float wred[8];
  const int i = blockIdx.x;
  const int tid = threadIdx.x;
  const int lane = tid & 63, wid = tid >> 6;
  const int beg = rowptr[i], end = rowptr[i + 1];
  const int deg = end - beg;
  const bool sm = (deg <= 512);

  for (int c0 = tid * 4; c0 < C; c0 += 1024)
    *(uint2*)&qs[c0] = *(const uint2*)(Qh + (size_t)i * C + c0);
  if (sm)
    for (int p = tid; p < deg; p += 256) ssrc[p] = csr_src[beg + p];
  if (tid < 8) wred[tid] = (tid < 4) ? -INFINITY : 0.f;
  __syncthreads();

  if (deg > 0) {
    float wmaxv = -INFINITY;
    for (int ep = wid; ep < deg; ep += 4) {
      int s = sm ? ssrc[ep] : csr_src[beg + ep];
      const unsigned short* kr = Kh + (size_t)s * C;
      float sum = 0.f;
      for (int c0 = lane * 8; c0 < C; c0 += 512) {
        uint4 kk = *(const uint4*)(kr + c0);
        uint4 qq4 = *(const uint4*)&qs[c0];
        const half2_t* kp = (const half2_t*)&kk;
        const half2_t* qp = (const half2_t*)&qq4;
        sum = dot2f16(kp[0], qp[0], sum);
        sum = dot2f16(kp[1], qp[1], sum);
        sum = dot2f16(kp[2], qp[2], sum);
        sum = dot2f16(kp[3], qp[3], sum);
      }
#pragma unroll
      for (int o = 32; o; o >>= 1) sum += __shfl_xor(sum, o);
      float lg = sum * scale;
      if (lane == 0) {
        if (sm) ebuf[ep] = lg; else gscratch[beg + ep] = lg;
      }
      wmaxv = fmaxf(wmaxv, lg);
    }
    if (lane == 0) wred[wid] = wmaxv;
    __syncthreads();
    float m = fmaxf(fmaxf(wred[0], wred[1]), fmaxf(wred[2], wred[3]));

    float part = 0.f;
    for (int ep = tid; ep < deg; ep += 256) {
      float lg = sm ? ebuf[ep] : gscratch[beg + ep];
      float e = expf(lg - m);
      if (sm) ebuf[ep] = e; else gscratch[beg + ep] = e;
      part += e;
    }
#pragma unroll
    for (int o = 32; o; o >>= 1) part += __shfl_xor(part, o);
    if (lane == 0) wred[4 + wid] = part;
  }
  __syncthreads();

  float total = wred[4] + wred[5] + wred[6] + wred[7];
  float denom = 1.f / (total + 1e-16f);
  const int cpt = C >> 8;  // 4 or 8 cols per thread
  const int col0 = tid * cpt;
  float acc[8];
#pragma unroll
  for (int j = 0; j < 8; ++j) acc[j] = 0.f;

  for (int ep = 0; ep < deg; ++ep) {
    float a = (sm ? ebuf[ep] : gscratch[beg + ep]) * denom;
    int s = sm ? ssrc[ep] : csr_src[beg + ep];
    const unsigned short* vr = Vh + (size_t)s * C + col0;
    if (cpt == 4) {
      ushort4 pv = *(const ushort4*)vr;
      const _Float16* ph = (const _Float16*)&pv;
#pragma unroll
      for (int u = 0; u < 4; ++u) acc[u] = fmaf(a, (float)ph[u], acc[u]);
    } else {
      uint4 pv = *(const uint4*)vr;
      const _Float16* ph = (const _Float16*)&pv;
#pragma unroll
      for (int u = 0; u < 8; ++u) acc[u] = fmaf(a, (float)ph[u], acc[u]);
    }
  }

  float* srow = skipio + (size_t)i * C + col0;
#pragma unroll
  for (int v4 = 0; v4 < 2; ++v4) {
    if (v4 * 4 < cpt) {
      float4 o = *(const float4*)(srow + v4 * 4);
      o.x += acc[v4 * 4 + 0];
      o.y += acc[v4 * 4 + 1];
      o.z += acc[v4 * 4 + 2];
      o.w += acc[v4 * 4 + 3];
      if (do_elu) {
        o.x = o.x > 0.f ? o.x : expm1f(o.x);
        o.y = o.y > 0.f ? o.y : expm1f(o.y);
        o.z = o.z > 0.f ? o.z : expm1f(o.z);
        o.w = o.w > 0.f ? o.w : expm1f(o.w);
      }
      if (writeH) {
        half4_t h;
        h.x = (_Float16)o.x;
        h.y = (_Float16)o.y;
        h.z = (_Float16)o.z;
        h.w = (_Float16)o.w;
        *(half4_t*)((_Float16*)Hb + (size_t)i * C + col0 + v4 * 4) = h;
      } else {
        *(float4*)(srow + v4 * 4) = o;
      }
    }
  }
}

// ---------------------------------------------------------------------------
// CSR build
// ---------------------------------------------------------------------------
__global__ void count_deg_k(const int* __restrict__ dst, int E,
                            int* __restrict__ cnt) {
  int e = blockIdx.x * blockDim.x + threadIdx.x;
  if (e < E) atomicAdd(&cnt[dst[e]], 1);
}

__global__ void scan_k(const int* __restrict__ cnt, int* __restrict__ rowptr,
                       int N) {
  __shared__ int part[1024];
  int t = threadIdx.x;
  int per = (N + 1023) >> 10;
  int base = t * per;
  int s = 0;
  for (int i = 0; i < per; ++i) {
    int idx = base + i;
    if (idx < N) s += cnt[idx];
  }
  part[t] = s;
  __syncthreads();
  for (int off = 1; off < 1024; off <<= 1) {
    int v = (t >= off) ? part[t - off] : 0;
    __syncthreads();
    part[t] += v;
    __syncthreads();
  }
  int run = part[t] - s;
  for (int i = 0; i < per; ++i) {
    int idx = base + i;
    if (idx < N) {
      rowptr[idx] = run;
      run += cnt[idx];
    }
  }
  if (t == 1023) rowptr[N] = part[1023];
}

__global__ void scatter_csr_k(const int* __restrict__ src,
                              const int* __restrict__ dst, int E,
                              const int* __restrict__ rowptr,
                              int* __restrict__ fill,
                              int* __restrict__ csr_src) {
  int e = blockIdx.x * blockDim.x + threadIdx.x;
  if (e >= E) return;
  int d = dst[e];
  int pos = rowptr[d] + atomicAdd(&fill[d], 1);
  csr_src[pos] = src[e];
}

// ---------------------------------------------------------------------------
extern "C" void kernel_launch(void* const* d_in, const int* in_sizes, int n_in,
                              void* d_out, int out_size, void* d_ws,
                              size_t ws_size, hipStream_t stream) {
  const float* x = (const float*)d_in[0];
  const int* eidx = (const int*)d_in[1];
  const int N = in_sizes[0] / 2048;
  const int E = in_sizes[1] / 2;
  const int* srcA = eidx;
  const int* dstA = eidx + E;
  float* dout = (float*)d_out;

  char* p = (char*)d_ws;
  auto alloc = [&](size_t bytes) {
    void* r = (void*)p;
    p += (bytes + 255) & ~(size_t)255;
    return r;
  };

  float* logits = (float*)alloc((size_t)E * 4);
  int* rowptr = (int*)alloc((size_t)(N + 1) * 4);
  int* cnt = (int*)alloc((size_t)N * 4);
  int* fill = (int*)alloc((size_t)N * 4);
  int* csr_src = (int*)alloc((size_t)E * 4);

  hipMemsetAsync(cnt, 0, (size_t)N * 4, stream);
  hipMemsetAsync(fill, 0, (size_t)N * 4, stream);
  count_deg_k<<<(E + 255) / 256, 256, 0, stream>>>(dstA, E, cnt);
  scan_k<<<1, 1024, 0, stream>>>(cnt, rowptr, N);
  scatter_csr_k<<<(E + 255) / 256, 256, 0, stream>>>(srcA, dstA, E, rowptr,
                                                     fill, csr_src);

  const size_t szH = (size_t)N * 2048 * 2;          // fp16 [N][2048]
  const size_t szWt = (size_t)4 * 1024 * 2048 * 2;  // fp16 [4C][K] max

  unsigned short* Hb = (unsigned short*)alloc(szH);
  unsigned short* Qh = (unsigned short*)alloc(szH);
  unsigned short* Kh = (unsigned short*)alloc(szH);
  unsigned short* Vh = (unsigned short*)alloc(szH);
  unsigned short* Wt = (unsigned short*)alloc(szWt);

  const int fi[4] = {2048, 1024, 2048, 1024};
  const int fo[4] = {1024, 2048, 1024, 2048};
  const int elu[4] = {1, 0, 1, 0};

  cast_f16_k<<<(int)(((size_t)N * 2048 / 4 + 255) / 256), 256, 0, stream>>>(
      x, Hb, (size_t)N * 2048 / 4);

  for (int L = 0; L < 4; ++L) {
    const int K = fi[L], C = fo[L];
    const int b = 2 + L * 8;
    const float scale = (float)(1.0 / sqrt((double)C));
    transp_f16_k<<<dim3(K / 32, C / 32, 4), 256, 0, stream>>>(
        (const float*)d_in[b + 0], (const float*)d_in[b + 2],
        (const float*)d_in[b + 4], (const float*)d_in[b + 6], Wt, K, C);
    const int NX = (N + 127) / 128;
    const int NY = 4 * C / 128;
    gemm_f16_k<<<NX * NY, 256, 0, stream>>>(
        Hb, Wt, (const float*)d_in[b + 1], (const float*)d_in[b + 3],
        (const float*)d_in[b + 5], (const float*)d_in[b + 7], Qh, Kh, Vh, dout,
        N, K, C, NX, NY);
    attn_fused2_k<<<N, 256, 0, stream>>>(Qh, Kh, Vh, rowptr, csr_src, logits,
                                         dout, Hb, C, scale, elu[L],
                                         L < 3 ? 1 : 0);
  }
}

// Round 12
// 1514.644 us; speedup vs baseline: 6.8354x; 1.0919x over previous
//
#include <hip/hip_runtime.h>
#include <cmath>
#include <cstddef>
#include <cstdint>

typedef __attribute__((ext_vector_type(8))) _Float16 half8_t;
typedef __attribute__((ext_vector_type(4))) _Float16 half4_t;
typedef __attribute__((ext_vector_type(2))) _Float16 half2_t;
typedef __attribute__((ext_vector_type(4))) float f32x4;

// ---------------------------------------------------------------------------
// helpers
// ---------------------------------------------------------------------------
__device__ __forceinline__ float dot2f16(half2_t a, half2_t b, float c) {
#if __has_builtin(__builtin_amdgcn_fdot2)
  return __builtin_amdgcn_fdot2(a, b, c, false);
#else
  return c + (float)a.x * (float)b.x + (float)a.y * (float)b.y;
#endif
}

// async global -> LDS, 16B per lane (wave-uniform LDS base + lane*16)
__device__ __forceinline__ void gload16(const unsigned short* g,
                                        unsigned short* l) {
  __builtin_amdgcn_global_load_lds(
      (const __attribute__((address_space(1))) unsigned int*)g,
      (__attribute__((address_space(3))) unsigned int*)l, 16, 0, 0);
}

// ---------------------------------------------------------------------------
// cast fp32 -> fp16 (vectorized)
// ---------------------------------------------------------------------------
__global__ __launch_bounds__(256) void cast_f16_k(
    const float* __restrict__ in, unsigned short* __restrict__ out, size_t n4) {
  size_t i = (size_t)blockIdx.x * blockDim.x + threadIdx.x;
  if (i >= n4) return;
  float4 v = ((const float4*)in)[i];
  half4_t h;
  h.x = (_Float16)v.x;
  h.y = (_Float16)v.y;
  h.z = (_Float16)v.z;
  h.w = (_Float16)v.w;
  ((half4_t*)out)[i] = h;
}

// ---------------------------------------------------------------------------
// Weight transpose, 4 matrices per launch (z = matrix):
// W[K][C] fp32 -> T[C][K] fp16 at offset z*C*K.
// ---------------------------------------------------------------------------
__global__ __launch_bounds__(256) void transp_f16_k(
    const float* __restrict__ W0, const float* __restrict__ W1,
    const float* __restrict__ W2, const float* __restrict__ W3,
    unsigned short* __restrict__ T, int K, int C) {
  __shared__ float t[32][33];
  const int m = blockIdx.z;
  const float* W = (m == 0) ? W0 : (m == 1) ? W1 : (m == 2) ? W2 : W3;
  _Float16* th = (_Float16*)T + (size_t)m * C * K;
  int k0 = blockIdx.x * 32, c0 = blockIdx.y * 32;
  int tx = threadIdx.x & 31, ty = threadIdx.x >> 5;  // ty 0..7
#pragma unroll
  for (int r = 0; r < 4; ++r)
    t[ty + r * 8][tx] = W[(size_t)(k0 + ty + r * 8) * C + c0 + tx];
  __syncthreads();
#pragma unroll
  for (int r = 0; r < 4; ++r) {
    int c = ty + r * 8;
    th[(size_t)(c0 + c) * K + k0 + tx] = (_Float16)t[tx][c];
  }
}

// ---------------------------------------------------------------------------
// Fused per-layer GEMM (fp16): [q|k|v|s] = X @ Wt^T + bias
// 256x128 tile, 512 threads = 8 waves (4x2). 3-buffer LDS (72KB),
// depth-2 prefetch, counted vmcnt (never 0 mid-loop), raw s_barrier.
// Column-fast + bijective XCD remap for A-panel L2 reuse.
// ---------------------------------------------------------------------------
__global__ __launch_bounds__(512) void gemm_f16_k(
    const unsigned short* __restrict__ Ab, const unsigned short* __restrict__ Wt,
    const float* __restrict__ bq, const float* __restrict__ bk,
    const float* __restrict__ bv, const float* __restrict__ bs,
    unsigned short* __restrict__ Qh, unsigned short* __restrict__ Kh,
    unsigned short* __restrict__ Vh, float* __restrict__ S, int M, int K,
    int C, int NX, int NY) {
  // per buffer: A = 256x32 fp16 (16KB) at [0], B = 128x32 fp16 (8KB) at [8192]
  __shared__ unsigned short lds[3][12288];

  const int nwg = NX * NY;
  const int bid = blockIdx.x;
  const int qq = nwg >> 3, rr = nwg & 7;
  const int xcd = bid & 7, idx = bid >> 3;
  const int wgid =
      (xcd < rr ? xcd * (qq + 1) : rr * (qq + 1) + (xcd - rr) * qq) + idx;
  const int by = wgid % NY, bx = wgid / NY;

  const int bm = bx * 256, n0 = by * 128;
  const int kind = n0 / C;  // 0=q 1=k 2=v 3=s
  const int tid = threadIdx.x;
  const int lane = tid & 63, w = tid >> 6;  // w 0..7
  const int wm = w >> 1, wn = w & 1;        // 4x2 wave grid
  const int fr = lane & 15, kg = lane >> 4;

  // staging: wave w covers A rows [w*16, w*16+16) and [128+w*16, ...),
  // B rows [w*16, w*16+16); 4 lanes per row, 8 fp16 (16B) per lane.
  const int srow = w * 16 + (lane >> 2);  // 0..127
  const int soff = (lane & 3) * 8;
  const size_t ga0 = (size_t)min(bm + srow, M - 1) * K + soff;
  const size_t ga1 = (size_t)min(bm + srow + 128, M - 1) * K + soff;
  const size_t gb0 = (size_t)(n0 + srow) * K + soff;
  const int la0 = w * 512;         // ushort offsets
  const int la1 = 4096 + w * 512;
  const int lb0 = 8192 + w * 512;

  f32x4 acc[4][4];
#pragma unroll
  for (int i = 0; i < 4; ++i)
#pragma unroll
    for (int j = 0; j < 4; ++j) acc[i][j] = (f32x4)0.f;

  auto STAGE = [&](int buf, int ko) {
    gload16(Ab + ga0 + ko, &lds[buf][la0]);
    gload16(Ab + ga1 + ko, &lds[buf][la1]);
    gload16(Wt + gb0 + ko, &lds[buf][lb0]);
  };

  const int T = K / 32;
  STAGE(0, 0);
  STAGE(1, 32);

  int buf = 0;
  for (int t = 0; t < T; ++t) {
    if (t + 1 < T)
      asm volatile("s_waitcnt vmcnt(3)" ::: "memory");  // tile t's 3 retired
    else
      asm volatile("s_waitcnt vmcnt(0)" ::: "memory");  // final drain
    __builtin_amdgcn_s_barrier();   // all waves' tile-t DMA visible
    asm volatile("" ::: "memory");  // no LDS reads hoisted above this point
    if (t + 2 < T) {
      int nb = buf + 2;
      if (nb >= 3) nb -= 3;
      STAGE(nb, (t + 2) * 32);  // overwrites buffer whose reads retired at t-1
    }
    const unsigned short* As = lds[buf];
    const unsigned short* Bs = lds[buf] + 8192;
    half8_t ah[4], bh[4];
#pragma unroll
    for (int i = 0; i < 4; ++i) {
      ah[i] = *(const half8_t*)(As + (wm * 64 + i * 16 + fr) * 32 + kg * 8);
      bh[i] = *(const half8_t*)(Bs + (wn * 64 + i * 16 + fr) * 32 + kg * 8);
    }
#pragma unroll
    for (int i = 0; i < 4; ++i)
#pragma unroll
      for (int j = 0; j < 4; ++j)
        acc[i][j] = __builtin_amdgcn_mfma_f32_16x16x32_f16(ah[i], bh[j],
                                                           acc[i][j], 0, 0, 0);
    asm volatile("s_waitcnt lgkmcnt(0)" ::: "memory");  // my LDS reads retired
    buf = (buf == 2) ? 0 : buf + 1;
  }

  const float* bptr = (kind == 0) ? bq : (kind == 1) ? bk : (kind == 2) ? bv : bs;
  const int cbase = (n0 - kind * C) + wn * 64;
  float bvv[4];
#pragma unroll
  for (int j = 0; j < 4; ++j) bvv[j] = bptr[cbase + j * 16 + fr];

  unsigned short* obu = (kind == 0) ? Qh : (kind == 1) ? Kh : Vh;
  _Float16* ob = (_Float16*)obu;
#pragma unroll
  for (int i = 0; i < 4; ++i) {
#pragma unroll
    for (int r = 0; r < 4; ++r) {
      int gr = bm + wm * 64 + i * 16 + kg * 4 + r;
      if (gr < M) {
        if (kind == 3) {
#pragma unroll
          for (int j = 0; j < 4; ++j)
            S[(size_t)gr * C + cbase + j * 16 + fr] = acc[i][j][r] + bvv[j];
        } else {
#pragma unroll
          for (int j = 0; j < 4; ++j)
            ob[(size_t)gr * C + cbase + j * 16 + fr] =
                (_Float16)(acc[i][j][r] + bvv[j]);
        }
      }
    }
  }
}

// ---------------------------------------------------------------------------
// Fused attention (fp16 q/k/v). skipio holds the skip GEMM output (fp32).
// ---------------------------------------------------------------------------
__global__ __launch_bounds__(256) void attn_fused2_k(
    const unsigned short* __restrict__ Qh, const unsigned short* __restrict__ Kh,
    const unsigned short* __restrict__ Vh, const int* __restrict__ rowptr,
    const int* __restrict__ csr_src, float* __restrict__ gscratch,
    float* __restrict__ skipio, unsigned short* __restrict__ Hb, int C,
    float scale, int do_elu, int writeH) {
  __shared__ _Float16 qs[2048];
  __shared__ float ebuf[512];
  __shared__ int ssrc[512];
  __shared__ float wred[8];
  const int i = blockIdx.x;
  const int tid = threadIdx.x;
  const int lane = tid & 63, wid = tid >> 6;
  const int beg = rowptr[i], end = rowptr[i + 1];
  const int deg = end - beg;
  const bool sm = (deg <= 512);

  for (int c0 = tid * 4; c0 < C; c0 += 1024)
    *(uint2*)&qs[c0] = *(const uint2*)(Qh + (size_t)i * C + c0);
  if (sm)
    for (int p = tid; p < deg; p += 256) ssrc[p] = csr_src[beg + p];
  if (tid < 8) wred[tid] = (tid < 4) ? -INFINITY : 0.f;
  __syncthreads();

  if (deg > 0) {
    float wmaxv = -INFINITY;
    for (int ep = wid; ep < deg; ep += 4) {
      int s = sm ? ssrc[ep] : csr_src[beg + ep];
      const unsigned short* kr = Kh + (size_t)s * C;
      float sum = 0.f;
      for (int c0 = lane * 8; c0 < C; c0 += 512) {
        uint4 kk = *(const uint4*)(kr + c0);
        uint4 qq4 = *(const uint4*)&qs[c0];
        const half2_t* kp = (const half2_t*)&kk;
        const half2_t* qp = (const half2_t*)&qq4;
        sum = dot2f16(kp[0], qp[0], sum);
        sum = dot2f16(kp[1], qp[1], sum);
        sum = dot2f16(kp[2], qp[2], sum);
        sum = dot2f16(kp[3], qp[3], sum);
      }
#pragma unroll
      for (int o = 32; o; o >>= 1) sum += __shfl_xor(sum, o);
      float lg = sum * scale;
      if (lane == 0) {
        if (sm) ebuf[ep] = lg; else gscratch[beg + ep] = lg;
      }
      wmaxv = fmaxf(wmaxv, lg);
    }
    if (lane == 0) wred[wid] = wmaxv;
    __syncthreads();
    float m = fmaxf(fmaxf(wred[0], wred[1]), fmaxf(wred[2], wred[3]));

    float part = 0.f;
    for (int ep = tid; ep < deg; ep += 256) {
      float lg = sm ? ebuf[ep] : gscratch[beg + ep];
      float e = expf(lg - m);
      if (sm) ebuf[ep] = e; else gscratch[beg + ep] = e;
      part += e;
    }
#pragma unroll
    for (int o = 32; o; o >>= 1) part += __shfl_xor(part, o);
    if (lane == 0) wred[4 + wid] = part;
  }
  __syncthreads();

  float total = wred[4] + wred[5] + wred[6] + wred[7];
  float denom = 1.f / (total + 1e-16f);
  const int cpt = C >> 8;  // 4 or 8 cols per thread
  const int col0 = tid * cpt;
  float acc[8];
#pragma unroll
  for (int j = 0; j < 8; ++j) acc[j] = 0.f;

  for (int ep = 0; ep < deg; ++ep) {
    float a = (sm ? ebuf[ep] : gscratch[beg + ep]) * denom;
    int s = sm ? ssrc[ep] : csr_src[beg + ep];
    const unsigned short* vr = Vh + (size_t)s * C + col0;
    if (cpt == 4) {
      ushort4 pv = *(const ushort4*)vr;
      const _Float16* ph = (const _Float16*)&pv;
#pragma unroll
      for (int u = 0; u < 4; ++u) acc[u] = fmaf(a, (float)ph[u], acc[u]);
    } else {
      uint4 pv = *(const uint4*)vr;
      const _Float16* ph = (const _Float16*)&pv;
#pragma unroll
      for (int u = 0; u < 8; ++u) acc[u] = fmaf(a, (float)ph[u], acc[u]);
    }
  }

  float* srow = skipio + (size_t)i * C + col0;
#pragma unroll
  for (int v4 = 0; v4 < 2; ++v4) {
    if (v4 * 4 < cpt) {
      float4 o = *(const float4*)(srow + v4 * 4);
      o.x += acc[v4 * 4 + 0];
      o.y += acc[v4 * 4 + 1];
      o.z += acc[v4 * 4 + 2];
      o.w += acc[v4 * 4 + 3];
      if (do_elu) {
        o.x = o.x > 0.f ? o.x : expm1f(o.x);
        o.y = o.y > 0.f ? o.y : expm1f(o.y);
        o.z = o.z > 0.f ? o.z : expm1f(o.z);
        o.w = o.w > 0.f ? o.w : expm1f(o.w);
      }
      if (writeH) {
        half4_t h;
        h.x = (_Float16)o.x;
        h.y = (_Float16)o.y;
        h.z = (_Float16)o.z;
        h.w = (_Float16)o.w;
        *(half4_t*)((_Float16*)Hb + (size_t)i * C + col0 + v4 * 4) = h;
      } else {
        *(float4*)(srow + v4 * 4) = o;
      }
    }
  }
}

// ---------------------------------------------------------------------------
// CSR build
// ---------------------------------------------------------------------------
__global__ void count_deg_k(const int* __restrict__ dst, int E,
                            int* __restrict__ cnt) {
  int e = blockIdx.x * blockDim.x + threadIdx.x;
  if (e < E) atomicAdd(&cnt[dst[e]], 1);
}

__global__ void scan_k(const int* __restrict__ cnt, int* __restrict__ rowptr,
                       int N) {
  __shared__ int part[1024];
  int t = threadIdx.x;
  int per = (N + 1023) >> 10;
  int base = t * per;
  int s = 0;
  for (int i = 0; i < per; ++i) {
    int idx = base + i;
    if (idx < N) s += cnt[idx];
  }
  part[t] = s;
  __syncthreads();
  for (int off = 1; off < 1024; off <<= 1) {
    int v = (t >= off) ? part[t - off] : 0;
    __syncthreads();
    part[t] += v;
    __syncthreads();
  }
  int run = part[t] - s;
  for (int i = 0; i < per; ++i) {
    int idx = base + i;
    if (idx < N) {
      rowptr[idx] = run;
      run += cnt[idx];
    }
  }
  if (t == 1023) rowptr[N] = part[1023];
}

__global__ void scatter_csr_k(const int* __restrict__ src,
                              const int* __restrict__ dst, int E,
                              const int* __restrict__ rowptr,
                              int* __restrict__ fill,
                              int* __restrict__ csr_src) {
  int e = blockIdx.x * blockDim.x + threadIdx.x;
  if (e >= E) return;
  int d = dst[e];
  int pos = rowptr[d] + atomicAdd(&fill[d], 1);
  csr_src[pos] = src[e];
}

// ---------------------------------------------------------------------------
extern "C" void kernel_launch(void* const* d_in, const int* in_sizes, int n_in,
                              void* d_out, int out_size, void* d_ws,
                              size_t ws_size, hipStream_t stream) {
  const float* x = (const float*)d_in[0];
  const int* eidx = (const int*)d_in[1];
  const int N = in_sizes[0] / 2048;
  const int E = in_sizes[1] / 2;
  const int* srcA = eidx;
  const int* dstA = eidx + E;
  float* dout = (float*)d_out;

  char* p = (char*)d_ws;
  auto alloc = [&](size_t bytes) {
    void* r = (void*)p;
    p += (bytes + 255) & ~(size_t)255;
    return r;
  };

  float* logits = (float*)alloc((size_t)E * 4);
  int* rowptr = (int*)alloc((size_t)(N + 1) * 4);
  int* cnt = (int*)alloc((size_t)N * 4);
  int* fill = (int*)alloc((size_t)N * 4);
  int* csr_src = (int*)alloc((size_t)E * 4);

  hipMemsetAsync(cnt, 0, (size_t)N * 4, stream);
  hipMemsetAsync(fill, 0, (size_t)N * 4, stream);
  count_deg_k<<<(E + 255) / 256, 256, 0, stream>>>(dstA, E, cnt);
  scan_k<<<1, 1024, 0, stream>>>(cnt, rowptr, N);
  scatter_csr_k<<<(E + 255) / 256, 256, 0, stream>>>(srcA, dstA, E, rowptr,
                                                     fill, csr_src);

  const size_t szH = (size_t)N * 2048 * 2;          // fp16 [N][2048]
  const size_t szWt = (size_t)4 * 1024 * 2048 * 2;  // fp16 [4C][K] max

  unsigned short* Hb = (unsigned short*)alloc(szH);
  unsigned short* Qh = (unsigned short*)alloc(szH);
  unsigned short* Kh = (unsigned short*)alloc(szH);
  unsigned short* Vh = (unsigned short*)alloc(szH);
  unsigned short* Wt = (unsigned short*)alloc(szWt);

  const int fi[4] = {2048, 1024, 2048, 1024};
  const int fo[4] = {1024, 2048, 1024, 2048};
  const int elu[4] = {1, 0, 1, 0};

  cast_f16_k<<<(int)(((size_t)N * 2048 / 4 + 255) / 256), 256, 0, stream>>>(
      x, Hb, (size_t)N * 2048 / 4);

  for (int L = 0; L < 4; ++L) {
    const int K = fi[L], C = fo[L];
    const int b = 2 + L * 8;
    const float scale = (float)(1.0 / sqrt((double)C));
    transp_f16_k<<<dim3(K / 32, C / 32, 4), 256, 0, stream>>>(
        (const float*)d_in[b + 0], (const float*)d_in[b + 2],
        (const float*)d_in[b + 4], (const float*)d_in[b + 6], Wt, K, C);
    const int NX = (N + 255) / 256;
    const int NY = 4 * C / 128;
    gemm_f16_k<<<NX * NY, 512, 0, stream>>>(
        Hb, Wt, (const float*)d_in[b + 1], (const float*)d_in[b + 3],
        (const float*)d_in[b + 5], (const float*)d_in[b + 7], Qh, Kh, Vh, dout,
        N, K, C, NX, NY);
    attn_fused2_k<<<N, 256, 0, stream>>>(Qh, Kh, Vh, rowptr, csr_src, logits,
                                         dout, Hb, C, scale, elu[L],
                                         L < 3 ? 1 : 0);
  }
}

// Round 15
// 1461.408 us; speedup vs baseline: 7.0844x; 1.0364x over previous
//
#include <hip/hip_runtime.h>
#include <cmath>
#include <cstddef>
#include <cstdint>

typedef __attribute__((ext_vector_type(8))) _Float16 half8_t;
typedef __attribute__((ext_vector_type(4))) _Float16 half4_t;
typedef __attribute__((ext_vector_type(2))) _Float16 half2_t;
typedef __attribute__((ext_vector_type(4))) float f32x4;

// ---------------------------------------------------------------------------
// helpers
// ---------------------------------------------------------------------------
__device__ __forceinline__ float dot2f16(half2_t a, half2_t b, float c) {
#if __has_builtin(__builtin_amdgcn_fdot2)
  return __builtin_amdgcn_fdot2(a, b, c, false);
#else
  return c + (float)a.x * (float)b.x + (float)a.y * (float)b.y;
#endif
}

// async global -> LDS, 16B per lane (wave-uniform LDS base + lane*16)
__device__ __forceinline__ void gload16(const unsigned short* g,
                                        unsigned short* l) {
  __builtin_amdgcn_global_load_lds(
      (const __attribute__((address_space(1))) unsigned int*)g,
      (__attribute__((address_space(3))) unsigned int*)l, 16, 0, 0);
}

// ---------------------------------------------------------------------------
// cast fp32 -> fp16 (vectorized)
// ---------------------------------------------------------------------------
__global__ __launch_bounds__(256) void cast_f16_k(
    const float* __restrict__ in, unsigned short* __restrict__ out, size_t n4) {
  size_t i = (size_t)blockIdx.x * blockDim.x + threadIdx.x;
  if (i >= n4) return;
  float4 v = ((const float4*)in)[i];
  half4_t h;
  h.x = (_Float16)v.x;
  h.y = (_Float16)v.y;
  h.z = (_Float16)v.z;
  h.w = (_Float16)v.w;
  ((half4_t*)out)[i] = h;
}

// ---------------------------------------------------------------------------
// Weight transpose, 4 matrices per launch (z = matrix):
// W[K][C] fp32 -> T[C][K] fp16 at offset z*C*K.
// ---------------------------------------------------------------------------
__global__ __launch_bounds__(256) void transp_f16_k(
    const float* __restrict__ W0, const float* __restrict__ W1,
    const float* __restrict__ W2, const float* __restrict__ W3,
    unsigned short* __restrict__ T, int K, int C) {
  __shared__ float t[32][33];
  const int m = blockIdx.z;
  const float* W = (m == 0) ? W0 : (m == 1) ? W1 : (m == 2) ? W2 : W3;
  _Float16* th = (_Float16*)T + (size_t)m * C * K;
  int k0 = blockIdx.x * 32, c0 = blockIdx.y * 32;
  int tx = threadIdx.x & 31, ty = threadIdx.x >> 5;  // ty 0..7
#pragma unroll
  for (int r = 0; r < 4; ++r)
    t[ty + r * 8][tx] = W[(size_t)(k0 + ty + r * 8) * C + c0 + tx];
  __syncthreads();
#pragma unroll
  for (int r = 0; r < 4; ++r) {
    int c = ty + r * 8;
    th[(size_t)(c0 + c) * K + k0 + tx] = (_Float16)t[tx][c];
  }
}

// ---------------------------------------------------------------------------
// Fused per-layer GEMM (fp16): [q|k|v|s] = X @ Wt^T + bias
// 256x128 tile, 512 threads = 8 waves (4x2). 3-buffer LDS (72KB),
// depth-2 prefetch, counted vmcnt, raw s_barrier.
// LDS chunk XOR-swizzle: source chunk (lane&3)^((lane>>2)&3), read kg^(fr&3).
// ---------------------------------------------------------------------------
__global__ __launch_bounds__(512) void gemm_f16_k(
    const unsigned short* __restrict__ Ab, const unsigned short* __restrict__ Wt,
    const float* __restrict__ bq, const float* __restrict__ bk,
    const float* __restrict__ bv, const float* __restrict__ bs,
    unsigned short* __restrict__ Qh, unsigned short* __restrict__ Kh,
    unsigned short* __restrict__ Vh, float* __restrict__ S, int M, int K,
    int C, int NX, int NY) {
  // per buffer: A = 256x32 fp16 (16KB) at [0], B = 128x32 fp16 (8KB) at [8192]
  __shared__ unsigned short lds[3][12288];

  const int nwg = NX * NY;
  const int bid = blockIdx.x;
  const int qq = nwg >> 3, rr = nwg & 7;
  const int xcd = bid & 7, idx = bid >> 3;
  const int wgid =
      (xcd < rr ? xcd * (qq + 1) : rr * (qq + 1) + (xcd - rr) * qq) + idx;
  const int by = wgid % NY, bx = wgid / NY;

  const int bm = bx * 256, n0 = by * 128;
  const int kind = n0 / C;  // 0=q 1=k 2=v 3=s
  const int tid = threadIdx.x;
  const int lane = tid & 63, w = tid >> 6;  // w 0..7
  const int wm = w >> 1, wn = w & 1;        // 4x2 wave grid
  const int fr = lane & 15, kg = lane >> 4;

  // staging: wave w covers A rows [w*16,+16) and [128+w*16,+16), B rows
  // [w*16,+16); 4 lanes/row, 16B/lane. Source chunk pre-swizzled so LDS slot
  // s holds global chunk s^(row&3); row&3 == (lane>>2)&3 for all three tiles.
  const int srow = w * 16 + (lane >> 2);  // 0..127
  const int soff = (((lane & 3) ^ ((lane >> 2) & 3))) * 8;
  const size_t ga0 = (size_t)min(bm + srow, M - 1) * K + soff;
  const size_t ga1 = (size_t)min(bm + srow + 128, M - 1) * K + soff;
  const size_t gb0 = (size_t)(n0 + srow) * K + soff;
  const int la0 = w * 512;  // ushort offsets
  const int la1 = 4096 + w * 512;
  const int lb0 = 8192 + w * 512;

  f32x4 acc[4][4];
#pragma unroll
  for (int i = 0; i < 4; ++i)
#pragma unroll
    for (int j = 0; j < 4; ++j) acc[i][j] = (f32x4)0.f;

  auto STAGE = [&](int buf, int ko) {
    gload16(Ab + ga0 + ko, &lds[buf][la0]);
    gload16(Ab + ga1 + ko, &lds[buf][la1]);
    gload16(Wt + gb0 + ko, &lds[buf][lb0]);
  };

  const int T = K / 32;
  STAGE(0, 0);
  STAGE(1, 32);

  const int rka = (kg ^ (fr & 3)) * 8;  // swizzled read chunk (ushorts)
  int buf = 0;
  for (int t = 0; t < T; ++t) {
    if (t + 1 < T)
      asm volatile("s_waitcnt vmcnt(3)" ::: "memory");  // tile t's 3 retired
    else
      asm volatile("s_waitcnt vmcnt(0)" ::: "memory");  // final drain
    __builtin_amdgcn_s_barrier();   // all waves' tile-t DMA visible
    asm volatile("" ::: "memory");  // no LDS reads hoisted above this point
    if (t + 2 < T) {
      int nb = buf + 2;
      if (nb >= 3) nb -= 3;
      STAGE(nb, (t + 2) * 32);  // overwrites buffer whose reads retired at t-1
    }
    const unsigned short* As = lds[buf];
    const unsigned short* Bs = lds[buf] + 8192;
    half8_t ah[4], bh[4];
#pragma unroll
    for (int i = 0; i < 4; ++i) {
      ah[i] = *(const half8_t*)(As + (wm * 64 + i * 16 + fr) * 32 + rka);
      bh[i] = *(const half8_t*)(Bs + (wn * 64 + i * 16 + fr) * 32 + rka);
    }
#pragma unroll
    for (int i = 0; i < 4; ++i)
#pragma unroll
      for (int j = 0; j < 4; ++j)
        acc[i][j] = __builtin_amdgcn_mfma_f32_16x16x32_f16(ah[i], bh[j],
                                                           acc[i][j], 0, 0, 0);
    asm volatile("s_waitcnt lgkmcnt(0)" ::: "memory");  // my LDS reads retired
    buf = (buf == 2) ? 0 : buf + 1;
  }

  const float* bptr = (kind == 0) ? bq : (kind == 1) ? bk : (kind == 2) ? bv : bs;
  const int cbase = (n0 - kind * C) + wn * 64;
  float bvv[4];
#pragma unroll
  for (int j = 0; j < 4; ++j) bvv[j] = bptr[cbase + j * 16 + fr];

  unsigned short* obu = (kind == 0) ? Qh : (kind == 1) ? Kh : Vh;
  _Float16* ob = (_Float16*)obu;
#pragma unroll
  for (int i = 0; i < 4; ++i) {
#pragma unroll
    for (int r = 0; r < 4; ++r) {
      int gr = bm + wm * 64 + i * 16 + kg * 4 + r;
      if (gr < M) {
        if (kind == 3) {
#pragma unroll
          for (int j = 0; j < 4; ++j)
            S[(size_t)gr * C + cbase + j * 16 + fr] = acc[i][j][r] + bvv[j];
        } else {
#pragma unroll
          for (int j = 0; j < 4; ++j)
            ob[(size_t)gr * C + cbase + j * 16 + fr] =
                (_Float16)(acc[i][j][r] + bvv[j]);
        }
      }
    }
  }
}

// ---------------------------------------------------------------------------
// Fused attention (fp16 q/k/v). skipio holds the skip GEMM output (fp32).
// MLP-tuned: 2-edge interleave in phase 1, 4-edge unroll in phase 3.
// ---------------------------------------------------------------------------
__global__ __launch_bounds__(256) void attn_fused2_k(
    const unsigned short* __restrict__ Qh, const unsigned short* __restrict__ Kh,
    const unsigned short* __restrict__ Vh, const int* __restrict__ rowptr,
    const int* __restrict__ csr_src, float* __restrict__ gscratch,
    float* __restrict__ skipio, unsigned short* __restrict__ Hb, int C,
    float scale, int do_elu, int writeH) {
  __shared__ _Float16 qs[2048];
  __shared__ float ebuf[512];
  __shared__ int ssrc[512];
  __shared__ float wred[8];
  const int i = blockIdx.x;
  const int tid = threadIdx.x;
  const int lane = tid & 63, wid = tid >> 6;
  const int beg = rowptr[i], end = rowptr[i + 1];
  const int deg = end - beg;
  const bool sm = (deg <= 512);

  for (int c0 = tid * 4; c0 < C; c0 += 1024)
    *(uint2*)&qs[c0] = *(const uint2*)(Qh + (size_t)i * C + c0);
  if (sm)
    for (int p = tid; p < deg; p += 256) ssrc[p] = csr_src[beg + p];
  if (tid < 8) wred[tid] = (tid < 4) ? -INFINITY : 0.f;
  __syncthreads();

  if (deg > 0) {
    float wmaxv = -INFINITY;
    if (sm) {
      // phase 1: 2 edges per wave, interleaved
      for (int ep = wid; ep < deg; ep += 8) {
        const int e1 = ep + 4;
        const bool h1 = e1 < deg;
        int s0 = ssrc[ep];
        int s1 = h1 ? ssrc[e1] : s0;
        const unsigned short* kr0 = Kh + (size_t)s0 * C;
        const unsigned short* kr1 = Kh + (size_t)s1 * C;
        float su0 = 0.f, su1 = 0.f;
        for (int c0 = lane * 8; c0 < C; c0 += 512) {
          uint4 k0 = *(const uint4*)(kr0 + c0);
          uint4 k1 = *(const uint4*)(kr1 + c0);
          uint4 qv = *(const uint4*)&qs[c0];
          const half2_t* kp0 = (const half2_t*)&k0;
          const half2_t* kp1 = (const half2_t*)&k1;
          const half2_t* qp = (const half2_t*)&qv;
#pragma unroll
          for (int u = 0; u < 4; ++u) {
            su0 = dot2f16(kp0[u], qp[u], su0);
            su1 = dot2f16(kp1[u], qp[u], su1);
          }
        }
#pragma unroll
        for (int o = 32; o; o >>= 1) {
          su0 += __shfl_xor(su0, o);
          su1 += __shfl_xor(su1, o);
        }
        float lg0 = su0 * scale;
        float lg1 = h1 ? su1 * scale : -INFINITY;
        if (lane == 0) {
          ebuf[ep] = lg0;
          if (h1) ebuf[e1] = lg1;
        }
        wmaxv = fmaxf(wmaxv, fmaxf(lg0, lg1));
      }
    } else {
      for (int ep = wid; ep < deg; ep += 4) {
        int s = csr_src[beg + ep];
        const unsigned short* kr = Kh + (size_t)s * C;
        float sum = 0.f;
        for (int c0 = lane * 8; c0 < C; c0 += 512) {
          uint4 kk = *(const uint4*)(kr + c0);
          uint4 qv = *(const uint4*)&qs[c0];
          const half2_t* kp = (const half2_t*)&kk;
          const half2_t* qp = (const half2_t*)&qv;
#pragma unroll
          for (int u = 0; u < 4; ++u) sum = dot2f16(kp[u], qp[u], sum);
        }
#pragma unroll
        for (int o = 32; o; o >>= 1) sum += __shfl_xor(sum, o);
        float lg = sum * scale;
        if (lane == 0) gscratch[beg + ep] = lg;
        wmaxv = fmaxf(wmaxv, lg);
      }
    }
    if (lane == 0) wred[wid] = wmaxv;
    __syncthreads();
    float m = fmaxf(fmaxf(wred[0], wred[1]), fmaxf(wred[2], wred[3]));

    float part = 0.f;
    for (int ep = tid; ep < deg; ep += 256) {
      float lg = sm ? ebuf[ep] : gscratch[beg + ep];
      float e = expf(lg - m);
      if (sm) ebuf[ep] = e; else gscratch[beg + ep] = e;
      part += e;
    }
#pragma unroll
    for (int o = 32; o; o >>= 1) part += __shfl_xor(part, o);
    if (lane == 0) wred[4 + wid] = part;
  }
  __syncthreads();

  float total = wred[4] + wred[5] + wred[6] + wred[7];
  float denom = 1.f / (total + 1e-16f);
  const int cpt = C >> 8;  // 4 or 8 cols per thread
  const int col0 = tid * cpt;
  float acc[8];
#pragma unroll
  for (int j = 0; j < 8; ++j) acc[j] = 0.f;

  // phase 3: aggregate alpha * v[src], 4-edge unroll
  if (sm) {
    int ep = 0;
    if (cpt == 8) {
      for (; ep + 4 <= deg; ep += 4) {
        float a0 = ebuf[ep] * denom, a1 = ebuf[ep + 1] * denom;
        float a2 = ebuf[ep + 2] * denom, a3 = ebuf[ep + 3] * denom;
        const unsigned short* v0 = Vh + (size_t)ssrc[ep] * C + col0;
        const unsigned short* v1 = Vh + (size_t)ssrc[ep + 1] * C + col0;
        const unsigned short* v2 = Vh + (size_t)ssrc[ep + 2] * C + col0;
        const unsigned short* v3 = Vh + (size_t)ssrc[ep + 3] * C + col0;
        uint4 p0 = *(const uint4*)v0, p1 = *(const uint4*)v1;
        uint4 p2 = *(const uint4*)v2, p3 = *(const uint4*)v3;
        const _Float16* h0 = (const _Float16*)&p0;
        const _Float16* h1 = (const _Float16*)&p1;
        const _Float16* h2 = (const _Float16*)&p2;
        const _Float16* h3 = (const _Float16*)&p3;
#pragma unroll
        for (int u = 0; u < 8; ++u) {
          acc[u] = fmaf(a0, (float)h0[u], acc[u]);
          acc[u] = fmaf(a1, (float)h1[u], acc[u]);
          acc[u] = fmaf(a2, (float)h2[u], acc[u]);
          acc[u] = fmaf(a3, (float)h3[u], acc[u]);
        }
      }
      for (; ep < deg; ++ep) {
        float a = ebuf[ep] * denom;
        uint4 pv = *(const uint4*)(Vh + (size_t)ssrc[ep] * C + col0);
        const _Float16* ph = (const _Float16*)&pv;
#pragma unroll
        for (int u = 0; u < 8; ++u) acc[u] = fmaf(a, (float)ph[u], acc[u]);
      }
    } else {
      for (; ep + 4 <= deg; ep += 4) {
        float a0 = ebuf[ep] * denom, a1 = ebuf[ep + 1] * denom;
        float a2 = ebuf[ep + 2] * denom, a3 = ebuf[ep + 3] * denom;
        ushort4 p0 = *(const ushort4*)(Vh + (size_t)ssrc[ep] * C + col0);
        ushort4 p1 = *(const ushort4*)(Vh + (size_t)ssrc[ep + 1] * C + col0);
        ushort4 p2 = *(const ushort4*)(Vh + (size_t)ssrc[ep + 2] * C + col0);
        ushort4 p3 = *(const ushort4*)(Vh + (size_t)ssrc[ep + 3] * C + col0);
        const _Float16* h0 = (const _Float16*)&p0;
        const _Float16* h1 = (const _Float16*)&p1;
        const _Float16* h2 = (const _Float16*)&p2;
        const _Float16* h3 = (const _Float16*)&p3;
#pragma unroll
        for (int u = 0; u < 4; ++u) {
          acc[u] = fmaf(a0, (float)h0[u], acc[u]);
          acc[u] = fmaf(a1, (float)h1[u], acc[u]);
          acc[u] = fmaf(a2, (float)h2[u], acc[u]);
          acc[u] = fmaf(a3, (float)h3[u], acc[u]);
        }
      }
      for (; ep < deg; ++ep) {
        float a = ebuf[ep] * denom;
        ushort4 pv = *(const ushort4*)(Vh + (size_t)ssrc[ep] * C + col0);
        const _Float16* ph = (const _Float16*)&pv;
#pragma unroll
        for (int u = 0; u < 4; ++u) acc[u] = fmaf(a, (float)ph[u], acc[u]);
      }
    }
  } else {
    for (int ep = 0; ep < deg; ++ep) {
      float a = gscratch[beg + ep] * denom;
      int s = csr_src[beg + ep];
      const unsigned short* vr = Vh + (size_t)s * C + col0;
      if (cpt == 4) {
        ushort4 pv = *(const ushort4*)vr;
        const _Float16* ph = (const _Float16*)&pv;
#pragma unroll
        for (int u = 0; u < 4; ++u) acc[u] = fmaf(a, (float)ph[u], acc[u]);
      } else {
        uint4 pv = *(const uint4*)vr;
        const _Float16* ph = (const _Float16*)&pv;
#pragma unroll
        for (int u = 0; u < 8; ++u) acc[u] = fmaf(a, (float)ph[u], acc[u]);
      }
    }
  }

  float* srow = skipio + (size_t)i * C + col0;
#pragma unroll
  for (int v4 = 0; v4 < 2; ++v4) {
    if (v4 * 4 < cpt) {
      float4 o = *(const float4*)(srow + v4 * 4);
      o.x += acc[v4 * 4 + 0];
      o.y += acc[v4 * 4 + 1];
      o.z += acc[v4 * 4 + 2];
      o.w += acc[v4 * 4 + 3];
      if (do_elu) {
        o.x = o.x > 0.f ? o.x : expm1f(o.x);
        o.y = o.y > 0.f ? o.y : expm1f(o.y);
        o.z = o.z > 0.f ? o.z : expm1f(o.z);
        o.w = o.w > 0.f ? o.w : expm1f(o.w);
      }
      if (writeH) {
        half4_t h;
        h.x = (_Float16)o.x;
        h.y = (_Float16)o.y;
        h.z = (_Float16)o.z;
        h.w = (_Float16)o.w;
        *(half4_t*)((_Float16*)Hb + (size_t)i * C + col0 + v4 * 4) = h;
      } else {
        *(float4*)(srow + v4 * 4) = o;
      }
    }
  }
}

// ---------------------------------------------------------------------------
// CSR build
// ---------------------------------------------------------------------------
__global__ void count_deg_k(const int* __restrict__ dst, int E,
                            int* __restrict__ cnt) {
  int e = blockIdx.x * blockDim.x + threadIdx.x;
  if (e < E) atomicAdd(&cnt[dst[e]], 1);
}

__global__ void scan_k(const int* __restrict__ cnt, int* __restrict__ rowptr,
                       int N) {
  __shared__ int part[1024];
  int t = threadIdx.x;
  int per = (N + 1023) >> 10;
  int base = t * per;
  int s = 0;
  for (int i = 0; i < per; ++i) {
    int idx = base + i;
    if (idx < N) s += cnt[idx];
  }
  part[t] = s;
  __syncthreads();
  for (int off = 1; off < 1024; off <<= 1) {
    int v = (t >= off) ? part[t - off] : 0;
    __syncthreads();
    part[t] += v;
    __syncthreads();
  }
  int run = part[t] - s;
  for (int i = 0; i < per; ++i) {
    int idx = base + i;
    if (idx < N) {
      rowptr[idx] = run;
      run += cnt[idx];
    }
  }
  if (t == 1023) rowptr[N] = part[1023];
}

__global__ void scatter_csr_k(const int* __restrict__ src,
                              const int* __restrict__ dst, int E,
                              const int* __restrict__ rowptr,
                              int* __restrict__ fill,
                              int* __restrict__ csr_src) {
  int e = blockIdx.x * blockDim.x + threadIdx.x;
  if (e >= E) return;
  int d = dst[e];
  int pos = rowptr[d] + atomicAdd(&fill[d], 1);
  csr_src[pos] = src[e];
}

// ---------------------------------------------------------------------------
extern "C" void kernel_launch(void* const* d_in, const int* in_sizes, int n_in,
                              void* d_out, int out_size, void* d_ws,
                              size_t ws_size, hipStream_t stream) {
  const float* x = (const float*)d_in[0];
  const int* eidx = (const int*)d_in[1];
  const int N = in_sizes[0] / 2048;
  const int E = in_sizes[1] / 2;
  const int* srcA = eidx;
  const int* dstA = eidx + E;
  float* dout = (float*)d_out;

  char* p = (char*)d_ws;
  auto alloc = [&](size_t bytes) {
    void* r = (void*)p;
    p += (bytes + 255) & ~(size_t)255;
    return r;
  };

  float* logits = (float*)alloc((size_t)E * 4);
  int* rowptr = (int*)alloc((size_t)(N + 1) * 4);
  int* cnt = (int*)alloc((size_t)N * 4);
  int* fill = (int*)alloc((size_t)N * 4);
  int* csr_src = (int*)alloc((size_t)E * 4);

  hipMemsetAsync(cnt, 0, (size_t)N * 4, stream);
  hipMemsetAsync(fill, 0, (size_t)N * 4, stream);
  count_deg_k<<<(E + 255) / 256, 256, 0, stream>>>(dstA, E, cnt);
  scan_k<<<1, 1024, 0, stream>>>(cnt, rowptr, N);
  scatter_csr_k<<<(E + 255) / 256, 256, 0, stream>>>(srcA, dstA, E, rowptr,
                                                     fill, csr_src);

  const size_t szH = (size_t)N * 2048 * 2;          // fp16 [N][2048]
  const size_t szWt = (size_t)4 * 1024 * 2048 * 2;  // fp16 [4C][K] per layer

  unsigned short* Hb = (unsigned short*)alloc(szH);
  unsigned short* Qh = (unsigned short*)alloc(szH);
  unsigned short* Kh = (unsigned short*)alloc(szH);
  unsigned short* Vh = (unsigned short*)alloc(szH);
  unsigned short* Wt[4];
  for (int L = 0; L < 4; ++L) Wt[L] = (unsigned short*)alloc(szWt);

  const int fi[4] = {2048, 1024, 2048, 1024};
  const int fo[4] = {1024, 2048, 1024, 2048};
  const int elu[4] = {1, 0, 1, 0};

  cast_f16_k<<<(int)(((size_t)N * 2048 / 4 + 255) / 256), 256, 0, stream>>>(
      x, Hb, (size_t)N * 2048 / 4);

  // all weight transposes upfront (independent of the layer chain)
  for (int L = 0; L < 4; ++L) {
    const int K = fi[L], C = fo[L];
    const int b = 2 + L * 8;
    transp_f16_k<<<dim3(K / 32, C / 32, 4), 256, 0, stream>>>(
        (const float*)d_in[b + 0], (const float*)d_in[b + 2],
        (const float*)d_in[b + 4], (const float*)d_in[b + 6], Wt[L], K, C);
  }

  for (int L = 0; L < 4; ++L) {
    const int K = fi[L], C = fo[L];
    const int b = 2 + L * 8;
    const float scale = (float)(1.0 / sqrt((double)C));
    const int NX = (N + 255) / 256;
    const int NY = 4 * C / 128;
    gemm_f16_k<<<NX * NY, 512, 0, stream>>>(
        Hb, Wt[L], (const float*)d_in[b + 1], (const float*)d_in[b + 3],
        (const float*)d_in[b + 5], (const float*)d_in[b + 7], Qh, Kh, Vh, dout,
        N, K, C, NX, NY);
    attn_fused2_k<<<N, 256, 0, stream>>>(Qh, Kh, Vh, rowptr, csr_src, logits,
                                         dout, Hb, C, scale, elu[L],
                                         L < 3 ? 1 : 0);
  }
}

// Round 16
// 1449.284 us; speedup vs baseline: 7.1437x; 1.0084x over previous
//
#include <hip/hip_runtime.h>
#include <cmath>
#include <cstddef>
#include <cstdint>

typedef __attribute__((ext_vector_type(8))) _Float16 half8_t;
typedef __attribute__((ext_vector_type(4))) _Float16 half4_t;
typedef __attribute__((ext_vector_type(2))) _Float16 half2_t;
typedef __attribute__((ext_vector_type(4))) float f32x4;

// ---------------------------------------------------------------------------
// helpers
// ---------------------------------------------------------------------------
__device__ __forceinline__ float dot2f16(half2_t a, half2_t b, float c) {
#if __has_builtin(__builtin_amdgcn_fdot2)
  return __builtin_amdgcn_fdot2(a, b, c, false);
#else
  return c + (float)a.x * (float)b.x + (float)a.y * (float)b.y;
#endif
}

// async global -> LDS, 16B per lane (wave-uniform LDS base + lane*16)
__device__ __forceinline__ void gload16(const unsigned short* g,
                                        unsigned short* l) {
  __builtin_amdgcn_global_load_lds(
      (const __attribute__((address_space(1))) unsigned int*)g,
      (__attribute__((address_space(3))) unsigned int*)l, 16, 0, 0);
}

// ---------------------------------------------------------------------------
// cast fp32 -> fp16 (vectorized)
// ---------------------------------------------------------------------------
__global__ __launch_bounds__(256) void cast_f16_k(
    const float* __restrict__ in, unsigned short* __restrict__ out, size_t n4) {
  size_t i = (size_t)blockIdx.x * blockDim.x + threadIdx.x;
  if (i >= n4) return;
  float4 v = ((const float4*)in)[i];
  half4_t h;
  h.x = (_Float16)v.x;
  h.y = (_Float16)v.y;
  h.z = (_Float16)v.z;
  h.w = (_Float16)v.w;
  ((half4_t*)out)[i] = h;
}

// ---------------------------------------------------------------------------
// ALL weight transposes in one launch. z = L*4+m (L=layer, m=matrix).
// W[K][C] fp32 -> T[L] + m*C*K as [C][K] fp16. Dims from layer parity.
// ---------------------------------------------------------------------------
struct TranspAll {
  const float* W[16];
  unsigned short* T[4];
};

__global__ __launch_bounds__(256) void transp_all_k(TranspAll a) {
  const int z = blockIdx.z;
  const int L = z >> 2, m = z & 3;
  const int K = (L & 1) ? 1024 : 2048;
  const int C = (L & 1) ? 2048 : 1024;
  const int k0 = blockIdx.x * 32, c0 = blockIdx.y * 32;
  if (k0 >= K || c0 >= C) return;
  __shared__ float t[32][33];
  const float* W = a.W[z];
  _Float16* th = (_Float16*)a.T[L] + (size_t)m * C * K;
  int tx = threadIdx.x & 31, ty = threadIdx.x >> 5;  // ty 0..7
#pragma unroll
  for (int r = 0; r < 4; ++r)
    t[ty + r * 8][tx] = W[(size_t)(k0 + ty + r * 8) * C + c0 + tx];
  __syncthreads();
#pragma unroll
  for (int r = 0; r < 4; ++r) {
    int c = ty + r * 8;
    th[(size_t)(c0 + c) * K + k0 + tx] = (_Float16)t[tx][c];
  }
}

// ---------------------------------------------------------------------------
// Fused per-layer GEMM (fp16): [q|k|v|s] = X @ Wt^T + bias
// 256x128 tile, 512 threads = 8 waves (4x2). 3-buffer LDS (72KB),
// depth-2 prefetch, counted vmcnt, raw s_barrier, setprio around MFMA.
// s output: fp16 to Sh when s16, else fp32 to S.
// ---------------------------------------------------------------------------
__global__ __launch_bounds__(512) void gemm_f16_k(
    const unsigned short* __restrict__ Ab, const unsigned short* __restrict__ Wt,
    const float* __restrict__ bq, const float* __restrict__ bk,
    const float* __restrict__ bv, const float* __restrict__ bs,
    unsigned short* __restrict__ Qh, unsigned short* __restrict__ Kh,
    unsigned short* __restrict__ Vh, float* __restrict__ S,
    unsigned short* __restrict__ Sh, int s16, int M, int K, int C, int NX,
    int NY) {
  // per buffer: A = 256x32 fp16 (16KB) at [0], B = 128x32 fp16 (8KB) at [8192]
  __shared__ unsigned short lds[3][12288];

  const int nwg = NX * NY;
  const int bid = blockIdx.x;
  const int qq = nwg >> 3, rr = nwg & 7;
  const int xcd = bid & 7, idx = bid >> 3;
  const int wgid =
      (xcd < rr ? xcd * (qq + 1) : rr * (qq + 1) + (xcd - rr) * qq) + idx;
  const int by = wgid % NY, bx = wgid / NY;

  const int bm = bx * 256, n0 = by * 128;
  const int kind = n0 / C;  // 0=q 1=k 2=v 3=s
  const int tid = threadIdx.x;
  const int lane = tid & 63, w = tid >> 6;  // w 0..7
  const int wm = w >> 1, wn = w & 1;        // 4x2 wave grid
  const int fr = lane & 15, kg = lane >> 4;

  const int srow = w * 16 + (lane >> 2);  // 0..127
  const int soff = (((lane & 3) ^ ((lane >> 2) & 3))) * 8;
  const size_t ga0 = (size_t)min(bm + srow, M - 1) * K + soff;
  const size_t ga1 = (size_t)min(bm + srow + 128, M - 1) * K + soff;
  const size_t gb0 = (size_t)(n0 + srow) * K + soff;
  const int la0 = w * 512;  // ushort offsets
  const int la1 = 4096 + w * 512;
  const int lb0 = 8192 + w * 512;

  f32x4 acc[4][4];
#pragma unroll
  for (int i = 0; i < 4; ++i)
#pragma unroll
    for (int j = 0; j < 4; ++j) acc[i][j] = (f32x4)0.f;

  auto STAGE = [&](int buf, int ko) {
    gload16(Ab + ga0 + ko, &lds[buf][la0]);
    gload16(Ab + ga1 + ko, &lds[buf][la1]);
    gload16(Wt + gb0 + ko, &lds[buf][lb0]);
  };

  const int T = K / 32;
  STAGE(0, 0);
  STAGE(1, 32);

  const int rka = (kg ^ (fr & 3)) * 8;  // swizzled read chunk (ushorts)
  int buf = 0;
  for (int t = 0; t < T; ++t) {
    if (t + 1 < T)
      asm volatile("s_waitcnt vmcnt(3)" ::: "memory");  // tile t's 3 retired
    else
      asm volatile("s_waitcnt vmcnt(0)" ::: "memory");  // final drain
    __builtin_amdgcn_s_barrier();   // all waves' tile-t DMA visible
    asm volatile("" ::: "memory");  // no LDS reads hoisted above this point
    if (t + 2 < T) {
      int nb = buf + 2;
      if (nb >= 3) nb -= 3;
      STAGE(nb, (t + 2) * 32);  // overwrites buffer whose reads retired at t-1
    }
    const unsigned short* As = lds[buf];
    const unsigned short* Bs = lds[buf] + 8192;
    half8_t ah[4], bh[4];
#pragma unroll
    for (int i = 0; i < 4; ++i) {
      ah[i] = *(const half8_t*)(As + (wm * 64 + i * 16 + fr) * 32 + rka);
      bh[i] = *(const half8_t*)(Bs + (wn * 64 + i * 16 + fr) * 32 + rka);
    }
    __builtin_amdgcn_s_setprio(1);
#pragma unroll
    for (int i = 0; i < 4; ++i)
#pragma unroll
      for (int j = 0; j < 4; ++j)
        acc[i][j] = __builtin_amdgcn_mfma_f32_16x16x32_f16(ah[i], bh[j],
                                                           acc[i][j], 0, 0, 0);
    __builtin_amdgcn_s_setprio(0);
    asm volatile("s_waitcnt lgkmcnt(0)" ::: "memory");  // my LDS reads retired
    buf = (buf == 2) ? 0 : buf + 1;
  }

  const float* bptr = (kind == 0) ? bq : (kind == 1) ? bk : (kind == 2) ? bv : bs;
  const int cbase = (n0 - kind * C) + wn * 64;
  float bvv[4];
#pragma unroll
  for (int j = 0; j < 4; ++j) bvv[j] = bptr[cbase + j * 16 + fr];

  unsigned short* obu = (kind == 0) ? Qh : (kind == 1) ? Kh : Vh;
  _Float16* ob = (_Float16*)obu;
  _Float16* sh = (_Float16*)Sh;
#pragma unroll
  for (int i = 0; i < 4; ++i) {
#pragma unroll
    for (int r = 0; r < 4; ++r) {
      int gr = bm + wm * 64 + i * 16 + kg * 4 + r;
      if (gr < M) {
        if (kind == 3) {
          if (s16) {
#pragma unroll
            for (int j = 0; j < 4; ++j)
              sh[(size_t)gr * C + cbase + j * 16 + fr] =
                  (_Float16)(acc[i][j][r] + bvv[j]);
          } else {
#pragma unroll
            for (int j = 0; j < 4; ++j)
              S[(size_t)gr * C + cbase + j * 16 + fr] = acc[i][j][r] + bvv[j];
          }
        } else {
#pragma unroll
          for (int j = 0; j < 4; ++j)
            ob[(size_t)gr * C + cbase + j * 16 + fr] =
                (_Float16)(acc[i][j][r] + bvv[j]);
        }
      }
    }
  }
}

// ---------------------------------------------------------------------------
// Fused attention (fp16 q/k/v). Skip read fp16 (Sh16) when skip16 else fp32.
// sm path: online per-wave softmax (no phase-2 pass).
// ---------------------------------------------------------------------------
__global__ __launch_bounds__(256) void attn_fused3_k(
    const unsigned short* __restrict__ Qh, const unsigned short* __restrict__ Kh,
    const unsigned short* __restrict__ Vh, const int* __restrict__ rowptr,
    const int* __restrict__ csr_src, float* __restrict__ gscratch,
    float* __restrict__ skipio, const unsigned short* __restrict__ Sh16,
    int skip16, unsigned short* __restrict__ Hb, int C, float scale,
    int do_elu, int writeH) {
  __shared__ _Float16 qs[2048];
  __shared__ float ebuf[512];
  __shared__ int ssrc[512];
  __shared__ float wred[8];
  const int i = blockIdx.x;
  const int tid = threadIdx.x;
  const int lane = tid & 63, wid = tid >> 6;
  const int beg = rowptr[i], end = rowptr[i + 1];
  const int deg = end - beg;
  const bool sm = (deg <= 512);

  for (int c0 = tid * 4; c0 < C; c0 += 1024)
    *(uint2*)&qs[c0] = *(const uint2*)(Qh + (size_t)i * C + c0);
  if (sm)
    for (int p = tid; p < deg; p += 256) ssrc[p] = csr_src[beg + p];
  if (tid < 8) wred[tid] = (tid < 4) ? -INFINITY : 0.f;
  __syncthreads();

  if (deg > 0) {
    if (sm) {
      // phase 1: 2 edges per wave interleaved; online wave max+sum
      float mw = -INFINITY, sw = 0.f;
      for (int ep = wid; ep < deg; ep += 8) {
        const int e1 = ep + 4;
        const bool h1 = e1 < deg;
        int s0 = ssrc[ep];
        int s1 = h1 ? ssrc[e1] : s0;
        const unsigned short* kr0 = Kh + (size_t)s0 * C;
        const unsigned short* kr1 = Kh + (size_t)s1 * C;
        float su0 = 0.f, su1 = 0.f;
        for (int c0 = lane * 8; c0 < C; c0 += 512) {
          uint4 k0 = *(const uint4*)(kr0 + c0);
          uint4 k1 = *(const uint4*)(kr1 + c0);
          uint4 qv = *(const uint4*)&qs[c0];
          const half2_t* kp0 = (const half2_t*)&k0;
          const half2_t* kp1 = (const half2_t*)&k1;
          const half2_t* qp = (const half2_t*)&qv;
#pragma unroll
          for (int u = 0; u < 4; ++u) {
            su0 = dot2f16(kp0[u], qp[u], su0);
            su1 = dot2f16(kp1[u], qp[u], su1);
          }
        }
#pragma unroll
        for (int o = 32; o; o >>= 1) {
          su0 += __shfl_xor(su0, o);
          su1 += __shfl_xor(su1, o);
        }
        float lg0 = su0 * scale;
        float lg1 = h1 ? su1 * scale : -INFINITY;
        if (lane == 0) {
          ebuf[ep] = lg0;
          if (h1) ebuf[e1] = lg1;
        }
        float nm = fmaxf(mw, fmaxf(lg0, lg1));
        sw = sw * expf(mw - nm) + expf(lg0 - nm) +
             (h1 ? expf(lg1 - nm) : 0.f);
        mw = nm;
      }
      if (lane == 0) {
        wred[wid] = mw;
        wred[4 + wid] = sw;
      }
      __syncthreads();
    } else {
      float wmaxv = -INFINITY;
      for (int ep = wid; ep < deg; ep += 4) {
        int s = csr_src[beg + ep];
        const unsigned short* kr = Kh + (size_t)s * C;
        float sum = 0.f;
        for (int c0 = lane * 8; c0 < C; c0 += 512) {
          uint4 kk = *(const uint4*)(kr + c0);
          uint4 qv = *(const uint4*)&qs[c0];
          const half2_t* kp = (const half2_t*)&kk;
          const half2_t* qp = (const half2_t*)&qv;
#pragma unroll
          for (int u = 0; u < 4; ++u) sum = dot2f16(kp[u], qp[u], sum);
        }
#pragma unroll
        for (int o = 32; o; o >>= 1) sum += __shfl_xor(sum, o);
        float lg = sum * scale;
        if (lane == 0) gscratch[beg + ep] = lg;
        wmaxv = fmaxf(wmaxv, lg);
      }
      if (lane == 0) wred[wid] = wmaxv;
      __syncthreads();
      float m = fmaxf(fmaxf(wred[0], wred[1]), fmaxf(wred[2], wred[3]));
      float part = 0.f;
      for (int ep = tid; ep < deg; ep += 256) {
        float e = expf(gscratch[beg + ep] - m);
        gscratch[beg + ep] = e;
        part += e;
      }
#pragma unroll
      for (int o = 32; o; o >>= 1) part += __shfl_xor(part, o);
      if (lane == 0) wred[4 + wid] = part;
      __syncthreads();
    }
  } else {
    __syncthreads();
  }

  const float gmax = fmaxf(fmaxf(wred[0], wred[1]), fmaxf(wred[2], wred[3]));
  float total;
  if (sm) {
    total = wred[4] * expf(wred[0] - gmax) + wred[5] * expf(wred[1] - gmax) +
            wred[6] * expf(wred[2] - gmax) + wred[7] * expf(wred[3] - gmax);
  } else {
    total = wred[4] + wred[5] + wred[6] + wred[7];
  }
  float denom = 1.f / (total + 1e-16f);
  const int cpt = C >> 8;  // 4 or 8 cols per thread
  const int col0 = tid * cpt;
  float acc[8];
#pragma unroll
  for (int j = 0; j < 8; ++j) acc[j] = 0.f;

  // phase 3: aggregate alpha * v[src], 4-edge unroll (sm)
  if (sm) {
    int ep = 0;
    if (cpt == 8) {
      for (; ep + 4 <= deg; ep += 4) {
        float a0 = expf(ebuf[ep] - gmax) * denom;
        float a1 = expf(ebuf[ep + 1] - gmax) * denom;
        float a2 = expf(ebuf[ep + 2] - gmax) * denom;
        float a3 = expf(ebuf[ep + 3] - gmax) * denom;
        uint4 p0 = *(const uint4*)(Vh + (size_t)ssrc[ep] * C + col0);
        uint4 p1 = *(const uint4*)(Vh + (size_t)ssrc[ep + 1] * C + col0);
        uint4 p2 = *(const uint4*)(Vh + (size_t)ssrc[ep + 2] * C + col0);
        uint4 p3 = *(const uint4*)(Vh + (size_t)ssrc[ep + 3] * C + col0);
        const _Float16* h0 = (const _Float16*)&p0;
        const _Float16* h1 = (const _Float16*)&p1;
        const _Float16* h2 = (const _Float16*)&p2;
        const _Float16* h3 = (const _Float16*)&p3;
#pragma unroll
        for (int u = 0; u < 8; ++u) {
          acc[u] = fmaf(a0, (float)h0[u], acc[u]);
          acc[u] = fmaf(a1, (float)h1[u], acc[u]);
          acc[u] = fmaf(a2, (float)h2[u], acc[u]);
          acc[u] = fmaf(a3, (float)h3[u], acc[u]);
        }
      }
      for (; ep < deg; ++ep) {
        float a = expf(ebuf[ep] - gmax) * denom;
        uint4 pv = *(const uint4*)(Vh + (size_t)ssrc[ep] * C + col0);
        const _Float16* ph = (const _Float16*)&pv;
#pragma unroll
        for (int u = 0; u < 8; ++u) acc[u] = fmaf(a, (float)ph[u], acc[u]);
      }
    } else {
      for (; ep + 4 <= deg; ep += 4) {
        float a0 = expf(ebuf[ep] - gmax) * denom;
        float a1 = expf(ebuf[ep + 1] - gmax) * denom;
        float a2 = expf(ebuf[ep + 2] - gmax) * denom;
        float a3 = expf(ebuf[ep + 3] - gmax) * denom;
        ushort4 p0 = *(const ushort4*)(Vh + (size_t)ssrc[ep] * C + col0);
        ushort4 p1 = *(const ushort4*)(Vh + (size_t)ssrc[ep + 1] * C + col0);
        ushort4 p2 = *(const ushort4*)(Vh + (size_t)ssrc[ep + 2] * C + col0);
        ushort4 p3 = *(const ushort4*)(Vh + (size_t)ssrc[ep + 3] * C + col0);
        const _Float16* h0 = (const _Float16*)&p0;
        const _Float16* h1 = (const _Float16*)&p1;
        const _Float16* h2 = (const _Float16*)&p2;
        const _Float16* h3 = (const _Float16*)&p3;
#pragma unroll
        for (int u = 0; u < 4; ++u) {
          acc[u] = fmaf(a0, (float)h0[u], acc[u]);
          acc[u] = fmaf(a1, (float)h1[u], acc[u]);
          acc[u] = fmaf(a2, (float)h2[u], acc[u]);
          acc[u] = fmaf(a3, (float)h3[u], acc[u]);
        }
      }
      for (; ep < deg; ++ep) {
        float a = expf(ebuf[ep] - gmax) * denom;
        ushort4 pv = *(const ushort4*)(Vh + (size_t)ssrc[ep] * C + col0);
        const _Float16* ph = (const _Float16*)&pv;
#pragma unroll
        for (int u = 0; u < 4; ++u) acc[u] = fmaf(a, (float)ph[u], acc[u]);
      }
    }
  } else {
    for (int ep = 0; ep < deg; ++ep) {
      float a = gscratch[beg + ep] * denom;
      int s = csr_src[beg + ep];
      const unsigned short* vr = Vh + (size_t)s * C + col0;
      if (cpt == 4) {
        ushort4 pv = *(const ushort4*)vr;
        const _Float16* ph = (const _Float16*)&pv;
#pragma unroll
        for (int u = 0; u < 4; ++u) acc[u] = fmaf(a, (float)ph[u], acc[u]);
      } else {
        uint4 pv = *(const uint4*)vr;
        const _Float16* ph = (const _Float16*)&pv;
#pragma unroll
        for (int u = 0; u < 8; ++u) acc[u] = fmaf(a, (float)ph[u], acc[u]);
      }
    }
  }

  float* srow = skipio + (size_t)i * C + col0;
#pragma unroll
  for (int v4 = 0; v4 < 2; ++v4) {
    if (v4 * 4 < cpt) {
      float4 o;
      if (skip16) {
        ushort4 s4 = *(const ushort4*)(Sh16 + (size_t)i * C + col0 + v4 * 4);
        const _Float16* sp = (const _Float16*)&s4;
        o = make_float4((float)sp[0], (float)sp[1], (float)sp[2], (float)sp[3]);
      } else {
        o = *(const float4*)(srow + v4 * 4);
      }
      o.x += acc[v4 * 4 + 0];
      o.y += acc[v4 * 4 + 1];
      o.z += acc[v4 * 4 + 2];
      o.w += acc[v4 * 4 + 3];
      if (do_elu) {
        o.x = o.x > 0.f ? o.x : expm1f(o.x);
        o.y = o.y > 0.f ? o.y : expm1f(o.y);
        o.z = o.z > 0.f ? o.z : expm1f(o.z);
        o.w = o.w > 0.f ? o.w : expm1f(o.w);
      }
      if (writeH) {
        half4_t h;
        h.x = (_Float16)o.x;
        h.y = (_Float16)o.y;
        h.z = (_Float16)o.z;
        h.w = (_Float16)o.w;
        *(half4_t*)((_Float16*)Hb + (size_t)i * C + col0 + v4 * 4) = h;
      } else {
        *(float4*)(srow + v4 * 4) = o;
      }
    }
  }
}

// ---------------------------------------------------------------------------
// CSR build
// ---------------------------------------------------------------------------
__global__ void count_deg_k(const int* __restrict__ dst, int E,
                            int* __restrict__ cnt) {
  int e = blockIdx.x * blockDim.x + threadIdx.x;
  if (e < E) atomicAdd(&cnt[dst[e]], 1);
}

__global__ void scan_k(const int* __restrict__ cnt, int* __restrict__ rowptr,
                       int N) {
  __shared__ int part[1024];
  int t = threadIdx.x;
  int per = (N + 1023) >> 10;
  int base = t * per;
  int s = 0;
  for (int i = 0; i < per; ++i) {
    int idx = base + i;
    if (idx < N) s += cnt[idx];
  }
  part[t] = s;
  __syncthreads();
  for (int off = 1; off < 1024; off <<= 1) {
    int v = (t >= off) ? part[t - off] : 0;
    __syncthreads();
    part[t] += v;
    __syncthreads();
  }
  int run = part[t] - s;
  for (int i = 0; i < per; ++i) {
    int idx = base + i;
    if (idx < N) {
      rowptr[idx] = run;
      run += cnt[idx];
    }
  }
  if (t == 1023) rowptr[N] = part[1023];
}

__global__ void scatter_csr_k(const int* __restrict__ src,
                              const int* __restrict__ dst, int E,
                              const int* __restrict__ rowptr,
                              int* __restrict__ fill,
                              int* __restrict__ csr_src) {
  int e = blockIdx.x * blockDim.x + threadIdx.x;
  if (e >= E) return;
  int d = dst[e];
  int pos = rowptr[d] + atomicAdd(&fill[d], 1);
  csr_src[pos] = src[e];
}

// ---------------------------------------------------------------------------
extern "C" void kernel_launch(void* const* d_in, const int* in_sizes, int n_in,
                              void* d_out, int out_size, void* d_ws,
                              size_t ws_size, hipStream_t stream) {
  const float* x = (const float*)d_in[0];
  const int* eidx = (const int*)d_in[1];
  const int N = in_sizes[0] / 2048;
  const int E = in_sizes[1] / 2;
  const int* srcA = eidx;
  const int* dstA = eidx + E;
  float* dout = (float*)d_out;

  char* p = (char*)d_ws;
  auto alloc = [&](size_t bytes) {
    void* r = (void*)p;
    p += (bytes + 255) & ~(size_t)255;
    return r;
  };

  float* logits = (float*)alloc((size_t)E * 4);
  int* rowptr = (int*)alloc((size_t)(N + 1) * 4);
  int* cnt = (int*)alloc((size_t)N * 4);
  int* fill = (int*)alloc((size_t)N * 4);
  int* csr_src = (int*)alloc((size_t)E * 4);

  hipMemsetAsync(cnt, 0, (size_t)N * 4, stream);
  hipMemsetAsync(fill, 0, (size_t)N * 4, stream);
  count_deg_k<<<(E + 255) / 256, 256, 0, stream>>>(dstA, E, cnt);
  scan_k<<<1, 1024, 0, stream>>>(cnt, rowptr, N);
  scatter_csr_k<<<(E + 255) / 256, 256, 0, stream>>>(srcA, dstA, E, rowptr,
                                                     fill, csr_src);

  const size_t szH = (size_t)N * 2048 * 2;          // fp16 [N][2048]
  const size_t szWt = (size_t)4 * 1024 * 2048 * 2;  // fp16 [4C][K] per layer

  unsigned short* Hb = (unsigned short*)alloc(szH);
  unsigned short* Qh = (unsigned short*)alloc(szH);
  unsigned short* Kh = (unsigned short*)alloc(szH);
  unsigned short* Vh = (unsigned short*)alloc(szH);
  unsigned short* Wt[4];
  for (int L = 0; L < 4; ++L) Wt[L] = (unsigned short*)alloc(szWt);

  const int fi[4] = {2048, 1024, 2048, 1024};
  const int fo[4] = {1024, 2048, 1024, 2048};
  const int elu[4] = {1, 0, 1, 0};

  cast_f16_k<<<(int)(((size_t)N * 2048 / 4 + 255) / 256), 256, 0, stream>>>(
      x, Hb, (size_t)N * 2048 / 4);

  // all 16 weight transposes in one launch
  TranspAll ta;
  for (int L = 0; L < 4; ++L) {
    for (int m = 0; m < 4; ++m)
      ta.W[L * 4 + m] = (const float*)d_in[2 + L * 8 + 2 * m];
    ta.T[L] = Wt[L];
  }
  transp_all_k<<<dim3(64, 64, 16), 256, 0, stream>>>(ta);

  // dout doubles as fp16 skip buffer for L<3 (fully rewritten at L=3)
  unsigned short* Sh = (unsigned short*)dout;

  for (int L = 0; L < 4; ++L) {
    const int K = fi[L], C = fo[L];
    const int b = 2 + L * 8;
    const float scale = (float)(1.0 / sqrt((double)C));
    const int NX = (N + 255) / 256;
    const int NY = 4 * C / 128;
    const int s16 = (L < 3) ? 1 : 0;
    gemm_f16_k<<<NX * NY, 512, 0, stream>>>(
        Hb, Wt[L], (const float*)d_in[b + 1], (const float*)d_in[b + 3],
        (const float*)d_in[b + 5], (const float*)d_in[b + 7], Qh, Kh, Vh, dout,
        Sh, s16, N, K, C, NX, NY);
    attn_fused3_k<<<N, 256, 0, stream>>>(Qh, Kh, Vh, rowptr, csr_src, logits,
                                         dout, Sh, s16, Hb, C, scale, elu[L],
                                         L < 3 ? 1 : 0);
  }
}

// Round 17
// 1423.195 us; speedup vs baseline: 7.2746x; 1.0183x over previous
//
#include <hip/hip_runtime.h>
#include <cmath>
#include <cstddef>
#include <cstdint>

typedef __attribute__((ext_vector_type(8))) _Float16 half8_t;
typedef __attribute__((ext_vector_type(4))) _Float16 half4_t;
typedef __attribute__((ext_vector_type(2))) _Float16 half2_t;
typedef __attribute__((ext_vector_type(4))) float f32x4;

// ---------------------------------------------------------------------------
// helpers
// ---------------------------------------------------------------------------
__device__ __forceinline__ float dot2f16(half2_t a, half2_t b, float c) {
#if __has_builtin(__builtin_amdgcn_fdot2)
  return __builtin_amdgcn_fdot2(a, b, c, false);
#else
  return c + (float)a.x * (float)b.x + (float)a.y * (float)b.y;
#endif
}

// async global -> LDS, 16B per lane (wave-uniform LDS base + lane*16)
__device__ __forceinline__ void gload16(const unsigned short* g,
                                        unsigned short* l) {
  __builtin_amdgcn_global_load_lds(
      (const __attribute__((address_space(1))) unsigned int*)g,
      (__attribute__((address_space(3))) unsigned int*)l, 16, 0, 0);
}

// ---------------------------------------------------------------------------
// cast fp32 -> fp16 (vectorized)
// ---------------------------------------------------------------------------
__global__ __launch_bounds__(256) void cast_f16_k(
    const float* __restrict__ in, unsigned short* __restrict__ out, size_t n4) {
  size_t i = (size_t)blockIdx.x * blockDim.x + threadIdx.x;
  if (i >= n4) return;
  float4 v = ((const float4*)in)[i];
  half4_t h;
  h.x = (_Float16)v.x;
  h.y = (_Float16)v.y;
  h.z = (_Float16)v.z;
  h.w = (_Float16)v.w;
  ((half4_t*)out)[i] = h;
}

// ---------------------------------------------------------------------------
// ALL weight transposes in one launch. z = L*4+m (L=layer, m=matrix).
// ---------------------------------------------------------------------------
struct TranspAll {
  const float* W[16];
  unsigned short* T[4];
};

__global__ __launch_bounds__(256) void transp_all_k(TranspAll a) {
  const int z = blockIdx.z;
  const int L = z >> 2, m = z & 3;
  const int K = (L & 1) ? 1024 : 2048;
  const int C = (L & 1) ? 2048 : 1024;
  const int k0 = blockIdx.x * 32, c0 = blockIdx.y * 32;
  if (k0 >= K || c0 >= C) return;
  __shared__ float t[32][33];
  const float* W = a.W[z];
  _Float16* th = (_Float16*)a.T[L] + (size_t)m * C * K;
  int tx = threadIdx.x & 31, ty = threadIdx.x >> 5;  // ty 0..7
#pragma unroll
  for (int r = 0; r < 4; ++r)
    t[ty + r * 8][tx] = W[(size_t)(k0 + ty + r * 8) * C + c0 + tx];
  __syncthreads();
#pragma unroll
  for (int r = 0; r < 4; ++r) {
    int c = ty + r * 8;
    th[(size_t)(c0 + c) * K + k0 + tx] = (_Float16)t[tx][c];
  }
}

// ---------------------------------------------------------------------------
// Fused per-layer GEMM (fp16): [q|k|v|s] = X @ Wt^T + bias
// 256x128 tile, 512 threads = 8 waves (4x2). 3-buffer LDS (72KB),
// depth-2 prefetch, counted vmcnt, raw s_barrier, setprio around MFMA.
// Block order: 5-row-panel groups (one per XCD) with column sweep inside,
// so the A-group stays L2-resident and B streams ONCE per XCD.
// ---------------------------------------------------------------------------
__global__ __launch_bounds__(512) void gemm_f16_k(
    const unsigned short* __restrict__ Ab, const unsigned short* __restrict__ Wt,
    const float* __restrict__ bq, const float* __restrict__ bk,
    const float* __restrict__ bv, const float* __restrict__ bs,
    unsigned short* __restrict__ Qh, unsigned short* __restrict__ Kh,
    unsigned short* __restrict__ Vh, float* __restrict__ S,
    unsigned short* __restrict__ Sh, int s16, int M, int K, int C, int NX,
    int NY) {
  __shared__ unsigned short lds[3][12288];  // A 256x32 @0, B 128x32 @8192

  const int nwg = NX * NY;
  const int bid = blockIdx.x;
  const int qq = nwg >> 3, rr = nwg & 7;
  const int xcd = bid & 7, idx = bid >> 3;
  const int wgid =
      (xcd < rr ? xcd * (qq + 1) : rr * (qq + 1) + (xcd - rr) * qq) + idx;
  // group mapping: GX row-panels share the column sweep (A L2-resident)
  int bx, by;
  const int GX = (NX % 5 == 0) ? 5 : ((NX % 4 == 0) ? 4 : 1);
  if (GX > 1) {
    const int gsz = GX * NY;
    const int g = wgid / gsz, rem = wgid % gsz;
    by = rem / GX;
    bx = g * GX + rem % GX;
  } else {
    by = wgid % NY;
    bx = wgid / NY;
  }

  const int bm = bx * 256, n0 = by * 128;
  const int kind = n0 / C;  // 0=q 1=k 2=v 3=s
  const int tid = threadIdx.x;
  const int lane = tid & 63, w = tid >> 6;  // w 0..7
  const int wm = w >> 1, wn = w & 1;        // 4x2 wave grid
  const int fr = lane & 15, kg = lane >> 4;

  const int srow = w * 16 + (lane >> 2);  // 0..127
  const int soff = (((lane & 3) ^ ((lane >> 2) & 3))) * 8;
  const size_t ga0 = (size_t)min(bm + srow, M - 1) * K + soff;
  const size_t ga1 = (size_t)min(bm + srow + 128, M - 1) * K + soff;
  const size_t gb0 = (size_t)(n0 + srow) * K + soff;
  const int la0 = w * 512;  // ushort offsets
  const int la1 = 4096 + w * 512;
  const int lb0 = 8192 + w * 512;

  f32x4 acc[4][4];
#pragma unroll
  for (int i = 0; i < 4; ++i)
#pragma unroll
    for (int j = 0; j < 4; ++j) acc[i][j] = (f32x4)0.f;

  auto STAGE = [&](int buf, int ko) {
    gload16(Ab + ga0 + ko, &lds[buf][la0]);
    gload16(Ab + ga1 + ko, &lds[buf][la1]);
    gload16(Wt + gb0 + ko, &lds[buf][lb0]);
  };

  const int T = K / 32;
  STAGE(0, 0);
  STAGE(1, 32);

  const int rka = (kg ^ (fr & 3)) * 8;  // swizzled read chunk (ushorts)
  int buf = 0;
  for (int t = 0; t < T; ++t) {
    if (t + 1 < T)
      asm volatile("s_waitcnt vmcnt(3)" ::: "memory");  // tile t's 3 retired
    else
      asm volatile("s_waitcnt vmcnt(0)" ::: "memory");  // final drain
    __builtin_amdgcn_s_barrier();   // all waves' tile-t DMA visible
    asm volatile("" ::: "memory");  // no LDS reads hoisted above this point
    if (t + 2 < T) {
      int nb = buf + 2;
      if (nb >= 3) nb -= 3;
      STAGE(nb, (t + 2) * 32);  // overwrites buffer whose reads retired at t-1
    }
    const unsigned short* As = lds[buf];
    const unsigned short* Bs = lds[buf] + 8192;
    half8_t ah[4], bh[4];
#pragma unroll
    for (int i = 0; i < 4; ++i) {
      ah[i] = *(const half8_t*)(As + (wm * 64 + i * 16 + fr) * 32 + rka);
      bh[i] = *(const half8_t*)(Bs + (wn * 64 + i * 16 + fr) * 32 + rka);
    }
    __builtin_amdgcn_s_setprio(1);
#pragma unroll
    for (int i = 0; i < 4; ++i)
#pragma unroll
      for (int j = 0; j < 4; ++j)
        acc[i][j] = __builtin_amdgcn_mfma_f32_16x16x32_f16(ah[i], bh[j],
                                                           acc[i][j], 0, 0, 0);
    __builtin_amdgcn_s_setprio(0);
    asm volatile("s_waitcnt lgkmcnt(0)" ::: "memory");  // my LDS reads retired
    buf = (buf == 2) ? 0 : buf + 1;
  }

  const float* bptr = (kind == 0) ? bq : (kind == 1) ? bk : (kind == 2) ? bv : bs;
  const int cbase = (n0 - kind * C) + wn * 64;
  float bvv[4];
#pragma unroll
  for (int j = 0; j < 4; ++j) bvv[j] = bptr[cbase + j * 16 + fr];

  unsigned short* obu = (kind == 0) ? Qh : (kind == 1) ? Kh : Vh;
  _Float16* ob = (_Float16*)obu;
  _Float16* sh = (_Float16*)Sh;
#pragma unroll
  for (int i = 0; i < 4; ++i) {
#pragma unroll
    for (int r = 0; r < 4; ++r) {
      int gr = bm + wm * 64 + i * 16 + kg * 4 + r;
      if (gr < M) {
        if (kind == 3) {
          if (s16) {
#pragma unroll
            for (int j = 0; j < 4; ++j)
              sh[(size_t)gr * C + cbase + j * 16 + fr] =
                  (_Float16)(acc[i][j][r] + bvv[j]);
          } else {
#pragma unroll
            for (int j = 0; j < 4; ++j)
              S[(size_t)gr * C + cbase + j * 16 + fr] = acc[i][j][r] + bvv[j];
          }
        } else {
#pragma unroll
          for (int j = 0; j < 4; ++j)
            ob[(size_t)gr * C + cbase + j * 16 + fr] =
                (_Float16)(acc[i][j][r] + bvv[j]);
        }
      }
    }
  }
}

// ---------------------------------------------------------------------------
// Fused attention (fp16 q/k/v). Skip read fp16 (Sh16) when skip16 else fp32.
// sm path: online per-wave softmax (no phase-2 pass).
// ---------------------------------------------------------------------------
__global__ __launch_bounds__(256) void attn_fused3_k(
    const unsigned short* __restrict__ Qh, const unsigned short* __restrict__ Kh,
    const unsigned short* __restrict__ Vh, const int* __restrict__ rowptr,
    const int* __restrict__ csr_src, float* __restrict__ gscratch,
    float* __restrict__ skipio, const unsigned short* __restrict__ Sh16,
    int skip16, unsigned short* __restrict__ Hb, int C, float scale,
    int do_elu, int writeH) {
  __shared__ _Float16 qs[2048];
  __shared__ float ebuf[512];
  __shared__ int ssrc[512];
  __shared__ float wred[8];
  const int i = blockIdx.x;
  const int tid = threadIdx.x;
  const int lane = tid & 63, wid = tid >> 6;
  const int beg = rowptr[i], end = rowptr[i + 1];
  const int deg = end - beg;
  const bool sm = (deg <= 512);

  for (int c0 = tid * 4; c0 < C; c0 += 1024)
    *(uint2*)&qs[c0] = *(const uint2*)(Qh + (size_t)i * C + c0);
  if (sm)
    for (int p = tid; p < deg; p += 256) ssrc[p] = csr_src[beg + p];
  if (tid < 8) wred[tid] = (tid < 4) ? -INFINITY : 0.f;
  __syncthreads();

  if (deg > 0) {
    if (sm) {
      float mw = -INFINITY, sw = 0.f;
      for (int ep = wid; ep < deg; ep += 8) {
        const int e1 = ep + 4;
        const bool h1 = e1 < deg;
        int s0 = ssrc[ep];
        int s1 = h1 ? ssrc[e1] : s0;
        const unsigned short* kr0 = Kh + (size_t)s0 * C;
        const unsigned short* kr1 = Kh + (size_t)s1 * C;
        float su0 = 0.f, su1 = 0.f;
        for (int c0 = lane * 8; c0 < C; c0 += 512) {
          uint4 k0 = *(const uint4*)(kr0 + c0);
          uint4 k1 = *(const uint4*)(kr1 + c0);
          uint4 qv = *(const uint4*)&qs[c0];
          const half2_t* kp0 = (const half2_t*)&k0;
          const half2_t* kp1 = (const half2_t*)&k1;
          const half2_t* qp = (const half2_t*)&qv;
#pragma unroll
          for (int u = 0; u < 4; ++u) {
            su0 = dot2f16(kp0[u], qp[u], su0);
            su1 = dot2f16(kp1[u], qp[u], su1);
          }
        }
#pragma unroll
        for (int o = 32; o; o >>= 1) {
          su0 += __shfl_xor(su0, o);
          su1 += __shfl_xor(su1, o);
        }
        float lg0 = su0 * scale;
        float lg1 = h1 ? su1 * scale : -INFINITY;
        if (lane == 0) {
          ebuf[ep] = lg0;
          if (h1) ebuf[e1] = lg1;
        }
        float nm = fmaxf(mw, fmaxf(lg0, lg1));
        sw = sw * expf(mw - nm) + expf(lg0 - nm) +
             (h1 ? expf(lg1 - nm) : 0.f);
        mw = nm;
      }
      if (lane == 0) {
        wred[wid] = mw;
        wred[4 + wid] = sw;
      }
      __syncthreads();
    } else {
      float wmaxv = -INFINITY;
      for (int ep = wid; ep < deg; ep += 4) {
        int s = csr_src[beg + ep];
        const unsigned short* kr = Kh + (size_t)s * C;
        float sum = 0.f;
        for (int c0 = lane * 8; c0 < C; c0 += 512) {
          uint4 kk = *(const uint4*)(kr + c0);
          uint4 qv = *(const uint4*)&qs[c0];
          const half2_t* kp = (const half2_t*)&kk;
          const half2_t* qp = (const half2_t*)&qv;
#pragma unroll
          for (int u = 0; u < 4; ++u) sum = dot2f16(kp[u], qp[u], sum);
        }
#pragma unroll
        for (int o = 32; o; o >>= 1) sum += __shfl_xor(sum, o);
        float lg = sum * scale;
        if (lane == 0) gscratch[beg + ep] = lg;
        wmaxv = fmaxf(wmaxv, lg);
      }
      if (lane == 0) wred[wid] = wmaxv;
      __syncthreads();
      float m = fmaxf(fmaxf(wred[0], wred[1]), fmaxf(wred[2], wred[3]));
      float part = 0.f;
      for (int ep = tid; ep < deg; ep += 256) {
        float e = expf(gscratch[beg + ep] - m);
        gscratch[beg + ep] = e;
        part += e;
      }
#pragma unroll
      for (int o = 32; o; o >>= 1) part += __shfl_xor(part, o);
      if (lane == 0) wred[4 + wid] = part;
      __syncthreads();
    }
  } else {
    __syncthreads();
  }

  const float gmax = fmaxf(fmaxf(wred[0], wred[1]), fmaxf(wred[2], wred[3]));
  float total;
  if (sm) {
    total = wred[4] * expf(wred[0] - gmax) + wred[5] * expf(wred[1] - gmax) +
            wred[6] * expf(wred[2] - gmax) + wred[7] * expf(wred[3] - gmax);
  } else {
    total = wred[4] + wred[5] + wred[6] + wred[7];
  }
  float denom = 1.f / (total + 1e-16f);
  const int cpt = C >> 8;  // 4 or 8 cols per thread
  const int col0 = tid * cpt;
  float acc[8];
#pragma unroll
  for (int j = 0; j < 8; ++j) acc[j] = 0.f;

  if (sm) {
    int ep = 0;
    if (cpt == 8) {
      for (; ep + 4 <= deg; ep += 4) {
        float a0 = expf(ebuf[ep] - gmax) * denom;
        float a1 = expf(ebuf[ep + 1] - gmax) * denom;
        float a2 = expf(ebuf[ep + 2] - gmax) * denom;
        float a3 = expf(ebuf[ep + 3] - gmax) * denom;
        uint4 p0 = *(const uint4*)(Vh + (size_t)ssrc[ep] * C + col0);
        uint4 p1 = *(const uint4*)(Vh + (size_t)ssrc[ep + 1] * C + col0);
        uint4 p2 = *(const uint4*)(Vh + (size_t)ssrc[ep + 2] * C + col0);
        uint4 p3 = *(const uint4*)(Vh + (size_t)ssrc[ep + 3] * C + col0);
        const _Float16* h0 = (const _Float16*)&p0;
        const _Float16* h1 = (const _Float16*)&p1;
        const _Float16* h2 = (const _Float16*)&p2;
        const _Float16* h3 = (const _Float16*)&p3;
#pragma unroll
        for (int u = 0; u < 8; ++u) {
          acc[u] = fmaf(a0, (float)h0[u], acc[u]);
          acc[u] = fmaf(a1, (float)h1[u], acc[u]);
          acc[u] = fmaf(a2, (float)h2[u], acc[u]);
          acc[u] = fmaf(a3, (float)h3[u], acc[u]);
        }
      }
      for (; ep < deg; ++ep) {
        float a = expf(ebuf[ep] - gmax) * denom;
        uint4 pv = *(const uint4*)(Vh + (size_t)ssrc[ep] * C + col0);
        const _Float16* ph = (const _Float16*)&pv;
#pragma unroll
        for (int u = 0; u < 8; ++u) acc[u] = fmaf(a, (float)ph[u], acc[u]);
      }
    } else {
      for (; ep + 4 <= deg; ep += 4) {
        float a0 = expf(ebuf[ep] - gmax) * denom;
        float a1 = expf(ebuf[ep + 1] - gmax) * denom;
        float a2 = expf(ebuf[ep + 2] - gmax) * denom;
        float a3 = expf(ebuf[ep + 3] - gmax) * denom;
        ushort4 p0 = *(const ushort4*)(Vh + (size_t)ssrc[ep] * C + col0);
        ushort4 p1 = *(const ushort4*)(Vh + (size_t)ssrc[ep + 1] * C + col0);
        ushort4 p2 = *(const ushort4*)(Vh + (size_t)ssrc[ep + 2] * C + col0);
        ushort4 p3 = *(const ushort4*)(Vh + (size_t)ssrc[ep + 3] * C + col0);
        const _Float16* h0 = (const _Float16*)&p0;
        const _Float16* h1 = (const _Float16*)&p1;
        const _Float16* h2 = (const _Float16*)&p2;
        const _Float16* h3 = (const _Float16*)&p3;
#pragma unroll
        for (int u = 0; u < 4; ++u) {
          acc[u] = fmaf(a0, (float)h0[u], acc[u]);
          acc[u] = fmaf(a1, (float)h1[u], acc[u]);
          acc[u] = fmaf(a2, (float)h2[u], acc[u]);
          acc[u] = fmaf(a3, (float)h3[u], acc[u]);
        }
      }
      for (; ep < deg; ++ep) {
        float a = expf(ebuf[ep] - gmax) * denom;
        ushort4 pv = *(const ushort4*)(Vh + (size_t)ssrc[ep] * C + col0);
        const _Float16* ph = (const _Float16*)&pv;
#pragma unroll
        for (int u = 0; u < 4; ++u) acc[u] = fmaf(a, (float)ph[u], acc[u]);
      }
    }
  } else {
    for (int ep = 0; ep < deg; ++ep) {
      float a = gscratch[beg + ep] * denom;
      int s = csr_src[beg + ep];
      const unsigned short* vr = Vh + (size_t)s * C + col0;
      if (cpt == 4) {
        ushort4 pv = *(const ushort4*)vr;
        const _Float16* ph = (const _Float16*)&pv;
#pragma unroll
        for (int u = 0; u < 4; ++u) acc[u] = fmaf(a, (float)ph[u], acc[u]);
      } else {
        uint4 pv = *(const uint4*)vr;
        const _Float16* ph = (const _Float16*)&pv;
#pragma unroll
        for (int u = 0; u < 8; ++u) acc[u] = fmaf(a, (float)ph[u], acc[u]);
      }
    }
  }

  float* srow = skipio + (size_t)i * C + col0;
#pragma unroll
  for (int v4 = 0; v4 < 2; ++v4) {
    if (v4 * 4 < cpt) {
      float4 o;
      if (skip16) {
        ushort4 s4 = *(const ushort4*)(Sh16 + (size_t)i * C + col0 + v4 * 4);
        const _Float16* sp = (const _Float16*)&s4;
        o = make_float4((float)sp[0], (float)sp[1], (float)sp[2], (float)sp[3]);
      } else {
        o = *(const float4*)(srow + v4 * 4);
      }
      o.x += acc[v4 * 4 + 0];
      o.y += acc[v4 * 4 + 1];
      o.z += acc[v4 * 4 + 2];
      o.w += acc[v4 * 4 + 3];
      if (do_elu) {
        o.x = o.x > 0.f ? o.x : expm1f(o.x);
        o.y = o.y > 0.f ? o.y : expm1f(o.y);
        o.z = o.z > 0.f ? o.z : expm1f(o.z);
        o.w = o.w > 0.f ? o.w : expm1f(o.w);
      }
      if (writeH) {
        half4_t h;
        h.x = (_Float16)o.x;
        h.y = (_Float16)o.y;
        h.z = (_Float16)o.z;
        h.w = (_Float16)o.w;
        *(half4_t*)((_Float16*)Hb + (size_t)i * C + col0 + v4 * 4) = h;
      } else {
        *(float4*)(srow + v4 * 4) = o;
      }
    }
  }
}

// ---------------------------------------------------------------------------
// CSR build
// ---------------------------------------------------------------------------
__global__ void count_deg_k(const int* __restrict__ dst, int E,
                            int* __restrict__ cnt) {
  int e = blockIdx.x * blockDim.x + threadIdx.x;
  if (e < E) atomicAdd(&cnt[dst[e]], 1);
}

__global__ void scan_k(const int* __restrict__ cnt, int* __restrict__ rowptr,
                       int N) {
  __shared__ int part[1024];
  int t = threadIdx.x;
  int per = (N + 1023) >> 10;
  int base = t * per;
  int s = 0;
  for (int i = 0; i < per; ++i) {
    int idx = base + i;
    if (idx < N) s += cnt[idx];
  }
  part[t] = s;
  __syncthreads();
  for (int off = 1; off < 1024; off <<= 1) {
    int v = (t >= off) ? part[t - off] : 0;
    __syncthreads();
    part[t] += v;
    __syncthreads();
  }
  int run = part[t] - s;
  for (int i = 0; i < per; ++i) {
    int idx = base + i;
    if (idx < N) {
      rowptr[idx] = run;
      run += cnt[idx];
    }
  }
  if (t == 1023) rowptr[N] = part[1023];
}

__global__ void scatter_csr_k(const int* __restrict__ src,
                              const int* __restrict__ dst, int E,
                              const int* __restrict__ rowptr,
                              int* __restrict__ fill,
                              int* __restrict__ csr_src) {
  int e = blockIdx.x * blockDim.x + threadIdx.x;
  if (e >= E) return;
  int d = dst[e];
  int pos = rowptr[d] + atomicAdd(&fill[d], 1);
  csr_src[pos] = src[e];
}

// ---------------------------------------------------------------------------
extern "C" void kernel_launch(void* const* d_in, const int* in_sizes, int n_in,
                              void* d_out, int out_size, void* d_ws,
                              size_t ws_size, hipStream_t stream) {
  const float* x = (const float*)d_in[0];
  const int* eidx = (const int*)d_in[1];
  const int N = in_sizes[0] / 2048;
  const int E = in_sizes[1] / 2;
  const int* srcA = eidx;
  const int* dstA = eidx + E;
  float* dout = (float*)d_out;

  char* p = (char*)d_ws;
  auto alloc = [&](size_t bytes) {
    void* r = (void*)p;
    p += (bytes + 255) & ~(size_t)255;
    return r;
  };

  float* logits = (float*)alloc((size_t)E * 4);
  int* rowptr = (int*)alloc((size_t)(N + 1) * 4);
  int* cnt = (int*)alloc((size_t)N * 4);
  int* fill = (int*)alloc((size_t)N * 4);
  int* csr_src = (int*)alloc((size_t)E * 4);

  hipMemsetAsync(cnt, 0, (size_t)N * 4, stream);
  hipMemsetAsync(fill, 0, (size_t)N * 4, stream);
  count_deg_k<<<(E + 255) / 256, 256, 0, stream>>>(dstA, E, cnt);
  scan_k<<<1, 1024, 0, stream>>>(cnt, rowptr, N);
  scatter_csr_k<<<(E + 255) / 256, 256, 0, stream>>>(srcA, dstA, E, rowptr,
                                                     fill, csr_src);

  const size_t szH = (size_t)N * 2048 * 2;          // fp16 [N][2048]
  const size_t szWt = (size_t)4 * 1024 * 2048 * 2;  // fp16 [4C][K] per layer

  unsigned short* Hb = (unsigned short*)alloc(szH);
  unsigned short* Qh = (unsigned short*)alloc(szH);
  unsigned short* Kh = (unsigned short*)alloc(szH);
  unsigned short* Vh = (unsigned short*)alloc(szH);
  unsigned short* Wt[4];
  for (int L = 0; L < 4; ++L) Wt[L] = (unsigned short*)alloc(szWt);

  const int fi[4] = {2048, 1024, 2048, 1024};
  const int fo[4] = {1024, 2048, 1024, 2048};
  const int elu[4] = {1, 0, 1, 0};

  cast_f16_k<<<(int)(((size_t)N * 2048 / 4 + 255) / 256), 256, 0, stream>>>(
      x, Hb, (size_t)N * 2048 / 4);

  TranspAll ta;
  for (int L = 0; L < 4; ++L) {
    for (int m = 0; m < 4; ++m)
      ta.W[L * 4 + m] = (const float*)d_in[2 + L * 8 + 2 * m];
    ta.T[L] = Wt[L];
  }
  transp_all_k<<<dim3(64, 64, 16), 256, 0, stream>>>(ta);

  // dout doubles as fp16 skip buffer for L<3 (fully rewritten at L=3)
  unsigned short* Sh = (unsigned short*)dout;

  for (int L = 0; L < 4; ++L) {
    const int K = fi[L], C = fo[L];
    const int b = 2 + L * 8;
    const float scale = (float)(1.0 / sqrt((double)C));
    const int NX = (N + 255) / 256;
    const int NY = 4 * C / 128;
    const int s16 = (L < 3) ? 1 : 0;
    gemm_f16_k<<<NX * NY, 512, 0, stream>>>(
        Hb, Wt[L], (const float*)d_in[b + 1], (const float*)d_in[b + 3],
        (const float*)d_in[b + 5], (const float*)d_in[b + 7], Qh, Kh, Vh, dout,
        Sh, s16, N, K, C, NX, NY);
    attn_fused3_k<<<N, 256, 0, stream>>>(Qh, Kh, Vh, rowptr, csr_src, logits,
                                         dout, Sh, s16, Hb, C, scale, elu[L],
                                         L < 3 ? 1 : 0);
  }
}